// Round 6
// baseline (2160.693 us; speedup 1.0000x reference)
//
#include <hip/hip_runtime.h>
#include <hip/hip_fp16.h>
#include <math.h>

// Tunables for the bucketed CSR build.
#define MAXB 1024        // max buckets supported by LDS arrays
#define TILE 4096        // edges per bin_scatter tile
#define SCAT_T 512       // threads in bin_scatter block
#define EPT (TILE / SCAT_T)
#define LCAP 14336       // bucket_csr LDS col capacity (56KB)

// ---------------- fp16 pack helpers ----------------

__device__ __forceinline__ unsigned int pack_f16(float a, float b) {
    __half2 h = __floats2half2_rn(a, b);
    return *reinterpret_cast<unsigned int*>(&h);
}
__device__ __forceinline__ float f16_lo(unsigned int u) {
    __half2 h = *reinterpret_cast<__half2*>(&u);
    return __low2float(h);
}
__device__ __forceinline__ float f16_hi(unsigned int u) {
    __half2 h = *reinterpret_cast<__half2*>(&u);
    return __high2float(h);
}

// ---------------- edge dtype detection (int32 vs int64) ----------------

__global__ void detect_kernel(const int* __restrict__ ei, int* __restrict__ flag) {
    int i = threadIdx.x;  // one block of 1024
    if (ei[2 * i + 1] != 0) atomicAdd(flag, 1);
}

__device__ __forceinline__ int load_src(const int* ei, int e, bool is64, int i) {
    return is64 ? ei[2 * i] : ei[i];
}
__device__ __forceinline__ int load_dst(const int* ei, int e, bool is64, int i) {
    return is64 ? ei[2 * e + 2 * i] : ei[e + i];
}

// ---------------- pass 1: per-bucket edge counts ----------------

__global__ __launch_bounds__(256) void bin_count(const int* __restrict__ ei, int e,
                                                 const int* __restrict__ flag, int shift,
                                                 int* __restrict__ gcnt) {
    __shared__ int h[MAXB];
    for (int i = threadIdx.x; i < MAXB; i += 256) h[i] = 0;
    __syncthreads();
    bool is64 = (*flag == 0);
    int stride = gridDim.x * 256;
    for (int i = blockIdx.x * 256 + threadIdx.x; i < e; i += stride) {
        int d = load_dst(ei, e, is64, i);
        atomicAdd(&h[d >> shift], 1);
    }
    __syncthreads();
    for (int i = threadIdx.x; i < MAXB; i += 256)
        if (h[i]) atomicAdd(&gcnt[i], h[i]);
}

// ---------------- pass 2: scan bucket counts -> base, init gcursor ----------------

__global__ void bin_scan_init(const int* __restrict__ gcnt, int nb,
                              int* __restrict__ base, int* __restrict__ gcursor) {
    __shared__ int sh[1024];
    int t = threadIdx.x;
    int v = (t < nb) ? gcnt[t] : 0;
    sh[t] = v;
    __syncthreads();
    for (int off = 1; off < 1024; off <<= 1) {
        int x = (t >= off) ? sh[t - off] : 0;
        __syncthreads();
        sh[t] += x;
        __syncthreads();
    }
    if (t < nb) {
        int excl = sh[t] - v;
        base[t] = excl;
        gcursor[t] = excl;
        if (t == nb - 1) base[nb] = sh[t];
    }
}

// ---------------- pass 3: tile counting-sort scatter into buckets ----------------

__global__ __launch_bounds__(SCAT_T) void bin_scatter(const int* __restrict__ ei, int e,
                                                      const int* __restrict__ flag, int shift,
                                                      int* __restrict__ gcursor,
                                                      unsigned int* __restrict__ gpk) {
    __shared__ int hist[MAXB];
    __shared__ int lbase[MAXB];
    __shared__ int gbase[MAXB];
    __shared__ int cur[MAXB];
    __shared__ unsigned int sbuf[TILE];
    __shared__ unsigned short sbkt[TILE];
    __shared__ int sh[SCAT_T];

    const int t = threadIdx.x;
    const int mask = (1 << shift) - 1;
    const bool is64 = (*flag == 0);
    const int tile0 = blockIdx.x * TILE;
    const int cnt = min(TILE, e - tile0);

    for (int i = t; i < MAXB; i += SCAT_T) hist[i] = 0;
    __syncthreads();

    unsigned int pk[EPT];
    int bk[EPT];
#pragma unroll
    for (int k = 0; k < EPT; k++) {
        int g = tile0 + k * SCAT_T + t;
        bk[k] = -1;
        if (g < e) {
            int s = load_src(ei, e, is64, g);
            int d = load_dst(ei, e, is64, g);
            int b = d >> shift;
            pk[k] = ((unsigned int)s << shift) | (unsigned int)(d & mask);
            bk[k] = b;
            atomicAdd(&hist[b], 1);
        }
    }
    __syncthreads();

    {
        int h0 = hist[2 * t];
        int h1 = hist[2 * t + 1];
        int s = h0 + h1;
        sh[t] = s;
        __syncthreads();
        for (int off = 1; off < SCAT_T; off <<= 1) {
            int x = (t >= off) ? sh[t - off] : 0;
            __syncthreads();
            sh[t] += x;
            __syncthreads();
        }
        int excl = sh[t] - s;
        lbase[2 * t] = excl;
        lbase[2 * t + 1] = excl + h0;
    }
    __syncthreads();

    for (int i = t; i < MAXB; i += SCAT_T) {
        int c = hist[i];
        if (c > 0) gbase[i] = atomicAdd(&gcursor[i], c);
        cur[i] = lbase[i];
    }
    __syncthreads();

#pragma unroll
    for (int k = 0; k < EPT; k++) {
        if (bk[k] >= 0) {
            int p = atomicAdd(&cur[bk[k]], 1);
            sbuf[p] = pk[k];
            sbkt[p] = (unsigned short)bk[k];
        }
    }
    __syncthreads();

    for (int i = t; i < cnt; i += SCAT_T) {
        int b = sbkt[i];
        gpk[gbase[b] + (i - lbase[b])] = sbuf[i];
    }
}

// ---------------- pass 4: per-bucket degree + dinv (coalesced) ----------------

__global__ __launch_bounds__(256) void bucket_deg(const unsigned int* __restrict__ gpk,
                                                  const int* __restrict__ base, int shift,
                                                  int n, int* __restrict__ deg,
                                                  float* __restrict__ dinv) {
    __shared__ int dc[MAXB];
    int b = blockIdx.x;
    int mask = (1 << shift) - 1;
    int node0 = b << shift;
    int nc = min(1 << shift, n - node0);
    for (int i = threadIdx.x; i < (1 << shift); i += 256) dc[i] = 0;
    __syncthreads();
    int lo = base[b], hi = base[b + 1];
    for (int j = lo + threadIdx.x; j < hi; j += 256)
        atomicAdd(&dc[gpk[j] & mask], 1);
    __syncthreads();
    for (int i = threadIdx.x; i < nc; i += 256) {
        int d = dc[i];
        deg[node0 + i] = d;
        dinv[node0 + i] = rsqrtf(1.0f + (float)d);
    }
}

// ---------------- row_ptr scan over deg ----------------

__global__ void scan_partial(const int* __restrict__ deg, int* __restrict__ out,
                             int* __restrict__ bsums, int n) {
    __shared__ int sh[256];
    int t = threadIdx.x;
    int base = blockIdx.x * 1024 + t * 4;
    int v0 = 0, v1 = 0, v2 = 0, v3 = 0;
    if (base + 0 < n) v0 = deg[base + 0];
    if (base + 1 < n) v1 = deg[base + 1];
    if (base + 2 < n) v2 = deg[base + 2];
    if (base + 3 < n) v3 = deg[base + 3];
    int s = v0 + v1 + v2 + v3;
    sh[t] = s;
    __syncthreads();
    for (int off = 1; off < 256; off <<= 1) {
        int x = (t >= off) ? sh[t - off] : 0;
        __syncthreads();
        sh[t] += x;
        __syncthreads();
    }
    int excl = sh[t] - s;
    if (base + 0 < n) out[base + 0] = excl;  excl += v0;
    if (base + 1 < n) out[base + 1] = excl;  excl += v1;
    if (base + 2 < n) out[base + 2] = excl;  excl += v2;
    if (base + 3 < n) out[base + 3] = excl;
    if (t == 255) bsums[blockIdx.x] = sh[255];
}

__global__ void scan_bsums(int* bsums, int nb) {
    __shared__ int sh[1024];
    int t = threadIdx.x;
    sh[t] = (t < nb) ? bsums[t] : 0;
    __syncthreads();
    for (int off = 1; off < 1024; off <<= 1) {
        int x = (t >= off) ? sh[t - off] : 0;
        __syncthreads();
        sh[t] += x;
        __syncthreads();
    }
    if (t < nb) bsums[t] = sh[t];
}

__global__ void scan_add(int* __restrict__ row_ptr, const int* __restrict__ bsums,
                         int n, int nb) {
    int i = blockIdx.x * blockDim.x + threadIdx.x;
    if (i < n) {
        int b = i >> 10;
        if (b > 0) row_ptr[i] += bsums[b - 1];
    } else if (i == n) {
        row_ptr[n] = bsums[nb - 1];
    }
}

// ---------------- pass 5: per-bucket exact CSR build in LDS ----------------

__global__ __launch_bounds__(256) void bucket_csr(const unsigned int* __restrict__ gpk,
                                                  const int* __restrict__ base,
                                                  const int* __restrict__ row_ptr, int shift,
                                                  int n, int* __restrict__ col) {
    __shared__ int lcol[LCAP];
    __shared__ int cur[MAXB];
    int b = blockIdx.x;
    int mask = (1 << shift) - 1;
    int node0 = b << shift;
    int nc = min(1 << shift, n - node0);
    int rstart = row_ptr[node0];
    for (int i = threadIdx.x; i < nc; i += 256)
        cur[i] = row_ptr[node0 + i] - rstart;
    __syncthreads();
    int lo = base[b], hi = base[b + 1];
    int ecnt = hi - lo;
    if (ecnt <= LCAP) {
        for (int j = lo + threadIdx.x; j < hi; j += 256) {
            unsigned int v = gpk[j];
            int p = atomicAdd(&cur[v & mask], 1);
            lcol[p] = (int)(v >> shift);
        }
        __syncthreads();
        for (int j = threadIdx.x; j < ecnt; j += 256)
            col[rstart + j] = lcol[j];
    } else {
        for (int j = lo + threadIdx.x; j < hi; j += 256) {
            unsigned int v = gpk[j];
            int p = atomicAdd(&cur[v & mask], 1);
            col[rstart + p] = (int)(v >> shift);
        }
    }
}

// ---------------- GEMM: out[n,CO] = A[n,CI] @ W[CI,CO] ----------------
// SCALE: multiply row by dinv[row]. PACKOUT: write packed fp16 half2 words
// (for the gather table); else fp32.
// R6 fix: #pragma unroll 2 on the k-loop + launch_bounds(256,4). R5's full
// unroll hoisted 16 k-steps x 8 rows of float4 loads -> 256 VGPR + ~360 MB
// scratch spill traffic per dispatch (226 us for a 12 us kernel).

template <int CI, int CO, bool SCALE, bool PACKOUT>
__global__ __launch_bounds__(256, 4) void gemm_kernel(const float* __restrict__ A,
                                                      const float* __restrict__ W,
                                                      const float* __restrict__ dinv,
                                                      void* __restrict__ outv, int n) {
    constexpr int CT = CO / 4;
    constexpr int RG = 256 / CT;
    constexpr int BR = RG * 8;
    __shared__ __align__(16) float Wl[CI * CO];
    for (int i = threadIdx.x; i < CI * CO; i += 256) Wl[i] = W[i];
    __syncthreads();

    int ct = threadIdx.x % CT;
    int rg = threadIdx.x / CT;
    int c0 = ct * 4;
    int row0 = blockIdx.x * BR + rg * 8;

    float acc[8][4] = {{0.f}};
#pragma unroll 2
    for (int k = 0; k < CI; k += 4) {
        float4 a[8];
#pragma unroll
        for (int r = 0; r < 8; r++) {
            int row = row0 + r;
            if (row < n)
                a[r] = *reinterpret_cast<const float4*>(&A[row * CI + k]);
            else
                a[r] = float4{0.f, 0.f, 0.f, 0.f};
        }
#pragma unroll
        for (int kk = 0; kk < 4; kk++) {
            float4 w = *reinterpret_cast<const float4*>(&Wl[(k + kk) * CO + c0]);
#pragma unroll
            for (int r = 0; r < 8; r++) {
                float av = (kk == 0) ? a[r].x : (kk == 1) ? a[r].y : (kk == 2) ? a[r].z : a[r].w;
                acc[r][0] += av * w.x;
                acc[r][1] += av * w.y;
                acc[r][2] += av * w.z;
                acc[r][3] += av * w.w;
            }
        }
    }
#pragma unroll
    for (int r = 0; r < 8; r++) {
        int row = row0 + r;
        if (row >= n) continue;
        float s = SCALE ? dinv[row] : 1.0f;
        if (PACKOUT) {
            unsigned int* o = (unsigned int*)outv;
            uint2 pk{pack_f16(acc[r][0] * s, acc[r][1] * s),
                     pack_f16(acc[r][2] * s, acc[r][3] * s)};
            *reinterpret_cast<uint2*>(&o[(size_t)row * (CO / 2) + ct * 2]) = pk;
        } else {
            float* o = (float*)outv;
            float4 v{acc[r][0] * s, acc[r][1] * s, acc[r][2] * s, acc[r][3] * s};
            *reinterpret_cast<float4*>(&o[(size_t)row * CO + c0]) = v;
        }
    }
}

// ---------------- Fused gather (fp16 table) + self-loop + bias + skip + relu ----------------
// ONE WAVE PER NODE; grid = cdiv(n,4) with 256-thread blocks.

template <int F>
__global__ __launch_bounds__(256) void gather_combine(
    const unsigned int* __restrict__ hp, const int* __restrict__ row_ptr,
    const int* __restrict__ col, const float* __restrict__ dinv,
    const float* __restrict__ bias, const float* __restrict__ sk,
    const float* __restrict__ bsk, float* __restrict__ out, int n) {
    constexpr int PF = F / 2;
    constexpr int EPW = 64 / PF;
    int wid = (blockIdx.x * blockDim.x + threadIdx.x) >> 6;
    int lane = threadIdx.x & 63;
    if (wid >= n) return;
    int sub = lane / PF;
    int fp = lane & (PF - 1);
    int start = row_ptr[wid];
    int end = row_ptr[wid + 1];

    float a0 = 0.f, a1 = 0.f;
    int j = start + sub;
    while (j + EPW < end) {
        int c0 = col[j];
        int c1 = col[j + EPW];
        unsigned int u0 = hp[(size_t)c0 * PF + fp];
        unsigned int u1 = hp[(size_t)c1 * PF + fp];
        a0 += f16_lo(u0); a1 += f16_hi(u0);
        a0 += f16_lo(u1); a1 += f16_hi(u1);
        j += 2 * EPW;
    }
    if (j < end) {
        unsigned int u = hp[(size_t)col[j] * PF + fp];
        a0 += f16_lo(u); a1 += f16_hi(u);
    }

#pragma unroll
    for (int m = PF; m < 64; m <<= 1) {
        a0 += __shfl_xor(a0, m);
        a1 += __shfl_xor(a1, m);
    }

    if (lane < PF) {
        float dn = dinv[wid];
        unsigned int us = hp[(size_t)wid * PF + fp];
        float v0 = dn * a0 + f16_lo(us) * dn + bias[2 * fp];
        float v1 = dn * a1 + f16_hi(us) * dn + bias[2 * fp + 1];
        if (sk) {
            float2 s2 = *reinterpret_cast<const float2*>(&sk[(size_t)wid * F + 2 * fp]);
            v0 += s2.x + bsk[2 * fp];
            v1 += s2.y + bsk[2 * fp + 1];
        }
        float2 o{fmaxf(v0, 0.f), fmaxf(v1, 0.f)};
        *reinterpret_cast<float2*>(&out[(size_t)wid * F + 2 * fp]) = o;
    }
}

// ---------------- Final: out[n] = sigmoid(h3[n,:16] @ Wlin + blin) ----------------

__global__ void final_kernel(const float* __restrict__ h3, const float* __restrict__ Wlin,
                             const float* __restrict__ blin, float* __restrict__ out, int n) {
    int i = blockIdx.x * blockDim.x + threadIdx.x;
    if (i >= n) return;
    float s = blin[0];
#pragma unroll
    for (int f = 0; f < 16; f++) s += h3[i * 16 + f] * Wlin[f];
    out[i] = 1.0f / (1.0f + expf(-s));
}

// ---------------- launch ----------------

extern "C" void kernel_launch(void* const* d_in, const int* in_sizes, int n_in,
                              void* d_out, int out_size, void* d_ws, size_t ws_size,
                              hipStream_t stream) {
    const float* x     = (const float*)d_in[0];
    const int*   ei    = (const int*)d_in[1];
    const float* W1    = (const float*)d_in[2];
    const float* b1    = (const float*)d_in[3];
    const float* W2    = (const float*)d_in[4];
    const float* b2    = (const float*)d_in[5];
    const float* W3    = (const float*)d_in[6];
    const float* b3    = (const float*)d_in[7];
    const float* Wsk02 = (const float*)d_in[8];
    const float* bsk02 = (const float*)d_in[9];
    const float* Wsk13 = (const float*)d_in[10];
    const float* bsk13 = (const float*)d_in[11];
    const float* Wlin  = (const float*)d_in[12];
    const float* blin  = (const float*)d_in[13];

    const int n = in_sizes[0] / 128;
    const int e = in_sizes[1] / 2;

    int shift = 8;
    while (((n + (1 << shift) - 1) >> shift) > MAXB) shift++;
    const int nbkt = (n + (1 << shift) - 1) >> shift;

    // workspace carve (256B aligned)
    char* p = (char*)d_ws;
    auto alloc = [&](size_t bytes) {
        void* r = (void*)p;
        p += (bytes + 255) / 256 * 256;
        return r;
    };
    int*   flag    = (int*)alloc(256);
    int*   gcnt    = (int*)alloc(MAXB * 4);
    int*   base    = (int*)alloc((MAXB + 1) * 4);
    int*   gcursor = (int*)alloc(MAXB * 4);
    int*   bsums   = (int*)alloc(4096);
    int*   deg     = (int*)alloc((size_t)n * 4);
    int*   row_ptr = (int*)alloc((size_t)(n + 1) * 4);
    float* dinv    = (float*)alloc((size_t)n * 4);
    int*   col     = (int*)alloc((size_t)e * 4);
    float* h1      = (float*)alloc((size_t)n * 64 * 4);
    float* h2      = (float*)alloc((size_t)n * 32 * 4);
    float* h3      = (float*)alloc((size_t)n * 16 * 4);
    float* sk      = (float*)alloc((size_t)n * 32 * 4);              // fp32 skip buffer
    size_t prebytes = (size_t)(e > n * 32 ? e : n * 32) * 4;
    unsigned int* preb = (unsigned int*)alloc(prebytes);             // fp16-packed gather table
    unsigned int* gpk  = preb;  // bucketed packed edges; dead before GEMM1 writes preb

    auto cdiv = [](int a, int b) { return (a + b - 1) / b; };

    // CSR build
    hipMemsetAsync(flag, 0, 4, stream);
    hipMemsetAsync(gcnt, 0, MAXB * 4, stream);
    detect_kernel<<<1, 1024, 0, stream>>>(ei, flag);
    bin_count<<<1024, 256, 0, stream>>>(ei, e, flag, shift, gcnt);
    bin_scan_init<<<1, 1024, 0, stream>>>(gcnt, nbkt, base, gcursor);
    bin_scatter<<<cdiv(e, TILE), SCAT_T, 0, stream>>>(ei, e, flag, shift, gcursor, gpk);
    bucket_deg<<<nbkt, 256, 0, stream>>>(gpk, base, shift, n, deg, dinv);
    scan_partial<<<cdiv(n, 1024), 256, 0, stream>>>(deg, row_ptr, bsums, n);
    scan_bsums<<<1, 1024, 0, stream>>>(bsums, cdiv(n, 1024));
    scan_add<<<cdiv(n + 1, 256), 256, 0, stream>>>(row_ptr, bsums, n, cdiv(n, 1024));
    bucket_csr<<<nbkt, 256, 0, stream>>>(gpk, base, row_ptr, shift, n, col);

    // layer 1: h1 = relu(conv(x, W1, b1))
    gemm_kernel<128, 64, true, true><<<cdiv(n, 128), 256, 0, stream>>>(x, W1, dinv, preb, n);
    gather_combine<64><<<cdiv(n, 4), 256, 0, stream>>>(preb, row_ptr, col, dinv, b1,
                                                       nullptr, nullptr, h1, n);

    // layer 2: h2 = relu(conv(h1, W2, b2) + x@Wsk02 + bsk02)
    gemm_kernel<64, 32, true, true><<<cdiv(n, 256), 256, 0, stream>>>(h1, W2, dinv, preb, n);
    gemm_kernel<128, 32, false, false><<<cdiv(n, 256), 256, 0, stream>>>(x, Wsk02, nullptr, sk, n);
    gather_combine<32><<<cdiv(n, 4), 256, 0, stream>>>(preb, row_ptr, col, dinv, b2,
                                                       sk, bsk02, h2, n);

    // layer 3: h3 = relu(conv(h2, W3, b3) + h1@Wsk13 + bsk13)
    gemm_kernel<32, 16, true, true><<<cdiv(n, 512), 256, 0, stream>>>(h2, W3, dinv, preb, n);
    gemm_kernel<64, 16, false, false><<<cdiv(n, 512), 256, 0, stream>>>(h1, Wsk13, nullptr, sk, n);
    gather_combine<16><<<cdiv(n, 4), 256, 0, stream>>>(preb, row_ptr, col, dinv, b3,
                                                       sk, bsk13, h3, n);

    // final
    final_kernel<<<cdiv(n, 256), 256, 0, stream>>>(h3, Wlin, blin, (float*)d_out, n);
}

// Round 7
// 856.910 us; speedup vs baseline: 2.5215x; 2.5215x over previous
//
#include <hip/hip_runtime.h>
#include <hip/hip_fp16.h>
#include <math.h>

// Tunables for the bucketed CSR build.
#define MAXB 1024        // max buckets supported by LDS arrays
#define TILE 4096        // edges per bin_scatter tile
#define SCAT_T 512       // threads in bin_scatter block
#define EPT (TILE / SCAT_T)
#define LCAP 14336       // bucket_csr LDS col capacity (56KB)

// ---------------- fp16 pack helpers ----------------

__device__ __forceinline__ unsigned int pack_f16(float a, float b) {
    __half2 h = __floats2half2_rn(a, b);
    return *reinterpret_cast<unsigned int*>(&h);
}
__device__ __forceinline__ float f16_lo(unsigned int u) {
    __half2 h = *reinterpret_cast<__half2*>(&u);
    return __low2float(h);
}
__device__ __forceinline__ float f16_hi(unsigned int u) {
    __half2 h = *reinterpret_cast<__half2*>(&u);
    return __high2float(h);
}

// ---------------- edge dtype detection (int32 vs int64) ----------------

__global__ void detect_kernel(const int* __restrict__ ei, int* __restrict__ flag) {
    int i = threadIdx.x;  // one block of 1024
    if (ei[2 * i + 1] != 0) atomicAdd(flag, 1);
}

__device__ __forceinline__ int load_src(const int* ei, int e, bool is64, int i) {
    return is64 ? ei[2 * i] : ei[i];
}
__device__ __forceinline__ int load_dst(const int* ei, int e, bool is64, int i) {
    return is64 ? ei[2 * e + 2 * i] : ei[e + i];
}

// ---------------- pass 1: per-bucket edge counts ----------------

__global__ __launch_bounds__(256) void bin_count(const int* __restrict__ ei, int e,
                                                 const int* __restrict__ flag, int shift,
                                                 int* __restrict__ gcnt) {
    __shared__ int h[MAXB];
    for (int i = threadIdx.x; i < MAXB; i += 256) h[i] = 0;
    __syncthreads();
    bool is64 = (*flag == 0);
    int stride = gridDim.x * 256;
    for (int i = blockIdx.x * 256 + threadIdx.x; i < e; i += stride) {
        int d = load_dst(ei, e, is64, i);
        atomicAdd(&h[d >> shift], 1);
    }
    __syncthreads();
    for (int i = threadIdx.x; i < MAXB; i += 256)
        if (h[i]) atomicAdd(&gcnt[i], h[i]);
}

// ---------------- pass 2: scan bucket counts -> base, init gcursor ----------------

__global__ void bin_scan_init(const int* __restrict__ gcnt, int nb,
                              int* __restrict__ base, int* __restrict__ gcursor) {
    __shared__ int sh[1024];
    int t = threadIdx.x;
    int v = (t < nb) ? gcnt[t] : 0;
    sh[t] = v;
    __syncthreads();
    for (int off = 1; off < 1024; off <<= 1) {
        int x = (t >= off) ? sh[t - off] : 0;
        __syncthreads();
        sh[t] += x;
        __syncthreads();
    }
    if (t < nb) {
        int excl = sh[t] - v;
        base[t] = excl;
        gcursor[t] = excl;
        if (t == nb - 1) base[nb] = sh[t];
    }
}

// ---------------- pass 3: tile counting-sort scatter into buckets ----------------

__global__ __launch_bounds__(SCAT_T) void bin_scatter(const int* __restrict__ ei, int e,
                                                      const int* __restrict__ flag, int shift,
                                                      int* __restrict__ gcursor,
                                                      unsigned int* __restrict__ gpk) {
    __shared__ int hist[MAXB];
    __shared__ int lbase[MAXB];
    __shared__ int gbase[MAXB];
    __shared__ int cur[MAXB];
    __shared__ unsigned int sbuf[TILE];
    __shared__ unsigned short sbkt[TILE];
    __shared__ int sh[SCAT_T];

    const int t = threadIdx.x;
    const int mask = (1 << shift) - 1;
    const bool is64 = (*flag == 0);
    const int tile0 = blockIdx.x * TILE;
    const int cnt = min(TILE, e - tile0);

    for (int i = t; i < MAXB; i += SCAT_T) hist[i] = 0;
    __syncthreads();

    unsigned int pk[EPT];
    int bk[EPT];
#pragma unroll
    for (int k = 0; k < EPT; k++) {
        int g = tile0 + k * SCAT_T + t;
        bk[k] = -1;
        if (g < e) {
            int s = load_src(ei, e, is64, g);
            int d = load_dst(ei, e, is64, g);
            int b = d >> shift;
            pk[k] = ((unsigned int)s << shift) | (unsigned int)(d & mask);
            bk[k] = b;
            atomicAdd(&hist[b], 1);
        }
    }
    __syncthreads();

    {
        int h0 = hist[2 * t];
        int h1 = hist[2 * t + 1];
        int s = h0 + h1;
        sh[t] = s;
        __syncthreads();
        for (int off = 1; off < SCAT_T; off <<= 1) {
            int x = (t >= off) ? sh[t - off] : 0;
            __syncthreads();
            sh[t] += x;
            __syncthreads();
        }
        int excl = sh[t] - s;
        lbase[2 * t] = excl;
        lbase[2 * t + 1] = excl + h0;
    }
    __syncthreads();

    for (int i = t; i < MAXB; i += SCAT_T) {
        int c = hist[i];
        if (c > 0) gbase[i] = atomicAdd(&gcursor[i], c);
        cur[i] = lbase[i];
    }
    __syncthreads();

#pragma unroll
    for (int k = 0; k < EPT; k++) {
        if (bk[k] >= 0) {
            int p = atomicAdd(&cur[bk[k]], 1);
            sbuf[p] = pk[k];
            sbkt[p] = (unsigned short)bk[k];
        }
    }
    __syncthreads();

    for (int i = t; i < cnt; i += SCAT_T) {
        int b = sbkt[i];
        gpk[gbase[b] + (i - lbase[b])] = sbuf[i];
    }
}

// ---------------- pass 4: per-bucket degree + dinv (coalesced) ----------------

__global__ __launch_bounds__(256) void bucket_deg(const unsigned int* __restrict__ gpk,
                                                  const int* __restrict__ base, int shift,
                                                  int n, int* __restrict__ deg,
                                                  float* __restrict__ dinv) {
    __shared__ int dc[MAXB];
    int b = blockIdx.x;
    int mask = (1 << shift) - 1;
    int node0 = b << shift;
    int nc = min(1 << shift, n - node0);
    for (int i = threadIdx.x; i < (1 << shift); i += 256) dc[i] = 0;
    __syncthreads();
    int lo = base[b], hi = base[b + 1];
    for (int j = lo + threadIdx.x; j < hi; j += 256)
        atomicAdd(&dc[gpk[j] & mask], 1);
    __syncthreads();
    for (int i = threadIdx.x; i < nc; i += 256) {
        int d = dc[i];
        deg[node0 + i] = d;
        dinv[node0 + i] = rsqrtf(1.0f + (float)d);
    }
}

// ---------------- row_ptr scan over deg ----------------

__global__ void scan_partial(const int* __restrict__ deg, int* __restrict__ out,
                             int* __restrict__ bsums, int n) {
    __shared__ int sh[256];
    int t = threadIdx.x;
    int base = blockIdx.x * 1024 + t * 4;
    int v0 = 0, v1 = 0, v2 = 0, v3 = 0;
    if (base + 0 < n) v0 = deg[base + 0];
    if (base + 1 < n) v1 = deg[base + 1];
    if (base + 2 < n) v2 = deg[base + 2];
    if (base + 3 < n) v3 = deg[base + 3];
    int s = v0 + v1 + v2 + v3;
    sh[t] = s;
    __syncthreads();
    for (int off = 1; off < 256; off <<= 1) {
        int x = (t >= off) ? sh[t - off] : 0;
        __syncthreads();
        sh[t] += x;
        __syncthreads();
    }
    int excl = sh[t] - s;
    if (base + 0 < n) out[base + 0] = excl;  excl += v0;
    if (base + 1 < n) out[base + 1] = excl;  excl += v1;
    if (base + 2 < n) out[base + 2] = excl;  excl += v2;
    if (base + 3 < n) out[base + 3] = excl;
    if (t == 255) bsums[blockIdx.x] = sh[255];
}

__global__ void scan_bsums(int* bsums, int nb) {
    __shared__ int sh[1024];
    int t = threadIdx.x;
    sh[t] = (t < nb) ? bsums[t] : 0;
    __syncthreads();
    for (int off = 1; off < 1024; off <<= 1) {
        int x = (t >= off) ? sh[t - off] : 0;
        __syncthreads();
        sh[t] += x;
        __syncthreads();
    }
    if (t < nb) bsums[t] = sh[t];
}

__global__ void scan_add(int* __restrict__ row_ptr, const int* __restrict__ bsums,
                         int n, int nb) {
    int i = blockIdx.x * blockDim.x + threadIdx.x;
    if (i < n) {
        int b = i >> 10;
        if (b > 0) row_ptr[i] += bsums[b - 1];
    } else if (i == n) {
        row_ptr[n] = bsums[nb - 1];
    }
}

// ---------------- pass 5: per-bucket exact CSR build in LDS ----------------

__global__ __launch_bounds__(256) void bucket_csr(const unsigned int* __restrict__ gpk,
                                                  const int* __restrict__ base,
                                                  const int* __restrict__ row_ptr, int shift,
                                                  int n, int* __restrict__ col) {
    __shared__ int lcol[LCAP];
    __shared__ int cur[MAXB];
    int b = blockIdx.x;
    int mask = (1 << shift) - 1;
    int node0 = b << shift;
    int nc = min(1 << shift, n - node0);
    int rstart = row_ptr[node0];
    for (int i = threadIdx.x; i < nc; i += 256)
        cur[i] = row_ptr[node0 + i] - rstart;
    __syncthreads();
    int lo = base[b], hi = base[b + 1];
    int ecnt = hi - lo;
    if (ecnt <= LCAP) {
        for (int j = lo + threadIdx.x; j < hi; j += 256) {
            unsigned int v = gpk[j];
            int p = atomicAdd(&cur[v & mask], 1);
            lcol[p] = (int)(v >> shift);
        }
        __syncthreads();
        for (int j = threadIdx.x; j < ecnt; j += 256)
            col[rstart + j] = lcol[j];
    } else {
        for (int j = lo + threadIdx.x; j < hi; j += 256) {
            unsigned int v = gpk[j];
            int p = atomicAdd(&cur[v & mask], 1);
            col[rstart + p] = (int)(v >> shift);
        }
    }
}

// ---------------- GEMM: out[n,CO] = A[n,CI] @ W[CI,CO] ----------------
// R7: register-lean 4 rows x 4 cols per thread (acc 16 + one k-step loads 16
// VGPR; ~70 live with unroll 2). NO min-waves launch_bounds arg: R6's
// (256,4) made the allocator clamp to 64 VGPR and spill 2.4 GB/dispatch.
// R5's full unroll (compile-time CI) hoisted 16 k-steps -> 256 VGPR + spills.

template <int CI, int CO, bool SCALE, bool PACKOUT>
__global__ __launch_bounds__(256) void gemm_kernel(const float* __restrict__ A,
                                                   const float* __restrict__ W,
                                                   const float* __restrict__ dinv,
                                                   void* __restrict__ outv, int n) {
    constexpr int CT = CO / 4;        // threads covering CO (4 cols each)
    constexpr int RG = 256 / CT;      // concurrent row-groups per block
    constexpr int TR = 4;             // rows per thread
    constexpr int BR = RG * TR;       // rows per block
    __shared__ __align__(16) float Wl[CI * CO];
    for (int i = threadIdx.x; i < CI * CO; i += 256) Wl[i] = W[i];
    __syncthreads();

    int ct = threadIdx.x % CT;
    int rg = threadIdx.x / CT;
    int c0 = ct * 4;
    int row0 = blockIdx.x * BR + rg * TR;

    float acc[TR][4] = {{0.f}};
#pragma unroll 2
    for (int k = 0; k < CI; k += 4) {
        float4 a[TR];
#pragma unroll
        for (int r = 0; r < TR; r++) {
            int row = row0 + r;
            a[r] = (row < n) ? *reinterpret_cast<const float4*>(&A[(size_t)row * CI + k])
                             : float4{0.f, 0.f, 0.f, 0.f};
        }
#pragma unroll
        for (int kk = 0; kk < 4; kk++) {
            float4 w = *reinterpret_cast<const float4*>(&Wl[(k + kk) * CO + c0]);
#pragma unroll
            for (int r = 0; r < TR; r++) {
                float av = (kk == 0) ? a[r].x : (kk == 1) ? a[r].y : (kk == 2) ? a[r].z : a[r].w;
                acc[r][0] += av * w.x;
                acc[r][1] += av * w.y;
                acc[r][2] += av * w.z;
                acc[r][3] += av * w.w;
            }
        }
    }
#pragma unroll
    for (int r = 0; r < TR; r++) {
        int row = row0 + r;
        if (row >= n) continue;
        float s = SCALE ? dinv[row] : 1.0f;
        if (PACKOUT) {
            unsigned int* o = (unsigned int*)outv;
            uint2 pk{pack_f16(acc[r][0] * s, acc[r][1] * s),
                     pack_f16(acc[r][2] * s, acc[r][3] * s)};
            *reinterpret_cast<uint2*>(&o[(size_t)row * (CO / 2) + ct * 2]) = pk;
        } else {
            float* o = (float*)outv;
            float4 v{acc[r][0] * s, acc[r][1] * s, acc[r][2] * s, acc[r][3] * s};
            *reinterpret_cast<float4*>(&o[(size_t)row * CO + c0]) = v;
        }
    }
}

// ---------------- Fused gather (fp16 table) + self-loop + bias + skip + relu ----------------
// ONE WAVE PER NODE; grid = cdiv(n,4) with 256-thread blocks.

template <int F>
__global__ __launch_bounds__(256) void gather_combine(
    const unsigned int* __restrict__ hp, const int* __restrict__ row_ptr,
    const int* __restrict__ col, const float* __restrict__ dinv,
    const float* __restrict__ bias, const float* __restrict__ sk,
    const float* __restrict__ bsk, float* __restrict__ out, int n) {
    constexpr int PF = F / 2;
    constexpr int EPW = 64 / PF;
    int wid = (blockIdx.x * blockDim.x + threadIdx.x) >> 6;
    int lane = threadIdx.x & 63;
    if (wid >= n) return;
    int sub = lane / PF;
    int fp = lane & (PF - 1);
    int start = row_ptr[wid];
    int end = row_ptr[wid + 1];

    float a0 = 0.f, a1 = 0.f;
    int j = start + sub;
    while (j + EPW < end) {
        int c0 = col[j];
        int c1 = col[j + EPW];
        unsigned int u0 = hp[(size_t)c0 * PF + fp];
        unsigned int u1 = hp[(size_t)c1 * PF + fp];
        a0 += f16_lo(u0); a1 += f16_hi(u0);
        a0 += f16_lo(u1); a1 += f16_hi(u1);
        j += 2 * EPW;
    }
    if (j < end) {
        unsigned int u = hp[(size_t)col[j] * PF + fp];
        a0 += f16_lo(u); a1 += f16_hi(u);
    }

#pragma unroll
    for (int m = PF; m < 64; m <<= 1) {
        a0 += __shfl_xor(a0, m);
        a1 += __shfl_xor(a1, m);
    }

    if (lane < PF) {
        float dn = dinv[wid];
        unsigned int us = hp[(size_t)wid * PF + fp];
        float v0 = dn * a0 + f16_lo(us) * dn + bias[2 * fp];
        float v1 = dn * a1 + f16_hi(us) * dn + bias[2 * fp + 1];
        if (sk) {
            float2 s2 = *reinterpret_cast<const float2*>(&sk[(size_t)wid * F + 2 * fp]);
            v0 += s2.x + bsk[2 * fp];
            v1 += s2.y + bsk[2 * fp + 1];
        }
        float2 o{fmaxf(v0, 0.f), fmaxf(v1, 0.f)};
        *reinterpret_cast<float2*>(&out[(size_t)wid * F + 2 * fp]) = o;
    }
}

// ---------------- Final: out[n] = sigmoid(h3[n,:16] @ Wlin + blin) ----------------

__global__ void final_kernel(const float* __restrict__ h3, const float* __restrict__ Wlin,
                             const float* __restrict__ blin, float* __restrict__ out, int n) {
    int i = blockIdx.x * blockDim.x + threadIdx.x;
    if (i >= n) return;
    float s = blin[0];
#pragma unroll
    for (int f = 0; f < 16; f++) s += h3[i * 16 + f] * Wlin[f];
    out[i] = 1.0f / (1.0f + expf(-s));
}

// ---------------- launch ----------------

extern "C" void kernel_launch(void* const* d_in, const int* in_sizes, int n_in,
                              void* d_out, int out_size, void* d_ws, size_t ws_size,
                              hipStream_t stream) {
    const float* x     = (const float*)d_in[0];
    const int*   ei    = (const int*)d_in[1];
    const float* W1    = (const float*)d_in[2];
    const float* b1    = (const float*)d_in[3];
    const float* W2    = (const float*)d_in[4];
    const float* b2    = (const float*)d_in[5];
    const float* W3    = (const float*)d_in[6];
    const float* b3    = (const float*)d_in[7];
    const float* Wsk02 = (const float*)d_in[8];
    const float* bsk02 = (const float*)d_in[9];
    const float* Wsk13 = (const float*)d_in[10];
    const float* bsk13 = (const float*)d_in[11];
    const float* Wlin  = (const float*)d_in[12];
    const float* blin  = (const float*)d_in[13];

    const int n = in_sizes[0] / 128;
    const int e = in_sizes[1] / 2;

    int shift = 8;
    while (((n + (1 << shift) - 1) >> shift) > MAXB) shift++;
    const int nbkt = (n + (1 << shift) - 1) >> shift;

    // workspace carve (256B aligned)
    char* p = (char*)d_ws;
    auto alloc = [&](size_t bytes) {
        void* r = (void*)p;
        p += (bytes + 255) / 256 * 256;
        return r;
    };
    int*   flag    = (int*)alloc(256);
    int*   gcnt    = (int*)alloc(MAXB * 4);
    int*   base    = (int*)alloc((MAXB + 1) * 4);
    int*   gcursor = (int*)alloc(MAXB * 4);
    int*   bsums   = (int*)alloc(4096);
    int*   deg     = (int*)alloc((size_t)n * 4);
    int*   row_ptr = (int*)alloc((size_t)(n + 1) * 4);
    float* dinv    = (float*)alloc((size_t)n * 4);
    int*   col     = (int*)alloc((size_t)e * 4);
    float* h1      = (float*)alloc((size_t)n * 64 * 4);
    float* h2      = (float*)alloc((size_t)n * 32 * 4);
    float* h3      = (float*)alloc((size_t)n * 16 * 4);
    float* sk      = (float*)alloc((size_t)n * 32 * 4);              // fp32 skip buffer
    size_t prebytes = (size_t)(e > n * 32 ? e : n * 32) * 4;
    unsigned int* preb = (unsigned int*)alloc(prebytes);             // fp16-packed gather table
    unsigned int* gpk  = preb;  // bucketed packed edges; dead before GEMM1 writes preb

    auto cdiv = [](int a, int b) { return (a + b - 1) / b; };

    // CSR build
    hipMemsetAsync(flag, 0, 4, stream);
    hipMemsetAsync(gcnt, 0, MAXB * 4, stream);
    detect_kernel<<<1, 1024, 0, stream>>>(ei, flag);
    bin_count<<<1024, 256, 0, stream>>>(ei, e, flag, shift, gcnt);
    bin_scan_init<<<1, 1024, 0, stream>>>(gcnt, nbkt, base, gcursor);
    bin_scatter<<<cdiv(e, TILE), SCAT_T, 0, stream>>>(ei, e, flag, shift, gcursor, gpk);
    bucket_deg<<<nbkt, 256, 0, stream>>>(gpk, base, shift, n, deg, dinv);
    scan_partial<<<cdiv(n, 1024), 256, 0, stream>>>(deg, row_ptr, bsums, n);
    scan_bsums<<<1, 1024, 0, stream>>>(bsums, cdiv(n, 1024));
    scan_add<<<cdiv(n + 1, 256), 256, 0, stream>>>(row_ptr, bsums, n, cdiv(n, 1024));
    bucket_csr<<<nbkt, 256, 0, stream>>>(gpk, base, row_ptr, shift, n, col);

    // layer 1: h1 = relu(conv(x, W1, b1))   [BR for <128,64> is 64 rows/block]
    gemm_kernel<128, 64, true, true><<<cdiv(n, 64), 256, 0, stream>>>(x, W1, dinv, preb, n);
    gather_combine<64><<<cdiv(n, 4), 256, 0, stream>>>(preb, row_ptr, col, dinv, b1,
                                                       nullptr, nullptr, h1, n);

    // layer 2: h2 = relu(conv(h1, W2, b2) + x@Wsk02 + bsk02)
    gemm_kernel<64, 32, true, true><<<cdiv(n, 128), 256, 0, stream>>>(h1, W2, dinv, preb, n);
    gemm_kernel<128, 32, false, false><<<cdiv(n, 128), 256, 0, stream>>>(x, Wsk02, nullptr, sk, n);
    gather_combine<32><<<cdiv(n, 4), 256, 0, stream>>>(preb, row_ptr, col, dinv, b2,
                                                       sk, bsk02, h2, n);

    // layer 3: h3 = relu(conv(h2, W3, b3) + h1@Wsk13 + bsk13)
    gemm_kernel<32, 16, true, true><<<cdiv(n, 256), 256, 0, stream>>>(h2, W3, dinv, preb, n);
    gemm_kernel<64, 16, false, false><<<cdiv(n, 256), 256, 0, stream>>>(h1, Wsk13, nullptr, sk, n);
    gather_combine<16><<<cdiv(n, 4), 256, 0, stream>>>(preb, row_ptr, col, dinv, b3,
                                                       sk, bsk13, h3, n);

    // final
    final_kernel<<<cdiv(n, 256), 256, 0, stream>>>(h3, Wlin, blin, (float*)d_out, n);
}

// Round 8
// 758.173 us; speedup vs baseline: 2.8499x; 1.1302x over previous
//
#include <hip/hip_runtime.h>
#include <hip/hip_fp16.h>
#include <math.h>

// Tunables for the bucketed CSR build.
#define MAXB 1024        // max buckets supported by LDS arrays
#define TILE 4096        // edges per bin_scatter tile
#define SCAT_T 512       // threads in bin_scatter block
#define EPT (TILE / SCAT_T)
#define LCAP 14336       // bucket_csr LDS col capacity (56KB)

// ---------------- fp16 pack helpers ----------------

__device__ __forceinline__ unsigned int pack_f16(float a, float b) {
    __half2 h = __floats2half2_rn(a, b);
    return *reinterpret_cast<unsigned int*>(&h);
}
__device__ __forceinline__ float f16_lo(unsigned int u) {
    __half2 h = *reinterpret_cast<__half2*>(&u);
    return __low2float(h);
}
__device__ __forceinline__ float f16_hi(unsigned int u) {
    __half2 h = *reinterpret_cast<__half2*>(&u);
    return __high2float(h);
}
// accumulate 8 fp16 (one uint4) into a[8]
__device__ __forceinline__ void acc8(float* a, uint4 u) {
    a[0] += f16_lo(u.x); a[1] += f16_hi(u.x);
    a[2] += f16_lo(u.y); a[3] += f16_hi(u.y);
    a[4] += f16_lo(u.z); a[5] += f16_hi(u.z);
    a[6] += f16_lo(u.w); a[7] += f16_hi(u.w);
}
__device__ __forceinline__ void unpack8(uint4 u, float* v) {
    v[0] = f16_lo(u.x); v[1] = f16_hi(u.x);
    v[2] = f16_lo(u.y); v[3] = f16_hi(u.y);
    v[4] = f16_lo(u.z); v[5] = f16_hi(u.z);
    v[6] = f16_lo(u.w); v[7] = f16_hi(u.w);
}

// ---------------- edge dtype detection (int32 vs int64) ----------------

__global__ void detect_kernel(const int* __restrict__ ei, int* __restrict__ flag) {
    int i = threadIdx.x;  // one block of 1024
    if (ei[2 * i + 1] != 0) atomicAdd(flag, 1);
}

__device__ __forceinline__ int load_src(const int* ei, int e, bool is64, int i) {
    return is64 ? ei[2 * i] : ei[i];
}
__device__ __forceinline__ int load_dst(const int* ei, int e, bool is64, int i) {
    return is64 ? ei[2 * e + 2 * i] : ei[e + i];
}

// ---------------- pass 1: per-bucket edge counts ----------------

__global__ __launch_bounds__(256) void bin_count(const int* __restrict__ ei, int e,
                                                 const int* __restrict__ flag, int shift,
                                                 int* __restrict__ gcnt) {
    __shared__ int h[MAXB];
    for (int i = threadIdx.x; i < MAXB; i += 256) h[i] = 0;
    __syncthreads();
    bool is64 = (*flag == 0);
    int stride = gridDim.x * 256;
    for (int i = blockIdx.x * 256 + threadIdx.x; i < e; i += stride) {
        int d = load_dst(ei, e, is64, i);
        atomicAdd(&h[d >> shift], 1);
    }
    __syncthreads();
    for (int i = threadIdx.x; i < MAXB; i += 256)
        if (h[i]) atomicAdd(&gcnt[i], h[i]);
}

// ---------------- pass 2: scan bucket counts -> base, init gcursor ----------------

__global__ void bin_scan_init(const int* __restrict__ gcnt, int nb,
                              int* __restrict__ base, int* __restrict__ gcursor) {
    __shared__ int sh[1024];
    int t = threadIdx.x;
    int v = (t < nb) ? gcnt[t] : 0;
    sh[t] = v;
    __syncthreads();
    for (int off = 1; off < 1024; off <<= 1) {
        int x = (t >= off) ? sh[t - off] : 0;
        __syncthreads();
        sh[t] += x;
        __syncthreads();
    }
    if (t < nb) {
        int excl = sh[t] - v;
        base[t] = excl;
        gcursor[t] = excl;
        if (t == nb - 1) base[nb] = sh[t];
    }
}

// ---------------- pass 3: tile counting-sort scatter into buckets ----------------

__global__ __launch_bounds__(SCAT_T) void bin_scatter(const int* __restrict__ ei, int e,
                                                      const int* __restrict__ flag, int shift,
                                                      int* __restrict__ gcursor,
                                                      unsigned int* __restrict__ gpk) {
    __shared__ int hist[MAXB];
    __shared__ int lbase[MAXB];
    __shared__ int gbase[MAXB];
    __shared__ int cur[MAXB];
    __shared__ unsigned int sbuf[TILE];
    __shared__ unsigned short sbkt[TILE];
    __shared__ int sh[SCAT_T];

    const int t = threadIdx.x;
    const int mask = (1 << shift) - 1;
    const bool is64 = (*flag == 0);
    const int tile0 = blockIdx.x * TILE;
    const int cnt = min(TILE, e - tile0);

    for (int i = t; i < MAXB; i += SCAT_T) hist[i] = 0;
    __syncthreads();

    unsigned int pk[EPT];
    int bk[EPT];
#pragma unroll
    for (int k = 0; k < EPT; k++) {
        int g = tile0 + k * SCAT_T + t;
        bk[k] = -1;
        if (g < e) {
            int s = load_src(ei, e, is64, g);
            int d = load_dst(ei, e, is64, g);
            int b = d >> shift;
            pk[k] = ((unsigned int)s << shift) | (unsigned int)(d & mask);
            bk[k] = b;
            atomicAdd(&hist[b], 1);
        }
    }
    __syncthreads();

    {
        int h0 = hist[2 * t];
        int h1 = hist[2 * t + 1];
        int s = h0 + h1;
        sh[t] = s;
        __syncthreads();
        for (int off = 1; off < SCAT_T; off <<= 1) {
            int x = (t >= off) ? sh[t - off] : 0;
            __syncthreads();
            sh[t] += x;
            __syncthreads();
        }
        int excl = sh[t] - s;
        lbase[2 * t] = excl;
        lbase[2 * t + 1] = excl + h0;
    }
    __syncthreads();

    for (int i = t; i < MAXB; i += SCAT_T) {
        int c = hist[i];
        if (c > 0) gbase[i] = atomicAdd(&gcursor[i], c);
        cur[i] = lbase[i];
    }
    __syncthreads();

#pragma unroll
    for (int k = 0; k < EPT; k++) {
        if (bk[k] >= 0) {
            int p = atomicAdd(&cur[bk[k]], 1);
            sbuf[p] = pk[k];
            sbkt[p] = (unsigned short)bk[k];
        }
    }
    __syncthreads();

    for (int i = t; i < cnt; i += SCAT_T) {
        int b = sbkt[i];
        gpk[gbase[b] + (i - lbase[b])] = sbuf[i];
    }
}

// ---------------- pass 4: per-bucket degree + dinv (coalesced) ----------------

__global__ __launch_bounds__(256) void bucket_deg(const unsigned int* __restrict__ gpk,
                                                  const int* __restrict__ base, int shift,
                                                  int n, int* __restrict__ deg,
                                                  float* __restrict__ dinv) {
    __shared__ int dc[MAXB];
    int b = blockIdx.x;
    int mask = (1 << shift) - 1;
    int node0 = b << shift;
    int nc = min(1 << shift, n - node0);
    for (int i = threadIdx.x; i < (1 << shift); i += 256) dc[i] = 0;
    __syncthreads();
    int lo = base[b], hi = base[b + 1];
    for (int j = lo + threadIdx.x; j < hi; j += 256)
        atomicAdd(&dc[gpk[j] & mask], 1);
    __syncthreads();
    for (int i = threadIdx.x; i < nc; i += 256) {
        int d = dc[i];
        deg[node0 + i] = d;
        dinv[node0 + i] = rsqrtf(1.0f + (float)d);
    }
}

// ---------------- row_ptr scan over deg ----------------

__global__ void scan_partial(const int* __restrict__ deg, int* __restrict__ out,
                             int* __restrict__ bsums, int n) {
    __shared__ int sh[256];
    int t = threadIdx.x;
    int base = blockIdx.x * 1024 + t * 4;
    int v0 = 0, v1 = 0, v2 = 0, v3 = 0;
    if (base + 0 < n) v0 = deg[base + 0];
    if (base + 1 < n) v1 = deg[base + 1];
    if (base + 2 < n) v2 = deg[base + 2];
    if (base + 3 < n) v3 = deg[base + 3];
    int s = v0 + v1 + v2 + v3;
    sh[t] = s;
    __syncthreads();
    for (int off = 1; off < 256; off <<= 1) {
        int x = (t >= off) ? sh[t - off] : 0;
        __syncthreads();
        sh[t] += x;
        __syncthreads();
    }
    int excl = sh[t] - s;
    if (base + 0 < n) out[base + 0] = excl;  excl += v0;
    if (base + 1 < n) out[base + 1] = excl;  excl += v1;
    if (base + 2 < n) out[base + 2] = excl;  excl += v2;
    if (base + 3 < n) out[base + 3] = excl;
    if (t == 255) bsums[blockIdx.x] = sh[255];
}

__global__ void scan_bsums(int* bsums, int nb) {
    __shared__ int sh[1024];
    int t = threadIdx.x;
    sh[t] = (t < nb) ? bsums[t] : 0;
    __syncthreads();
    for (int off = 1; off < 1024; off <<= 1) {
        int x = (t >= off) ? sh[t - off] : 0;
        __syncthreads();
        sh[t] += x;
        __syncthreads();
    }
    if (t < nb) bsums[t] = sh[t];
}

__global__ void scan_add(int* __restrict__ row_ptr, const int* __restrict__ bsums,
                         int n, int nb) {
    int i = blockIdx.x * blockDim.x + threadIdx.x;
    if (i < n) {
        int b = i >> 10;
        if (b > 0) row_ptr[i] += bsums[b - 1];
    } else if (i == n) {
        row_ptr[n] = bsums[nb - 1];
    }
}

// ---------------- pass 5: per-bucket exact CSR build in LDS ----------------

__global__ __launch_bounds__(256) void bucket_csr(const unsigned int* __restrict__ gpk,
                                                  const int* __restrict__ base,
                                                  const int* __restrict__ row_ptr, int shift,
                                                  int n, int* __restrict__ col) {
    __shared__ int lcol[LCAP];
    __shared__ int cur[MAXB];
    int b = blockIdx.x;
    int mask = (1 << shift) - 1;
    int node0 = b << shift;
    int nc = min(1 << shift, n - node0);
    int rstart = row_ptr[node0];
    for (int i = threadIdx.x; i < nc; i += 256)
        cur[i] = row_ptr[node0 + i] - rstart;
    __syncthreads();
    int lo = base[b], hi = base[b + 1];
    int ecnt = hi - lo;
    if (ecnt <= LCAP) {
        for (int j = lo + threadIdx.x; j < hi; j += 256) {
            unsigned int v = gpk[j];
            int p = atomicAdd(&cur[v & mask], 1);
            lcol[p] = (int)(v >> shift);
        }
        __syncthreads();
        for (int j = threadIdx.x; j < ecnt; j += 256)
            col[rstart + j] = lcol[j];
    } else {
        for (int j = lo + threadIdx.x; j < hi; j += 256) {
            unsigned int v = gpk[j];
            int p = atomicAdd(&cur[v & mask], 1);
            col[rstart + p] = (int)(v >> shift);
        }
    }
}

// ---------------- GEMM: out[n,CO] = A[n,CI] @ W[CI,CO] ----------------
// R7 structure kept: 4 rows x 4 cols per thread, unroll 2, plain
// launch_bounds(256). (R6's (256,4) clamped to 64 VGPR and spilled; R5's
// full unroll hoisted 16 k-steps -> 256 VGPR and spilled.)

template <int CI, int CO, bool SCALE, bool PACKOUT>
__global__ __launch_bounds__(256) void gemm_kernel(const float* __restrict__ A,
                                                   const float* __restrict__ W,
                                                   const float* __restrict__ dinv,
                                                   void* __restrict__ outv, int n) {
    constexpr int CT = CO / 4;        // threads covering CO (4 cols each)
    constexpr int RG = 256 / CT;      // concurrent row-groups per block
    constexpr int TR = 4;             // rows per thread
    constexpr int BR = RG * TR;       // rows per block
    __shared__ __align__(16) float Wl[CI * CO];
    for (int i = threadIdx.x; i < CI * CO; i += 256) Wl[i] = W[i];
    __syncthreads();

    int ct = threadIdx.x % CT;
    int rg = threadIdx.x / CT;
    int c0 = ct * 4;
    int row0 = blockIdx.x * BR + rg * TR;

    float acc[TR][4] = {{0.f}};
#pragma unroll 2
    for (int k = 0; k < CI; k += 4) {
        float4 a[TR];
#pragma unroll
        for (int r = 0; r < TR; r++) {
            int row = row0 + r;
            a[r] = (row < n) ? *reinterpret_cast<const float4*>(&A[(size_t)row * CI + k])
                             : float4{0.f, 0.f, 0.f, 0.f};
        }
#pragma unroll
        for (int kk = 0; kk < 4; kk++) {
            float4 w = *reinterpret_cast<const float4*>(&Wl[(k + kk) * CO + c0]);
#pragma unroll
            for (int r = 0; r < TR; r++) {
                float av = (kk == 0) ? a[r].x : (kk == 1) ? a[r].y : (kk == 2) ? a[r].z : a[r].w;
                acc[r][0] += av * w.x;
                acc[r][1] += av * w.y;
                acc[r][2] += av * w.z;
                acc[r][3] += av * w.w;
            }
        }
    }
#pragma unroll
    for (int r = 0; r < TR; r++) {
        int row = row0 + r;
        if (row >= n) continue;
        float s = SCALE ? dinv[row] : 1.0f;
        if (PACKOUT) {
            unsigned int* o = (unsigned int*)outv;
            uint2 pk{pack_f16(acc[r][0] * s, acc[r][1] * s),
                     pack_f16(acc[r][2] * s, acc[r][3] * s)};
            *reinterpret_cast<uint2*>(&o[(size_t)row * (CO / 2) + ct * 2]) = pk;
        } else {
            float* o = (float*)outv;
            float4 v{acc[r][0] * s, acc[r][1] * s, acc[r][2] * s, acc[r][3] * s};
            *reinterpret_cast<float4*>(&o[(size_t)row * CO + c0]) = v;
        }
    }
}

// ---------------- Fused gather (fp16 table, uint4 loads) + self-loop + bias + skip + relu ----
// ONE WAVE PER NODE; grid = cdiv(n,4) with 256-thread blocks.
// R8: each lane loads 16 B (uint4 = 8 fp16 feats); an edge needs L = F/8
// lanes; EPW = 64/L edges in flight per pass (8/16/32 for F=64/32/16), main
// loop 4x unrolled -> 16-32 outstanding loads/wave (R7 had ~2: latency-bound
// at 199 us with both pipes <40%).

template <int F>
__global__ __launch_bounds__(256) void gather_combine(
    const uint4* __restrict__ hp4, const int* __restrict__ row_ptr,
    const int* __restrict__ col, const float* __restrict__ dinv,
    const float* __restrict__ bias, const float* __restrict__ sk,
    const float* __restrict__ bsk, float* __restrict__ out, int n) {
    constexpr int L = F / 8;      // lanes per edge; also uint4 words per row
    constexpr int EPW = 64 / L;   // edges concurrently per wave-pass
    int wid = (blockIdx.x * blockDim.x + threadIdx.x) >> 6;
    int lane = threadIdx.x & 63;
    if (wid >= n) return;
    int s = lane / L;             // edge slot
    int el = lane % L;            // feat octet within row
    int start = row_ptr[wid];
    int end = row_ptr[wid + 1];

    float a[8] = {0.f, 0.f, 0.f, 0.f, 0.f, 0.f, 0.f, 0.f};
    int j = start + s;
    while (j + 3 * EPW < end) {   // 4 independent load chains
        int c0 = col[j];
        int c1 = col[j + EPW];
        int c2 = col[j + 2 * EPW];
        int c3 = col[j + 3 * EPW];
        uint4 u0 = hp4[(size_t)c0 * L + el];
        uint4 u1 = hp4[(size_t)c1 * L + el];
        uint4 u2 = hp4[(size_t)c2 * L + el];
        uint4 u3 = hp4[(size_t)c3 * L + el];
        acc8(a, u0); acc8(a, u1); acc8(a, u2); acc8(a, u3);
        j += 4 * EPW;
    }
    while (j < end) {
        uint4 u = hp4[(size_t)col[j] * L + el];
        acc8(a, u);
        j += EPW;
    }

    // reduce across edge slots (lanes with same el)
#pragma unroll
    for (int m = L; m < 64; m <<= 1) {
#pragma unroll
        for (int q = 0; q < 8; q++) a[q] += __shfl_xor(a[q], m);
    }

    if (lane < L) {
        float dn = dinv[wid];
        uint4 us = hp4[(size_t)wid * L + el];
        float v[8];
        unpack8(us, v);
        float4 b0 = *reinterpret_cast<const float4*>(&bias[8 * el]);
        float4 b1 = *reinterpret_cast<const float4*>(&bias[8 * el + 4]);
        float o[8];
        o[0] = dn * a[0] + v[0] * dn + b0.x;
        o[1] = dn * a[1] + v[1] * dn + b0.y;
        o[2] = dn * a[2] + v[2] * dn + b0.z;
        o[3] = dn * a[3] + v[3] * dn + b0.w;
        o[4] = dn * a[4] + v[4] * dn + b1.x;
        o[5] = dn * a[5] + v[5] * dn + b1.y;
        o[6] = dn * a[6] + v[6] * dn + b1.z;
        o[7] = dn * a[7] + v[7] * dn + b1.w;
        if (sk) {
            float4 s0 = *reinterpret_cast<const float4*>(&sk[(size_t)wid * F + 8 * el]);
            float4 s1 = *reinterpret_cast<const float4*>(&sk[(size_t)wid * F + 8 * el + 4]);
            float4 k0 = *reinterpret_cast<const float4*>(&bsk[8 * el]);
            float4 k1 = *reinterpret_cast<const float4*>(&bsk[8 * el + 4]);
            o[0] += s0.x + k0.x; o[1] += s0.y + k0.y;
            o[2] += s0.z + k0.z; o[3] += s0.w + k0.w;
            o[4] += s1.x + k1.x; o[5] += s1.y + k1.y;
            o[6] += s1.z + k1.z; o[7] += s1.w + k1.w;
        }
        float4 w0{fmaxf(o[0], 0.f), fmaxf(o[1], 0.f), fmaxf(o[2], 0.f), fmaxf(o[3], 0.f)};
        float4 w1{fmaxf(o[4], 0.f), fmaxf(o[5], 0.f), fmaxf(o[6], 0.f), fmaxf(o[7], 0.f)};
        *reinterpret_cast<float4*>(&out[(size_t)wid * F + 8 * el]) = w0;
        *reinterpret_cast<float4*>(&out[(size_t)wid * F + 8 * el + 4]) = w1;
    }
}

// ---------------- Final: out[n] = sigmoid(h3[n,:16] @ Wlin + blin) ----------------

__global__ void final_kernel(const float* __restrict__ h3, const float* __restrict__ Wlin,
                             const float* __restrict__ blin, float* __restrict__ out, int n) {
    int i = blockIdx.x * blockDim.x + threadIdx.x;
    if (i >= n) return;
    float s = blin[0];
#pragma unroll
    for (int f = 0; f < 16; f++) s += h3[i * 16 + f] * Wlin[f];
    out[i] = 1.0f / (1.0f + expf(-s));
}

// ---------------- launch ----------------

extern "C" void kernel_launch(void* const* d_in, const int* in_sizes, int n_in,
                              void* d_out, int out_size, void* d_ws, size_t ws_size,
                              hipStream_t stream) {
    const float* x     = (const float*)d_in[0];
    const int*   ei    = (const int*)d_in[1];
    const float* W1    = (const float*)d_in[2];
    const float* b1    = (const float*)d_in[3];
    const float* W2    = (const float*)d_in[4];
    const float* b2    = (const float*)d_in[5];
    const float* W3    = (const float*)d_in[6];
    const float* b3    = (const float*)d_in[7];
    const float* Wsk02 = (const float*)d_in[8];
    const float* bsk02 = (const float*)d_in[9];
    const float* Wsk13 = (const float*)d_in[10];
    const float* bsk13 = (const float*)d_in[11];
    const float* Wlin  = (const float*)d_in[12];
    const float* blin  = (const float*)d_in[13];

    const int n = in_sizes[0] / 128;
    const int e = in_sizes[1] / 2;

    int shift = 8;
    while (((n + (1 << shift) - 1) >> shift) > MAXB) shift++;
    const int nbkt = (n + (1 << shift) - 1) >> shift;

    // workspace carve (256B aligned)
    char* p = (char*)d_ws;
    auto alloc = [&](size_t bytes) {
        void* r = (void*)p;
        p += (bytes + 255) / 256 * 256;
        return r;
    };
    int*   flag    = (int*)alloc(256);
    int*   gcnt    = (int*)alloc(MAXB * 4);
    int*   base    = (int*)alloc((MAXB + 1) * 4);
    int*   gcursor = (int*)alloc(MAXB * 4);
    int*   bsums   = (int*)alloc(4096);
    int*   deg     = (int*)alloc((size_t)n * 4);
    int*   row_ptr = (int*)alloc((size_t)(n + 1) * 4);
    float* dinv    = (float*)alloc((size_t)n * 4);
    int*   col     = (int*)alloc((size_t)e * 4);
    float* h1      = (float*)alloc((size_t)n * 64 * 4);
    float* h2      = (float*)alloc((size_t)n * 32 * 4);
    float* h3      = (float*)alloc((size_t)n * 16 * 4);
    float* sk      = (float*)alloc((size_t)n * 32 * 4);              // fp32 skip buffer
    size_t prebytes = (size_t)(e > n * 32 ? e : n * 32) * 4;
    unsigned int* preb = (unsigned int*)alloc(prebytes);             // fp16-packed gather table
    unsigned int* gpk  = preb;  // bucketed packed edges; dead before GEMM1 writes preb

    auto cdiv = [](int a, int b) { return (a + b - 1) / b; };

    // CSR build
    hipMemsetAsync(flag, 0, 4, stream);
    hipMemsetAsync(gcnt, 0, MAXB * 4, stream);
    detect_kernel<<<1, 1024, 0, stream>>>(ei, flag);
    bin_count<<<1024, 256, 0, stream>>>(ei, e, flag, shift, gcnt);
    bin_scan_init<<<1, 1024, 0, stream>>>(gcnt, nbkt, base, gcursor);
    bin_scatter<<<cdiv(e, TILE), SCAT_T, 0, stream>>>(ei, e, flag, shift, gcursor, gpk);
    bucket_deg<<<nbkt, 256, 0, stream>>>(gpk, base, shift, n, deg, dinv);
    scan_partial<<<cdiv(n, 1024), 256, 0, stream>>>(deg, row_ptr, bsums, n);
    scan_bsums<<<1, 1024, 0, stream>>>(bsums, cdiv(n, 1024));
    scan_add<<<cdiv(n + 1, 256), 256, 0, stream>>>(row_ptr, bsums, n, cdiv(n, 1024));
    bucket_csr<<<nbkt, 256, 0, stream>>>(gpk, base, row_ptr, shift, n, col);

    // layer 1: h1 = relu(conv(x, W1, b1))
    gemm_kernel<128, 64, true, true><<<cdiv(n, 64), 256, 0, stream>>>(x, W1, dinv, preb, n);
    gather_combine<64><<<cdiv(n, 4), 256, 0, stream>>>((const uint4*)preb, row_ptr, col, dinv,
                                                       b1, nullptr, nullptr, h1, n);

    // layer 2: h2 = relu(conv(h1, W2, b2) + x@Wsk02 + bsk02)
    gemm_kernel<64, 32, true, true><<<cdiv(n, 128), 256, 0, stream>>>(h1, W2, dinv, preb, n);
    gemm_kernel<128, 32, false, false><<<cdiv(n, 128), 256, 0, stream>>>(x, Wsk02, nullptr, sk, n);
    gather_combine<32><<<cdiv(n, 4), 256, 0, stream>>>((const uint4*)preb, row_ptr, col, dinv,
                                                       b2, sk, bsk02, h2, n);

    // layer 3: h3 = relu(conv(h2, W3, b3) + h1@Wsk13 + bsk13)
    gemm_kernel<32, 16, true, true><<<cdiv(n, 256), 256, 0, stream>>>(h2, W3, dinv, preb, n);
    gemm_kernel<64, 16, false, false><<<cdiv(n, 256), 256, 0, stream>>>(h1, Wsk13, nullptr, sk, n);
    gather_combine<16><<<cdiv(n, 4), 256, 0, stream>>>((const uint4*)preb, row_ptr, col, dinv,
                                                       b3, sk, bsk13, h3, n);

    // final
    final_kernel<<<cdiv(n, 256), 256, 0, stream>>>(h3, Wlin, blin, (float*)d_out, n);
}

// Round 9
// 639.211 us; speedup vs baseline: 3.3803x; 1.1861x over previous
//
#include <hip/hip_runtime.h>
#include <hip/hip_fp16.h>
#include <math.h>

// Tunables for the bucketed CSR build.
#define MAXB 1024        // max buckets supported by LDS arrays
#define TILE 4096        // edges per bin_scatter tile
#define SCAT_T 512       // threads in bin_scatter block
#define EPT (TILE / SCAT_T)
#define LCAP 14336       // bucket_csr LDS col capacity (56KB)

// ---------------- fp16 pack helpers ----------------

__device__ __forceinline__ unsigned int pack_f16(float a, float b) {
    __half2 h = __floats2half2_rn(a, b);
    return *reinterpret_cast<unsigned int*>(&h);
}
__device__ __forceinline__ float f16_lo(unsigned int u) {
    __half2 h = *reinterpret_cast<__half2*>(&u);
    return __low2float(h);
}
__device__ __forceinline__ float f16_hi(unsigned int u) {
    __half2 h = *reinterpret_cast<__half2*>(&u);
    return __high2float(h);
}
// accumulate 8 fp16 (one uint4) into a[8]
__device__ __forceinline__ void acc8(float* a, uint4 u) {
    a[0] += f16_lo(u.x); a[1] += f16_hi(u.x);
    a[2] += f16_lo(u.y); a[3] += f16_hi(u.y);
    a[4] += f16_lo(u.z); a[5] += f16_hi(u.z);
    a[6] += f16_lo(u.w); a[7] += f16_hi(u.w);
}
__device__ __forceinline__ void unpack8(uint4 u, float* v) {
    v[0] = f16_lo(u.x); v[1] = f16_hi(u.x);
    v[2] = f16_lo(u.y); v[3] = f16_hi(u.y);
    v[4] = f16_lo(u.z); v[5] = f16_hi(u.z);
    v[6] = f16_lo(u.w); v[7] = f16_hi(u.w);
}

// ---------------- edge dtype detection (int32 vs int64) ----------------

__global__ void detect_kernel(const int* __restrict__ ei, int* __restrict__ flag) {
    int i = threadIdx.x;  // one block of 1024
    if (ei[2 * i + 1] != 0) atomicAdd(flag, 1);
}

__device__ __forceinline__ int load_src(const int* ei, int e, bool is64, int i) {
    return is64 ? ei[2 * i] : ei[i];
}
__device__ __forceinline__ int load_dst(const int* ei, int e, bool is64, int i) {
    return is64 ? ei[2 * e + 2 * i] : ei[e + i];
}

// ---------------- pass 1: per-bucket edge counts ----------------

__global__ __launch_bounds__(256) void bin_count(const int* __restrict__ ei, int e,
                                                 const int* __restrict__ flag, int shift,
                                                 int* __restrict__ gcnt) {
    __shared__ int h[MAXB];
    for (int i = threadIdx.x; i < MAXB; i += 256) h[i] = 0;
    __syncthreads();
    bool is64 = (*flag == 0);
    int stride = gridDim.x * 256;
    for (int i = blockIdx.x * 256 + threadIdx.x; i < e; i += stride) {
        int d = load_dst(ei, e, is64, i);
        atomicAdd(&h[d >> shift], 1);
    }
    __syncthreads();
    for (int i = threadIdx.x; i < MAXB; i += 256)
        if (h[i]) atomicAdd(&gcnt[i], h[i]);
}

// ---------------- pass 2: scan bucket counts -> base, init gcursor ----------------

__global__ void bin_scan_init(const int* __restrict__ gcnt, int nb,
                              int* __restrict__ base, int* __restrict__ gcursor) {
    __shared__ int sh[1024];
    int t = threadIdx.x;
    int v = (t < nb) ? gcnt[t] : 0;
    sh[t] = v;
    __syncthreads();
    for (int off = 1; off < 1024; off <<= 1) {
        int x = (t >= off) ? sh[t - off] : 0;
        __syncthreads();
        sh[t] += x;
        __syncthreads();
    }
    if (t < nb) {
        int excl = sh[t] - v;
        base[t] = excl;
        gcursor[t] = excl;
        if (t == nb - 1) base[nb] = sh[t];
    }
}

// ---------------- pass 3: tile counting-sort scatter into buckets ----------------

__global__ __launch_bounds__(SCAT_T) void bin_scatter(const int* __restrict__ ei, int e,
                                                      const int* __restrict__ flag, int shift,
                                                      int* __restrict__ gcursor,
                                                      unsigned int* __restrict__ gpk) {
    __shared__ int hist[MAXB];
    __shared__ int lbase[MAXB];
    __shared__ int gbase[MAXB];
    __shared__ int cur[MAXB];
    __shared__ unsigned int sbuf[TILE];
    __shared__ unsigned short sbkt[TILE];
    __shared__ int sh[SCAT_T];

    const int t = threadIdx.x;
    const int mask = (1 << shift) - 1;
    const bool is64 = (*flag == 0);
    const int tile0 = blockIdx.x * TILE;
    const int cnt = min(TILE, e - tile0);

    for (int i = t; i < MAXB; i += SCAT_T) hist[i] = 0;
    __syncthreads();

    unsigned int pk[EPT];
    int bk[EPT];
#pragma unroll
    for (int k = 0; k < EPT; k++) {
        int g = tile0 + k * SCAT_T + t;
        bk[k] = -1;
        if (g < e) {
            int s = load_src(ei, e, is64, g);
            int d = load_dst(ei, e, is64, g);
            int b = d >> shift;
            pk[k] = ((unsigned int)s << shift) | (unsigned int)(d & mask);
            bk[k] = b;
            atomicAdd(&hist[b], 1);
        }
    }
    __syncthreads();

    {
        int h0 = hist[2 * t];
        int h1 = hist[2 * t + 1];
        int s = h0 + h1;
        sh[t] = s;
        __syncthreads();
        for (int off = 1; off < SCAT_T; off <<= 1) {
            int x = (t >= off) ? sh[t - off] : 0;
            __syncthreads();
            sh[t] += x;
            __syncthreads();
        }
        int excl = sh[t] - s;
        lbase[2 * t] = excl;
        lbase[2 * t + 1] = excl + h0;
    }
    __syncthreads();

    for (int i = t; i < MAXB; i += SCAT_T) {
        int c = hist[i];
        if (c > 0) gbase[i] = atomicAdd(&gcursor[i], c);
        cur[i] = lbase[i];
    }
    __syncthreads();

#pragma unroll
    for (int k = 0; k < EPT; k++) {
        if (bk[k] >= 0) {
            int p = atomicAdd(&cur[bk[k]], 1);
            sbuf[p] = pk[k];
            sbkt[p] = (unsigned short)bk[k];
        }
    }
    __syncthreads();

    for (int i = t; i < cnt; i += SCAT_T) {
        int b = sbkt[i];
        gpk[gbase[b] + (i - lbase[b])] = sbuf[i];
    }
}

// ---------------- pass 4: per-bucket degree + dinv (coalesced) ----------------

__global__ __launch_bounds__(256) void bucket_deg(const unsigned int* __restrict__ gpk,
                                                  const int* __restrict__ base, int shift,
                                                  int n, int* __restrict__ deg,
                                                  float* __restrict__ dinv) {
    __shared__ int dc[MAXB];
    int b = blockIdx.x;
    int mask = (1 << shift) - 1;
    int node0 = b << shift;
    int nc = min(1 << shift, n - node0);
    for (int i = threadIdx.x; i < (1 << shift); i += 256) dc[i] = 0;
    __syncthreads();
    int lo = base[b], hi = base[b + 1];
    for (int j = lo + threadIdx.x; j < hi; j += 256)
        atomicAdd(&dc[gpk[j] & mask], 1);
    __syncthreads();
    for (int i = threadIdx.x; i < nc; i += 256) {
        int d = dc[i];
        deg[node0 + i] = d;
        dinv[node0 + i] = rsqrtf(1.0f + (float)d);
    }
}

// ---------------- row_ptr scan over deg ----------------

__global__ void scan_partial(const int* __restrict__ deg, int* __restrict__ out,
                             int* __restrict__ bsums, int n) {
    __shared__ int sh[256];
    int t = threadIdx.x;
    int base = blockIdx.x * 1024 + t * 4;
    int v0 = 0, v1 = 0, v2 = 0, v3 = 0;
    if (base + 0 < n) v0 = deg[base + 0];
    if (base + 1 < n) v1 = deg[base + 1];
    if (base + 2 < n) v2 = deg[base + 2];
    if (base + 3 < n) v3 = deg[base + 3];
    int s = v0 + v1 + v2 + v3;
    sh[t] = s;
    __syncthreads();
    for (int off = 1; off < 256; off <<= 1) {
        int x = (t >= off) ? sh[t - off] : 0;
        __syncthreads();
        sh[t] += x;
        __syncthreads();
    }
    int excl = sh[t] - s;
    if (base + 0 < n) out[base + 0] = excl;  excl += v0;
    if (base + 1 < n) out[base + 1] = excl;  excl += v1;
    if (base + 2 < n) out[base + 2] = excl;  excl += v2;
    if (base + 3 < n) out[base + 3] = excl;
    if (t == 255) bsums[blockIdx.x] = sh[255];
}

__global__ void scan_bsums(int* bsums, int nb) {
    __shared__ int sh[1024];
    int t = threadIdx.x;
    sh[t] = (t < nb) ? bsums[t] : 0;
    __syncthreads();
    for (int off = 1; off < 1024; off <<= 1) {
        int x = (t >= off) ? sh[t - off] : 0;
        __syncthreads();
        sh[t] += x;
        __syncthreads();
    }
    if (t < nb) bsums[t] = sh[t];
}

__global__ void scan_add(int* __restrict__ row_ptr, const int* __restrict__ bsums,
                         int n, int nb) {
    int i = blockIdx.x * blockDim.x + threadIdx.x;
    if (i < n) {
        int b = i >> 10;
        if (b > 0) row_ptr[i] += bsums[b - 1];
    } else if (i == n) {
        row_ptr[n] = bsums[nb - 1];
    }
}

// ---------------- pass 5: per-bucket exact CSR build in LDS ----------------

__global__ __launch_bounds__(256) void bucket_csr(const unsigned int* __restrict__ gpk,
                                                  const int* __restrict__ base,
                                                  const int* __restrict__ row_ptr, int shift,
                                                  int n, int* __restrict__ col) {
    __shared__ int lcol[LCAP];
    __shared__ int cur[MAXB];
    int b = blockIdx.x;
    int mask = (1 << shift) - 1;
    int node0 = b << shift;
    int nc = min(1 << shift, n - node0);
    int rstart = row_ptr[node0];
    for (int i = threadIdx.x; i < nc; i += 256)
        cur[i] = row_ptr[node0 + i] - rstart;
    __syncthreads();
    int lo = base[b], hi = base[b + 1];
    int ecnt = hi - lo;
    if (ecnt <= LCAP) {
        for (int j = lo + threadIdx.x; j < hi; j += 256) {
            unsigned int v = gpk[j];
            int p = atomicAdd(&cur[v & mask], 1);
            lcol[p] = (int)(v >> shift);
        }
        __syncthreads();
        for (int j = threadIdx.x; j < ecnt; j += 256)
            col[rstart + j] = lcol[j];
    } else {
        for (int j = lo + threadIdx.x; j < hi; j += 256) {
            unsigned int v = gpk[j];
            int p = atomicAdd(&cur[v & mask], 1);
            col[rstart + p] = (int)(v >> shift);
        }
    }
}

// ---------------- Fused dual-output GEMM ----------------
// out1[n,CO1] = (A@W1)*dinv  -> packed fp16 (gather table)
// out2[n,CO2] = A@W2         -> fp32 (skip buffer), CO2 == CO1/2 or 0
// One pass over A serves both products (R8: x and h1 were each streamed
// twice). k-loop uses an explicit depth-2 register pipeline (cur/nxt rotate)
// so ~8 A-loads stay in flight per thread (R8 gemm was latency-bound: 160 us,
// VALUBusy 25%, hbm 6%). TR=4 rows x 4(+2) cols per thread; plain
// launch_bounds(256) (R6's min-waves clamped VGPR to 64 and spilled).

template <int CI, int CO1, int CO2>
__global__ __launch_bounds__(256) void gemm_fused(const float* __restrict__ A,
                                                  const float* __restrict__ W1g,
                                                  const float* __restrict__ W2g,
                                                  const float* __restrict__ dinv,
                                                  unsigned int* __restrict__ out1,
                                                  float* __restrict__ out2, int n) {
    constexpr int CT = CO1 / 4;       // threads covering CO1 (4 cols each)
    constexpr int RG = 256 / CT;      // row-groups per block
    constexpr int TR = 4;             // rows per thread
    constexpr int BR = RG * TR;       // rows per block
    __shared__ __align__(16) float Wl1[CI * CO1];
    __shared__ __align__(16) float Wl2[CO2 > 0 ? CI * CO2 : 4];
    for (int i = threadIdx.x; i < CI * CO1; i += 256) Wl1[i] = W1g[i];
    if (CO2 > 0)
        for (int i = threadIdx.x; i < CI * CO2; i += 256) Wl2[i] = W2g[i];
    __syncthreads();

    const int ct = threadIdx.x % CT;
    const int rg = threadIdx.x / CT;
    const int row0 = blockIdx.x * BR + rg * TR;

    float acc1[TR][4] = {{0.f}};
    float acc2[TR][2] = {{0.f}};

    auto loadA = [&](float4* buf, int k) {
#pragma unroll
        for (int r = 0; r < TR; r++) {
            int row = row0 + r;
            buf[r] = (row < n) ? *reinterpret_cast<const float4*>(&A[(size_t)row * CI + k])
                               : float4{0.f, 0.f, 0.f, 0.f};
        }
    };
    auto fmaStep = [&](const float4* buf, int k) {
#pragma unroll
        for (int kk = 0; kk < 4; kk++) {
            float4 w1 = *reinterpret_cast<const float4*>(&Wl1[(k + kk) * CO1 + ct * 4]);
            float2 w2{0.f, 0.f};
            if (CO2 > 0) w2 = *reinterpret_cast<const float2*>(&Wl2[(k + kk) * CO2 + ct * 2]);
#pragma unroll
            for (int r = 0; r < TR; r++) {
                float av = (kk == 0) ? buf[r].x : (kk == 1) ? buf[r].y
                         : (kk == 2) ? buf[r].z : buf[r].w;
                acc1[r][0] += av * w1.x;
                acc1[r][1] += av * w1.y;
                acc1[r][2] += av * w1.z;
                acc1[r][3] += av * w1.w;
                if (CO2 > 0) {
                    acc2[r][0] += av * w2.x;
                    acc2[r][1] += av * w2.y;
                }
            }
        }
    };

    float4 cur[TR], nxt[TR] = {};
    loadA(cur, 0);
#pragma unroll 2
    for (int k = 0; k < CI; k += 4) {
        if (k + 4 < CI) loadA(nxt, k + 4);   // issue next step's loads early
        fmaStep(cur, k);
#pragma unroll
        for (int r = 0; r < TR; r++) cur[r] = nxt[r];
    }

#pragma unroll
    for (int r = 0; r < TR; r++) {
        int row = row0 + r;
        if (row >= n) continue;
        float s = dinv[row];
        uint2 pk{pack_f16(acc1[r][0] * s, acc1[r][1] * s),
                 pack_f16(acc1[r][2] * s, acc1[r][3] * s)};
        *reinterpret_cast<uint2*>(&out1[(size_t)row * (CO1 / 2) + ct * 2]) = pk;
        if (CO2 > 0) {
            float2 v{acc2[r][0], acc2[r][1]};
            *reinterpret_cast<float2*>(&out2[(size_t)row * CO2 + ct * 2]) = v;
        }
    }
}

// ---------------- Fused gather (fp16 table, uint4 loads) + self-loop + bias + skip + relu ----
// ONE WAVE PER NODE; grid = cdiv(n,4) with 256-thread blocks.
// Each lane loads 16 B (uint4 = 8 fp16 feats); edge needs L = F/8 lanes;
// EPW = 64/L edges in flight per pass, 4x unrolled.

template <int F>
__global__ __launch_bounds__(256) void gather_combine(
    const uint4* __restrict__ hp4, const int* __restrict__ row_ptr,
    const int* __restrict__ col, const float* __restrict__ dinv,
    const float* __restrict__ bias, const float* __restrict__ sk,
    const float* __restrict__ bsk, float* __restrict__ out, int n) {
    constexpr int L = F / 8;      // lanes per edge; also uint4 words per row
    constexpr int EPW = 64 / L;   // edges concurrently per wave-pass
    int wid = (blockIdx.x * blockDim.x + threadIdx.x) >> 6;
    int lane = threadIdx.x & 63;
    if (wid >= n) return;
    int s = lane / L;             // edge slot
    int el = lane % L;            // feat octet within row
    int start = row_ptr[wid];
    int end = row_ptr[wid + 1];

    float a[8] = {0.f, 0.f, 0.f, 0.f, 0.f, 0.f, 0.f, 0.f};
    int j = start + s;
    while (j + 3 * EPW < end) {   // 4 independent load chains
        int c0 = col[j];
        int c1 = col[j + EPW];
        int c2 = col[j + 2 * EPW];
        int c3 = col[j + 3 * EPW];
        uint4 u0 = hp4[(size_t)c0 * L + el];
        uint4 u1 = hp4[(size_t)c1 * L + el];
        uint4 u2 = hp4[(size_t)c2 * L + el];
        uint4 u3 = hp4[(size_t)c3 * L + el];
        acc8(a, u0); acc8(a, u1); acc8(a, u2); acc8(a, u3);
        j += 4 * EPW;
    }
    while (j < end) {
        uint4 u = hp4[(size_t)col[j] * L + el];
        acc8(a, u);
        j += EPW;
    }

    // reduce across edge slots (lanes with same el)
#pragma unroll
    for (int m = L; m < 64; m <<= 1) {
#pragma unroll
        for (int q = 0; q < 8; q++) a[q] += __shfl_xor(a[q], m);
    }

    if (lane < L) {
        float dn = dinv[wid];
        uint4 us = hp4[(size_t)wid * L + el];
        float v[8];
        unpack8(us, v);
        float4 b0 = *reinterpret_cast<const float4*>(&bias[8 * el]);
        float4 b1 = *reinterpret_cast<const float4*>(&bias[8 * el + 4]);
        float o[8];
        o[0] = dn * a[0] + v[0] * dn + b0.x;
        o[1] = dn * a[1] + v[1] * dn + b0.y;
        o[2] = dn * a[2] + v[2] * dn + b0.z;
        o[3] = dn * a[3] + v[3] * dn + b0.w;
        o[4] = dn * a[4] + v[4] * dn + b1.x;
        o[5] = dn * a[5] + v[5] * dn + b1.y;
        o[6] = dn * a[6] + v[6] * dn + b1.z;
        o[7] = dn * a[7] + v[7] * dn + b1.w;
        if (sk) {
            float4 s0 = *reinterpret_cast<const float4*>(&sk[(size_t)wid * F + 8 * el]);
            float4 s1 = *reinterpret_cast<const float4*>(&sk[(size_t)wid * F + 8 * el + 4]);
            float4 k0 = *reinterpret_cast<const float4*>(&bsk[8 * el]);
            float4 k1 = *reinterpret_cast<const float4*>(&bsk[8 * el + 4]);
            o[0] += s0.x + k0.x; o[1] += s0.y + k0.y;
            o[2] += s0.z + k0.z; o[3] += s0.w + k0.w;
            o[4] += s1.x + k1.x; o[5] += s1.y + k1.y;
            o[6] += s1.z + k1.z; o[7] += s1.w + k1.w;
        }
        float4 w0{fmaxf(o[0], 0.f), fmaxf(o[1], 0.f), fmaxf(o[2], 0.f), fmaxf(o[3], 0.f)};
        float4 w1{fmaxf(o[4], 0.f), fmaxf(o[5], 0.f), fmaxf(o[6], 0.f), fmaxf(o[7], 0.f)};
        *reinterpret_cast<float4*>(&out[(size_t)wid * F + 8 * el]) = w0;
        *reinterpret_cast<float4*>(&out[(size_t)wid * F + 8 * el + 4]) = w1;
    }
}

// ---------------- Final: out[n] = sigmoid(h3[n,:16] @ Wlin + blin) ----------------

__global__ void final_kernel(const float* __restrict__ h3, const float* __restrict__ Wlin,
                             const float* __restrict__ blin, float* __restrict__ out, int n) {
    int i = blockIdx.x * blockDim.x + threadIdx.x;
    if (i >= n) return;
    float s = blin[0];
#pragma unroll
    for (int f = 0; f < 16; f++) s += h3[i * 16 + f] * Wlin[f];
    out[i] = 1.0f / (1.0f + expf(-s));
}

// ---------------- launch ----------------

extern "C" void kernel_launch(void* const* d_in, const int* in_sizes, int n_in,
                              void* d_out, int out_size, void* d_ws, size_t ws_size,
                              hipStream_t stream) {
    const float* x     = (const float*)d_in[0];
    const int*   ei    = (const int*)d_in[1];
    const float* W1    = (const float*)d_in[2];
    const float* b1    = (const float*)d_in[3];
    const float* W2    = (const float*)d_in[4];
    const float* b2    = (const float*)d_in[5];
    const float* W3    = (const float*)d_in[6];
    const float* b3    = (const float*)d_in[7];
    const float* Wsk02 = (const float*)d_in[8];
    const float* bsk02 = (const float*)d_in[9];
    const float* Wsk13 = (const float*)d_in[10];
    const float* bsk13 = (const float*)d_in[11];
    const float* Wlin  = (const float*)d_in[12];
    const float* blin  = (const float*)d_in[13];

    const int n = in_sizes[0] / 128;
    const int e = in_sizes[1] / 2;

    int shift = 8;
    while (((n + (1 << shift) - 1) >> shift) > MAXB) shift++;
    const int nbkt = (n + (1 << shift) - 1) >> shift;

    // workspace carve (256B aligned)
    char* p = (char*)d_ws;
    auto alloc = [&](size_t bytes) {
        void* r = (void*)p;
        p += (bytes + 255) / 256 * 256;
        return r;
    };
    int*   flag    = (int*)alloc(256);
    int*   gcnt    = (int*)alloc(MAXB * 4);
    int*   base    = (int*)alloc((MAXB + 1) * 4);
    int*   gcursor = (int*)alloc(MAXB * 4);
    int*   bsums   = (int*)alloc(4096);
    int*   deg     = (int*)alloc((size_t)n * 4);
    int*   row_ptr = (int*)alloc((size_t)(n + 1) * 4);
    float* dinv    = (float*)alloc((size_t)n * 4);
    int*   col     = (int*)alloc((size_t)e * 4);
    float* h1      = (float*)alloc((size_t)n * 64 * 4);
    float* h2      = (float*)alloc((size_t)n * 32 * 4);
    float* h3      = (float*)alloc((size_t)n * 16 * 4);
    float* sk02    = (float*)alloc((size_t)n * 32 * 4);              // x@Wsk02 (fp32)
    float* sk13    = (float*)alloc((size_t)n * 16 * 4);              // h1@Wsk13 (fp32)
    size_t prebytes = (size_t)(e > n * 32 ? e : n * 32) * 4;
    unsigned int* preb = (unsigned int*)alloc(prebytes);             // fp16-packed gather table
    unsigned int* gpk  = preb;  // bucketed packed edges; dead before fusedA writes preb

    auto cdiv = [](int a, int b) { return (a + b - 1) / b; };

    // CSR build
    hipMemsetAsync(flag, 0, 4, stream);
    hipMemsetAsync(gcnt, 0, MAXB * 4, stream);
    detect_kernel<<<1, 1024, 0, stream>>>(ei, flag);
    bin_count<<<1024, 256, 0, stream>>>(ei, e, flag, shift, gcnt);
    bin_scan_init<<<1, 1024, 0, stream>>>(gcnt, nbkt, base, gcursor);
    bin_scatter<<<cdiv(e, TILE), SCAT_T, 0, stream>>>(ei, e, flag, shift, gcursor, gpk);
    bucket_deg<<<nbkt, 256, 0, stream>>>(gpk, base, shift, n, deg, dinv);
    scan_partial<<<cdiv(n, 1024), 256, 0, stream>>>(deg, row_ptr, bsums, n);
    scan_bsums<<<1, 1024, 0, stream>>>(bsums, cdiv(n, 1024));
    scan_add<<<cdiv(n + 1, 256), 256, 0, stream>>>(row_ptr, bsums, n, cdiv(n, 1024));
    bucket_csr<<<nbkt, 256, 0, stream>>>(gpk, base, row_ptr, shift, n, col);

    // fused GEMM A: preb = (x@W1)*dinv (fp16), sk02 = x@Wsk02 (fp32) — x read once
    gemm_fused<128, 64, 32><<<cdiv(n, 64), 256, 0, stream>>>(x, W1, Wsk02, dinv,
                                                             preb, sk02, n);
    // layer 1 aggregate: h1 = relu(conv(x, W1, b1))
    gather_combine<64><<<cdiv(n, 4), 256, 0, stream>>>((const uint4*)preb, row_ptr, col, dinv,
                                                       b1, nullptr, nullptr, h1, n);

    // fused GEMM B: preb = (h1@W2)*dinv (fp16), sk13 = h1@Wsk13 (fp32) — h1 read once
    gemm_fused<64, 32, 16><<<cdiv(n, 128), 256, 0, stream>>>(h1, W2, Wsk13, dinv,
                                                             preb, sk13, n);
    // layer 2 aggregate: h2 = relu(conv(h1, W2, b2) + x@Wsk02 + bsk02)
    gather_combine<32><<<cdiv(n, 4), 256, 0, stream>>>((const uint4*)preb, row_ptr, col, dinv,
                                                       b2, sk02, bsk02, h2, n);

    // GEMM C: preb = (h2@W3)*dinv (fp16)
    gemm_fused<32, 16, 0><<<cdiv(n, 256), 256, 0, stream>>>(h2, W3, nullptr, dinv,
                                                            preb, nullptr, n);
    // layer 3 aggregate: h3 = relu(conv(h2, W3, b3) + h1@Wsk13 + bsk13)
    gather_combine<16><<<cdiv(n, 4), 256, 0, stream>>>((const uint4*)preb, row_ptr, col, dinv,
                                                       b3, sk13, bsk13, h3, n);

    // final
    final_kernel<<<cdiv(n, 256), 256, 0, stream>>>(h3, Wlin, blin, (float*)d_out, n);
}

// Round 10
// 637.923 us; speedup vs baseline: 3.3871x; 1.0020x over previous
//
#include <hip/hip_runtime.h>
#include <hip/hip_fp16.h>
#include <math.h>

// Tunables for the bucketed CSR build.
#define MAXB 1024        // max buckets supported by LDS arrays
#define TILE 4096        // edges per bin_scatter tile
#define SCAT_T 512       // threads in bin_scatter block
#define EPT (TILE / SCAT_T)
#define LCAP 14336       // bucket_csr LDS col capacity (56KB)

// ---------------- fp16 pack helpers ----------------

__device__ __forceinline__ unsigned int pack_f16(float a, float b) {
    __half2 h = __floats2half2_rn(a, b);
    return *reinterpret_cast<unsigned int*>(&h);
}
__device__ __forceinline__ float f16_lo(unsigned int u) {
    __half2 h = *reinterpret_cast<__half2*>(&u);
    return __low2float(h);
}
__device__ __forceinline__ float f16_hi(unsigned int u) {
    __half2 h = *reinterpret_cast<__half2*>(&u);
    return __high2float(h);
}
// accumulate 8 fp16 (one uint4) into a[8]
__device__ __forceinline__ void acc8(float* a, uint4 u) {
    a[0] += f16_lo(u.x); a[1] += f16_hi(u.x);
    a[2] += f16_lo(u.y); a[3] += f16_hi(u.y);
    a[4] += f16_lo(u.z); a[5] += f16_hi(u.z);
    a[6] += f16_lo(u.w); a[7] += f16_hi(u.w);
}
__device__ __forceinline__ void unpack8(uint4 u, float* v) {
    v[0] = f16_lo(u.x); v[1] = f16_hi(u.x);
    v[2] = f16_lo(u.y); v[3] = f16_hi(u.y);
    v[4] = f16_lo(u.z); v[5] = f16_hi(u.z);
    v[6] = f16_lo(u.w); v[7] = f16_hi(u.w);
}

// ---------------- edge dtype detection (int32 vs int64) ----------------

__global__ void detect_kernel(const int* __restrict__ ei, int* __restrict__ flag) {
    int i = threadIdx.x;  // one block of 1024
    if (ei[2 * i + 1] != 0) atomicAdd(flag, 1);
}

__device__ __forceinline__ int load_src(const int* ei, int e, bool is64, int i) {
    return is64 ? ei[2 * i] : ei[i];
}
__device__ __forceinline__ int load_dst(const int* ei, int e, bool is64, int i) {
    return is64 ? ei[2 * e + 2 * i] : ei[e + i];
}

// ---------------- pass 1: per-bucket edge counts ----------------

__global__ __launch_bounds__(256) void bin_count(const int* __restrict__ ei, int e,
                                                 const int* __restrict__ flag, int shift,
                                                 int* __restrict__ gcnt) {
    __shared__ int h[MAXB];
    for (int i = threadIdx.x; i < MAXB; i += 256) h[i] = 0;
    __syncthreads();
    bool is64 = (*flag == 0);
    int stride = gridDim.x * 256;
    for (int i = blockIdx.x * 256 + threadIdx.x; i < e; i += stride) {
        int d = load_dst(ei, e, is64, i);
        atomicAdd(&h[d >> shift], 1);
    }
    __syncthreads();
    for (int i = threadIdx.x; i < MAXB; i += 256)
        if (h[i]) atomicAdd(&gcnt[i], h[i]);
}

// ---------------- pass 2: scan bucket counts -> base, init gcursor ----------------

__global__ void bin_scan_init(const int* __restrict__ gcnt, int nb,
                              int* __restrict__ base, int* __restrict__ gcursor) {
    __shared__ int sh[1024];
    int t = threadIdx.x;
    int v = (t < nb) ? gcnt[t] : 0;
    sh[t] = v;
    __syncthreads();
    for (int off = 1; off < 1024; off <<= 1) {
        int x = (t >= off) ? sh[t - off] : 0;
        __syncthreads();
        sh[t] += x;
        __syncthreads();
    }
    if (t < nb) {
        int excl = sh[t] - v;
        base[t] = excl;
        gcursor[t] = excl;
        if (t == nb - 1) base[nb] = sh[t];
    }
}

// ---------------- pass 3: tile counting-sort scatter into buckets ----------------

__global__ __launch_bounds__(SCAT_T) void bin_scatter(const int* __restrict__ ei, int e,
                                                      const int* __restrict__ flag, int shift,
                                                      int* __restrict__ gcursor,
                                                      unsigned int* __restrict__ gpk) {
    __shared__ int hist[MAXB];
    __shared__ int lbase[MAXB];
    __shared__ int gbase[MAXB];
    __shared__ int cur[MAXB];
    __shared__ unsigned int sbuf[TILE];
    __shared__ unsigned short sbkt[TILE];
    __shared__ int sh[SCAT_T];

    const int t = threadIdx.x;
    const int mask = (1 << shift) - 1;
    const bool is64 = (*flag == 0);
    const int tile0 = blockIdx.x * TILE;
    const int cnt = min(TILE, e - tile0);

    for (int i = t; i < MAXB; i += SCAT_T) hist[i] = 0;
    __syncthreads();

    unsigned int pk[EPT];
    int bk[EPT];
#pragma unroll
    for (int k = 0; k < EPT; k++) {
        int g = tile0 + k * SCAT_T + t;
        bk[k] = -1;
        if (g < e) {
            int s = load_src(ei, e, is64, g);
            int d = load_dst(ei, e, is64, g);
            int b = d >> shift;
            pk[k] = ((unsigned int)s << shift) | (unsigned int)(d & mask);
            bk[k] = b;
            atomicAdd(&hist[b], 1);
        }
    }
    __syncthreads();

    {
        int h0 = hist[2 * t];
        int h1 = hist[2 * t + 1];
        int s = h0 + h1;
        sh[t] = s;
        __syncthreads();
        for (int off = 1; off < SCAT_T; off <<= 1) {
            int x = (t >= off) ? sh[t - off] : 0;
            __syncthreads();
            sh[t] += x;
            __syncthreads();
        }
        int excl = sh[t] - s;
        lbase[2 * t] = excl;
        lbase[2 * t + 1] = excl + h0;
    }
    __syncthreads();

    for (int i = t; i < MAXB; i += SCAT_T) {
        int c = hist[i];
        if (c > 0) gbase[i] = atomicAdd(&gcursor[i], c);
        cur[i] = lbase[i];
    }
    __syncthreads();

#pragma unroll
    for (int k = 0; k < EPT; k++) {
        if (bk[k] >= 0) {
            int p = atomicAdd(&cur[bk[k]], 1);
            sbuf[p] = pk[k];
            sbkt[p] = (unsigned short)bk[k];
        }
    }
    __syncthreads();

    for (int i = t; i < cnt; i += SCAT_T) {
        int b = sbkt[i];
        gpk[gbase[b] + (i - lbase[b])] = sbuf[i];
    }
}

// ---------------- pass 4: per-bucket degree + dinv (coalesced) ----------------

__global__ __launch_bounds__(256) void bucket_deg(const unsigned int* __restrict__ gpk,
                                                  const int* __restrict__ base, int shift,
                                                  int n, int* __restrict__ deg,
                                                  float* __restrict__ dinv) {
    __shared__ int dc[MAXB];
    int b = blockIdx.x;
    int mask = (1 << shift) - 1;
    int node0 = b << shift;
    int nc = min(1 << shift, n - node0);
    for (int i = threadIdx.x; i < (1 << shift); i += 256) dc[i] = 0;
    __syncthreads();
    int lo = base[b], hi = base[b + 1];
    for (int j = lo + threadIdx.x; j < hi; j += 256)
        atomicAdd(&dc[gpk[j] & mask], 1);
    __syncthreads();
    for (int i = threadIdx.x; i < nc; i += 256) {
        int d = dc[i];
        deg[node0 + i] = d;
        dinv[node0 + i] = rsqrtf(1.0f + (float)d);
    }
}

// ---------------- row_ptr scan over deg ----------------

__global__ void scan_partial(const int* __restrict__ deg, int* __restrict__ out,
                             int* __restrict__ bsums, int n) {
    __shared__ int sh[256];
    int t = threadIdx.x;
    int base = blockIdx.x * 1024 + t * 4;
    int v0 = 0, v1 = 0, v2 = 0, v3 = 0;
    if (base + 0 < n) v0 = deg[base + 0];
    if (base + 1 < n) v1 = deg[base + 1];
    if (base + 2 < n) v2 = deg[base + 2];
    if (base + 3 < n) v3 = deg[base + 3];
    int s = v0 + v1 + v2 + v3;
    sh[t] = s;
    __syncthreads();
    for (int off = 1; off < 256; off <<= 1) {
        int x = (t >= off) ? sh[t - off] : 0;
        __syncthreads();
        sh[t] += x;
        __syncthreads();
    }
    int excl = sh[t] - s;
    if (base + 0 < n) out[base + 0] = excl;  excl += v0;
    if (base + 1 < n) out[base + 1] = excl;  excl += v1;
    if (base + 2 < n) out[base + 2] = excl;  excl += v2;
    if (base + 3 < n) out[base + 3] = excl;
    if (t == 255) bsums[blockIdx.x] = sh[255];
}

__global__ void scan_bsums(int* bsums, int nb) {
    __shared__ int sh[1024];
    int t = threadIdx.x;
    sh[t] = (t < nb) ? bsums[t] : 0;
    __syncthreads();
    for (int off = 1; off < 1024; off <<= 1) {
        int x = (t >= off) ? sh[t - off] : 0;
        __syncthreads();
        sh[t] += x;
        __syncthreads();
    }
    if (t < nb) bsums[t] = sh[t];
}

__global__ void scan_add(int* __restrict__ row_ptr, const int* __restrict__ bsums,
                         int n, int nb) {
    int i = blockIdx.x * blockDim.x + threadIdx.x;
    if (i < n) {
        int b = i >> 10;
        if (b > 0) row_ptr[i] += bsums[b - 1];
    } else if (i == n) {
        row_ptr[n] = bsums[nb - 1];
    }
}

// ---------------- pass 5: per-bucket exact CSR build in LDS ----------------

__global__ __launch_bounds__(256) void bucket_csr(const unsigned int* __restrict__ gpk,
                                                  const int* __restrict__ base,
                                                  const int* __restrict__ row_ptr, int shift,
                                                  int n, int* __restrict__ col) {
    __shared__ int lcol[LCAP];
    __shared__ int cur[MAXB];
    int b = blockIdx.x;
    int mask = (1 << shift) - 1;
    int node0 = b << shift;
    int nc = min(1 << shift, n - node0);
    int rstart = row_ptr[node0];
    for (int i = threadIdx.x; i < nc; i += 256)
        cur[i] = row_ptr[node0 + i] - rstart;
    __syncthreads();
    int lo = base[b], hi = base[b + 1];
    int ecnt = hi - lo;
    if (ecnt <= LCAP) {
        for (int j = lo + threadIdx.x; j < hi; j += 256) {
            unsigned int v = gpk[j];
            int p = atomicAdd(&cur[v & mask], 1);
            lcol[p] = (int)(v >> shift);
        }
        __syncthreads();
        for (int j = threadIdx.x; j < ecnt; j += 256)
            col[rstart + j] = lcol[j];
    } else {
        for (int j = lo + threadIdx.x; j < hi; j += 256) {
            unsigned int v = gpk[j];
            int p = atomicAdd(&cur[v & mask], 1);
            col[rstart + p] = (int)(v >> shift);
        }
    }
}

// ---------------- Fused dual-output GEMM ----------------
// out1[n,CO1] = (A@W1)*dinv  -> packed fp16 (gather table)
// out2[n,CO2] = A@W2         -> fp32 (skip buffer), CO2 == CO1/2 or 0
// R10: THREADS=512 -> same 48KB LDS now hosts 8 waves/block: 3 blocks/CU =
// 24 waves/CU (R9 @256thr was 12 waves/CU, 28% occupancy, latency-exposed).
// Depth-2 register pipeline in k-loop; TR=4 rows/thread (R5/R6: bigger tiles
// or min-waves bounds spill).

template <int THREADS, int CI, int CO1, int CO2>
__global__ __launch_bounds__(THREADS) void gemm_fused(const float* __restrict__ A,
                                                      const float* __restrict__ W1g,
                                                      const float* __restrict__ W2g,
                                                      const float* __restrict__ dinv,
                                                      unsigned int* __restrict__ out1,
                                                      float* __restrict__ out2, int n) {
    constexpr int CT = CO1 / 4;       // threads covering CO1 (4 cols each)
    constexpr int RG = THREADS / CT;  // row-groups per block
    constexpr int TR = 4;             // rows per thread
    constexpr int BR = RG * TR;       // rows per block
    __shared__ __align__(16) float Wl1[CI * CO1];
    __shared__ __align__(16) float Wl2[CO2 > 0 ? CI * CO2 : 4];
    for (int i = threadIdx.x; i < CI * CO1; i += THREADS) Wl1[i] = W1g[i];
    if (CO2 > 0)
        for (int i = threadIdx.x; i < CI * CO2; i += THREADS) Wl2[i] = W2g[i];
    __syncthreads();

    const int ct = threadIdx.x % CT;
    const int rg = threadIdx.x / CT;
    const int row0 = blockIdx.x * BR + rg * TR;

    float acc1[TR][4] = {{0.f}};
    float acc2[TR][2] = {{0.f}};

    auto loadA = [&](float4* buf, int k) {
#pragma unroll
        for (int r = 0; r < TR; r++) {
            int row = row0 + r;
            buf[r] = (row < n) ? *reinterpret_cast<const float4*>(&A[(size_t)row * CI + k])
                               : float4{0.f, 0.f, 0.f, 0.f};
        }
    };
    auto fmaStep = [&](const float4* buf, int k) {
#pragma unroll
        for (int kk = 0; kk < 4; kk++) {
            float4 w1 = *reinterpret_cast<const float4*>(&Wl1[(k + kk) * CO1 + ct * 4]);
            float2 w2{0.f, 0.f};
            if (CO2 > 0) w2 = *reinterpret_cast<const float2*>(&Wl2[(k + kk) * CO2 + ct * 2]);
#pragma unroll
            for (int r = 0; r < TR; r++) {
                float av = (kk == 0) ? buf[r].x : (kk == 1) ? buf[r].y
                         : (kk == 2) ? buf[r].z : buf[r].w;
                acc1[r][0] += av * w1.x;
                acc1[r][1] += av * w1.y;
                acc1[r][2] += av * w1.z;
                acc1[r][3] += av * w1.w;
                if (CO2 > 0) {
                    acc2[r][0] += av * w2.x;
                    acc2[r][1] += av * w2.y;
                }
            }
        }
    };

    float4 cur[TR], nxt[TR] = {};
    loadA(cur, 0);
#pragma unroll 2
    for (int k = 0; k < CI; k += 4) {
        if (k + 4 < CI) loadA(nxt, k + 4);   // issue next step's loads early
        fmaStep(cur, k);
#pragma unroll
        for (int r = 0; r < TR; r++) cur[r] = nxt[r];
    }

#pragma unroll
    for (int r = 0; r < TR; r++) {
        int row = row0 + r;
        if (row >= n) continue;
        float s = dinv[row];
        uint2 pk{pack_f16(acc1[r][0] * s, acc1[r][1] * s),
                 pack_f16(acc1[r][2] * s, acc1[r][3] * s)};
        *reinterpret_cast<uint2*>(&out1[(size_t)row * (CO1 / 2) + ct * 2]) = pk;
        if (CO2 > 0) {
            float2 v{acc2[r][0], acc2[r][1]};
            *reinterpret_cast<float2*>(&out2[(size_t)row * CO2 + ct * 2]) = v;
        }
    }
}

// ---------------- Fused gather (fp16 table, uint4 loads) + self-loop + bias + skip + relu ----
// ONE WAVE PER NODE; grid = cdiv(n,4) with 256-thread blocks.
// Each lane loads 16 B (uint4 = 8 fp16 feats); edge needs L = F/8 lanes;
// EPW = 64/L edges in flight per pass, 4x unrolled.
// FINAL=true (layer 3): instead of storing h3, fuse the head:
// out[wid] = sigmoid(relu(h3) @ Wlin + blin) — kills the h3 round-trip.

template <int F, bool FINAL>
__global__ __launch_bounds__(256) void gather_combine(
    const uint4* __restrict__ hp4, const int* __restrict__ row_ptr,
    const int* __restrict__ col, const float* __restrict__ dinv,
    const float* __restrict__ bias, const float* __restrict__ sk,
    const float* __restrict__ bsk, float* __restrict__ out,
    const float* __restrict__ Wlin, const float* __restrict__ blin, int n) {
    constexpr int L = F / 8;      // lanes per edge; also uint4 words per row
    constexpr int EPW = 64 / L;   // edges concurrently per wave-pass
    int wid = (blockIdx.x * blockDim.x + threadIdx.x) >> 6;
    int lane = threadIdx.x & 63;
    if (wid >= n) return;
    int s = lane / L;             // edge slot
    int el = lane % L;            // feat octet within row
    int start = row_ptr[wid];
    int end = row_ptr[wid + 1];

    float a[8] = {0.f, 0.f, 0.f, 0.f, 0.f, 0.f, 0.f, 0.f};
    int j = start + s;
    while (j + 3 * EPW < end) {   // 4 independent load chains
        int c0 = col[j];
        int c1 = col[j + EPW];
        int c2 = col[j + 2 * EPW];
        int c3 = col[j + 3 * EPW];
        uint4 u0 = hp4[(size_t)c0 * L + el];
        uint4 u1 = hp4[(size_t)c1 * L + el];
        uint4 u2 = hp4[(size_t)c2 * L + el];
        uint4 u3 = hp4[(size_t)c3 * L + el];
        acc8(a, u0); acc8(a, u1); acc8(a, u2); acc8(a, u3);
        j += 4 * EPW;
    }
    while (j < end) {
        uint4 u = hp4[(size_t)col[j] * L + el];
        acc8(a, u);
        j += EPW;
    }

    // reduce across edge slots (lanes with same el)
#pragma unroll
    for (int m = L; m < 64; m <<= 1) {
#pragma unroll
        for (int q = 0; q < 8; q++) a[q] += __shfl_xor(a[q], m);
    }

    if (lane < L) {
        float dn = dinv[wid];
        uint4 us = hp4[(size_t)wid * L + el];
        float v[8];
        unpack8(us, v);
        float4 b0 = *reinterpret_cast<const float4*>(&bias[8 * el]);
        float4 b1 = *reinterpret_cast<const float4*>(&bias[8 * el + 4]);
        float o[8];
        o[0] = dn * a[0] + v[0] * dn + b0.x;
        o[1] = dn * a[1] + v[1] * dn + b0.y;
        o[2] = dn * a[2] + v[2] * dn + b0.z;
        o[3] = dn * a[3] + v[3] * dn + b0.w;
        o[4] = dn * a[4] + v[4] * dn + b1.x;
        o[5] = dn * a[5] + v[5] * dn + b1.y;
        o[6] = dn * a[6] + v[6] * dn + b1.z;
        o[7] = dn * a[7] + v[7] * dn + b1.w;
        if (sk) {
            float4 s0 = *reinterpret_cast<const float4*>(&sk[(size_t)wid * F + 8 * el]);
            float4 s1 = *reinterpret_cast<const float4*>(&sk[(size_t)wid * F + 8 * el + 4]);
            float4 k0 = *reinterpret_cast<const float4*>(&bsk[8 * el]);
            float4 k1 = *reinterpret_cast<const float4*>(&bsk[8 * el + 4]);
            o[0] += s0.x + k0.x; o[1] += s0.y + k0.y;
            o[2] += s0.z + k0.z; o[3] += s0.w + k0.w;
            o[4] += s1.x + k1.x; o[5] += s1.y + k1.y;
            o[6] += s1.z + k1.z; o[7] += s1.w + k1.w;
        }
#pragma unroll
        for (int q = 0; q < 8; q++) o[q] = fmaxf(o[q], 0.f);
        if (FINAL) {
            // head: dot(relu(h3), Wlin) split across lanes 0 (feats 0-7) and 1 (8-15)
            float4 wl0 = *reinterpret_cast<const float4*>(&Wlin[8 * el]);
            float4 wl1 = *reinterpret_cast<const float4*>(&Wlin[8 * el + 4]);
            float d = o[0] * wl0.x + o[1] * wl0.y + o[2] * wl0.z + o[3] * wl0.w +
                      o[4] * wl1.x + o[5] * wl1.y + o[6] * wl1.z + o[7] * wl1.w;
            d += __shfl_xor(d, 1);
            if (el == 0) out[wid] = 1.0f / (1.0f + expf(-(d + blin[0])));
        } else {
            float4 w0{o[0], o[1], o[2], o[3]};
            float4 w1{o[4], o[5], o[6], o[7]};
            *reinterpret_cast<float4*>(&out[(size_t)wid * F + 8 * el]) = w0;
            *reinterpret_cast<float4*>(&out[(size_t)wid * F + 8 * el + 4]) = w1;
        }
    }
}

// ---------------- launch ----------------

extern "C" void kernel_launch(void* const* d_in, const int* in_sizes, int n_in,
                              void* d_out, int out_size, void* d_ws, size_t ws_size,
                              hipStream_t stream) {
    const float* x     = (const float*)d_in[0];
    const int*   ei    = (const int*)d_in[1];
    const float* W1    = (const float*)d_in[2];
    const float* b1    = (const float*)d_in[3];
    const float* W2    = (const float*)d_in[4];
    const float* b2    = (const float*)d_in[5];
    const float* W3    = (const float*)d_in[6];
    const float* b3    = (const float*)d_in[7];
    const float* Wsk02 = (const float*)d_in[8];
    const float* bsk02 = (const float*)d_in[9];
    const float* Wsk13 = (const float*)d_in[10];
    const float* bsk13 = (const float*)d_in[11];
    const float* Wlin  = (const float*)d_in[12];
    const float* blin  = (const float*)d_in[13];

    const int n = in_sizes[0] / 128;
    const int e = in_sizes[1] / 2;

    int shift = 8;
    while (((n + (1 << shift) - 1) >> shift) > MAXB) shift++;
    const int nbkt = (n + (1 << shift) - 1) >> shift;

    // workspace carve (256B aligned)
    char* p = (char*)d_ws;
    auto alloc = [&](size_t bytes) {
        void* r = (void*)p;
        p += (bytes + 255) / 256 * 256;
        return r;
    };
    int*   flag    = (int*)alloc(256);
    int*   gcnt    = (int*)alloc(MAXB * 4);
    int*   base    = (int*)alloc((MAXB + 1) * 4);
    int*   gcursor = (int*)alloc(MAXB * 4);
    int*   bsums   = (int*)alloc(4096);
    int*   deg     = (int*)alloc((size_t)n * 4);
    int*   row_ptr = (int*)alloc((size_t)(n + 1) * 4);
    float* dinv    = (float*)alloc((size_t)n * 4);
    int*   col     = (int*)alloc((size_t)e * 4);
    float* h1      = (float*)alloc((size_t)n * 64 * 4);
    float* h2      = (float*)alloc((size_t)n * 32 * 4);
    float* sk02    = (float*)alloc((size_t)n * 32 * 4);              // x@Wsk02 (fp32)
    float* sk13    = (float*)alloc((size_t)n * 16 * 4);              // h1@Wsk13 (fp32)
    size_t prebytes = (size_t)(e > n * 32 ? e : n * 32) * 4;
    unsigned int* preb = (unsigned int*)alloc(prebytes);             // fp16-packed gather table
    unsigned int* gpk  = preb;  // bucketed packed edges; dead before fusedA writes preb

    auto cdiv = [](int a, int b) { return (a + b - 1) / b; };

    // CSR build
    hipMemsetAsync(flag, 0, 4, stream);
    hipMemsetAsync(gcnt, 0, MAXB * 4, stream);
    detect_kernel<<<1, 1024, 0, stream>>>(ei, flag);
    bin_count<<<1024, 256, 0, stream>>>(ei, e, flag, shift, gcnt);
    bin_scan_init<<<1, 1024, 0, stream>>>(gcnt, nbkt, base, gcursor);
    bin_scatter<<<cdiv(e, TILE), SCAT_T, 0, stream>>>(ei, e, flag, shift, gcursor, gpk);
    bucket_deg<<<nbkt, 256, 0, stream>>>(gpk, base, shift, n, deg, dinv);
    scan_partial<<<cdiv(n, 1024), 256, 0, stream>>>(deg, row_ptr, bsums, n);
    scan_bsums<<<1, 1024, 0, stream>>>(bsums, cdiv(n, 1024));
    scan_add<<<cdiv(n + 1, 256), 256, 0, stream>>>(row_ptr, bsums, n, cdiv(n, 1024));
    bucket_csr<<<nbkt, 256, 0, stream>>>(gpk, base, row_ptr, shift, n, col);

    // fused GEMM A: preb = (x@W1)*dinv (fp16), sk02 = x@Wsk02 (fp32); BR = 128
    gemm_fused<512, 128, 64, 32><<<cdiv(n, 128), 512, 0, stream>>>(x, W1, Wsk02, dinv,
                                                                   preb, sk02, n);
    // layer 1 aggregate: h1 = relu(conv(x, W1, b1))
    gather_combine<64, false><<<cdiv(n, 4), 256, 0, stream>>>(
        (const uint4*)preb, row_ptr, col, dinv, b1, nullptr, nullptr, h1, nullptr, nullptr, n);

    // fused GEMM B: preb = (h1@W2)*dinv (fp16), sk13 = h1@Wsk13 (fp32); BR = 256
    gemm_fused<512, 64, 32, 16><<<cdiv(n, 256), 512, 0, stream>>>(h1, W2, Wsk13, dinv,
                                                                  preb, sk13, n);
    // layer 2 aggregate: h2 = relu(conv(h1, W2, b2) + x@Wsk02 + bsk02)
    gather_combine<32, false><<<cdiv(n, 4), 256, 0, stream>>>(
        (const uint4*)preb, row_ptr, col, dinv, b2, sk02, bsk02, h2, nullptr, nullptr, n);

    // GEMM C: preb = (h2@W3)*dinv (fp16); BR = 512
    gemm_fused<512, 32, 16, 0><<<cdiv(n, 512), 512, 0, stream>>>(h2, W3, nullptr, dinv,
                                                                 preb, nullptr, n);
    // layer 3 aggregate + head: out = sigmoid(relu(conv(h2,W3,b3)+h1@Wsk13+bsk13) @ Wlin + blin)
    gather_combine<16, true><<<cdiv(n, 4), 256, 0, stream>>>(
        (const uint4*)preb, row_ptr, col, dinv, b3, sk13, bsk13, (float*)d_out, Wlin, blin, n);
}

// Round 11
// 635.427 us; speedup vs baseline: 3.4004x; 1.0039x over previous
//
#include <hip/hip_runtime.h>
#include <hip/hip_fp16.h>
#include <math.h>

// Tunables for the bucketed CSR build.
#define MAXB 1024        // max buckets supported by LDS arrays
#define TILE 4096        // edges per bin_scatter tile
#define SCAT_T 512       // threads in bin_scatter block
#define EPT (TILE / SCAT_T)
#define LCAP 13568       // bucket_build LDS col capacity (53KB; avg bucket ~8.2k)

// ---------------- fp16 pack helpers ----------------

__device__ __forceinline__ unsigned int pack_f16(float a, float b) {
    __half2 h = __floats2half2_rn(a, b);
    return *reinterpret_cast<unsigned int*>(&h);
}
__device__ __forceinline__ float f16_lo(unsigned int u) {
    __half2 h = *reinterpret_cast<__half2*>(&u);
    return __low2float(h);
}
__device__ __forceinline__ float f16_hi(unsigned int u) {
    __half2 h = *reinterpret_cast<__half2*>(&u);
    return __high2float(h);
}
// accumulate 8 fp16 (one uint4) into a[8] (fp32)
__device__ __forceinline__ void acc8(float* a, uint4 u) {
    a[0] += f16_lo(u.x); a[1] += f16_hi(u.x);
    a[2] += f16_lo(u.y); a[3] += f16_hi(u.y);
    a[4] += f16_lo(u.z); a[5] += f16_hi(u.z);
    a[6] += f16_lo(u.w); a[7] += f16_hi(u.w);
}
__device__ __forceinline__ void unpack8(uint4 u, float* v) {
    v[0] = f16_lo(u.x); v[1] = f16_hi(u.x);
    v[2] = f16_lo(u.y); v[3] = f16_hi(u.y);
    v[4] = f16_lo(u.z); v[5] = f16_hi(u.z);
    v[6] = f16_lo(u.w); v[7] = f16_hi(u.w);
}
// packed fp16 pairwise add (v_pk_add_f16): 4 instrs for 8 feats
__device__ __forceinline__ uint4 h2add4(uint4 a, uint4 b) {
    const __half2* pa = reinterpret_cast<const __half2*>(&a);
    const __half2* pb = reinterpret_cast<const __half2*>(&b);
    uint4 r;
    __half2* pr = reinterpret_cast<__half2*>(&r);
#pragma unroll
    for (int i = 0; i < 4; i++) pr[i] = __hadd2(pa[i], pb[i]);
    return r;
}

// ---------------- edge dtype detection (int32 vs int64) ----------------

__global__ void detect_kernel(const int* __restrict__ ei, int* __restrict__ flag) {
    int i = threadIdx.x;  // one block of 1024
    if (ei[2 * i + 1] != 0) atomicAdd(flag, 1);
}

__device__ __forceinline__ int load_src(const int* ei, int e, bool is64, int i) {
    return is64 ? ei[2 * i] : ei[i];
}
__device__ __forceinline__ int load_dst(const int* ei, int e, bool is64, int i) {
    return is64 ? ei[2 * e + 2 * i] : ei[e + i];
}

// ---------------- pass 1: per-bucket edge counts ----------------

__global__ __launch_bounds__(256) void bin_count(const int* __restrict__ ei, int e,
                                                 const int* __restrict__ flag, int shift,
                                                 int* __restrict__ gcnt) {
    __shared__ int h[MAXB];
    for (int i = threadIdx.x; i < MAXB; i += 256) h[i] = 0;
    __syncthreads();
    bool is64 = (*flag == 0);
    int stride = gridDim.x * 256;
    for (int i = blockIdx.x * 256 + threadIdx.x; i < e; i += stride) {
        int d = load_dst(ei, e, is64, i);
        atomicAdd(&h[d >> shift], 1);
    }
    __syncthreads();
    for (int i = threadIdx.x; i < MAXB; i += 256)
        if (h[i]) atomicAdd(&gcnt[i], h[i]);
}

// ---------------- pass 2: scan bucket counts -> base, init gcursor ----------------

__global__ void bin_scan_init(const int* __restrict__ gcnt, int nb,
                              int* __restrict__ base, int* __restrict__ gcursor) {
    __shared__ int sh[1024];
    int t = threadIdx.x;
    int v = (t < nb) ? gcnt[t] : 0;
    sh[t] = v;
    __syncthreads();
    for (int off = 1; off < 1024; off <<= 1) {
        int x = (t >= off) ? sh[t - off] : 0;
        __syncthreads();
        sh[t] += x;
        __syncthreads();
    }
    if (t < nb) {
        int excl = sh[t] - v;
        base[t] = excl;
        gcursor[t] = excl;
        if (t == nb - 1) base[nb] = sh[t];
    }
}

// ---------------- pass 3: tile counting-sort scatter into buckets ----------------

__global__ __launch_bounds__(SCAT_T) void bin_scatter(const int* __restrict__ ei, int e,
                                                      const int* __restrict__ flag, int shift,
                                                      int* __restrict__ gcursor,
                                                      unsigned int* __restrict__ gpk) {
    __shared__ int hist[MAXB];
    __shared__ int lbase[MAXB];
    __shared__ int gbase[MAXB];
    __shared__ int cur[MAXB];
    __shared__ unsigned int sbuf[TILE];
    __shared__ unsigned short sbkt[TILE];
    __shared__ int sh[SCAT_T];

    const int t = threadIdx.x;
    const int mask = (1 << shift) - 1;
    const bool is64 = (*flag == 0);
    const int tile0 = blockIdx.x * TILE;
    const int cnt = min(TILE, e - tile0);

    for (int i = t; i < MAXB; i += SCAT_T) hist[i] = 0;
    __syncthreads();

    unsigned int pk[EPT];
    int bk[EPT];
#pragma unroll
    for (int k = 0; k < EPT; k++) {
        int g = tile0 + k * SCAT_T + t;
        bk[k] = -1;
        if (g < e) {
            int s = load_src(ei, e, is64, g);
            int d = load_dst(ei, e, is64, g);
            int b = d >> shift;
            pk[k] = ((unsigned int)s << shift) | (unsigned int)(d & mask);
            bk[k] = b;
            atomicAdd(&hist[b], 1);
        }
    }
    __syncthreads();

    {
        int h0 = hist[2 * t];
        int h1 = hist[2 * t + 1];
        int s = h0 + h1;
        sh[t] = s;
        __syncthreads();
        for (int off = 1; off < SCAT_T; off <<= 1) {
            int x = (t >= off) ? sh[t - off] : 0;
            __syncthreads();
            sh[t] += x;
            __syncthreads();
        }
        int excl = sh[t] - s;
        lbase[2 * t] = excl;
        lbase[2 * t + 1] = excl + h0;
    }
    __syncthreads();

    for (int i = t; i < MAXB; i += SCAT_T) {
        int c = hist[i];
        if (c > 0) gbase[i] = atomicAdd(&gcursor[i], c);
        cur[i] = lbase[i];
    }
    __syncthreads();

#pragma unroll
    for (int k = 0; k < EPT; k++) {
        if (bk[k] >= 0) {
            int p = atomicAdd(&cur[bk[k]], 1);
            sbuf[p] = pk[k];
            sbkt[p] = (unsigned short)bk[k];
        }
    }
    __syncthreads();

    for (int i = t; i < cnt; i += SCAT_T) {
        int b = sbkt[i];
        gpk[gbase[b] + (i - lbase[b])] = sbuf[i];
    }
}

// ---------------- pass 4 (R11 fused): dinv + row_ptr + CSR col in ONE bucket pass ----
// row_ptr needs no global scan: row_ptr[node0+i] = base[b] + excl_scan(dc)[i]
// since gpk is already bucket-sorted. Replaces bucket_deg + 3 scan kernels +
// bucket_csr (saves one 25.6 MB gpk pass + 4 launches).

__global__ __launch_bounds__(256) void bucket_build(const unsigned int* __restrict__ gpk,
                                                    const int* __restrict__ base, int shift,
                                                    int n, int e, float* __restrict__ dinv,
                                                    int* __restrict__ row_ptr,
                                                    int* __restrict__ col) {
    __shared__ int lcol[LCAP];
    __shared__ int dc[MAXB];
    __shared__ int cur[MAXB];
    __shared__ int sh[256];
    const int t = threadIdx.x;
    const int b = blockIdx.x;
    const int mask = (1 << shift) - 1;
    const int width = 1 << shift;
    const int node0 = b << shift;
    const int nc = min(width, n - node0);
    const int lo = base[b], hi = base[b + 1];
    const int ecnt = hi - lo;

    for (int i = t; i < width; i += 256) dc[i] = 0;
    __syncthreads();
    // histogram within-bucket degrees
    for (int j = lo + t; j < hi; j += 256)
        atomicAdd(&dc[gpk[j] & mask], 1);
    __syncthreads();
    // exclusive scan of dc[0..width) : 4 entries/thread (width <= 1024)
    {
        int b4 = t * 4;
        int v0 = (b4 + 0 < width) ? dc[b4 + 0] : 0;
        int v1 = (b4 + 1 < width) ? dc[b4 + 1] : 0;
        int v2 = (b4 + 2 < width) ? dc[b4 + 2] : 0;
        int v3 = (b4 + 3 < width) ? dc[b4 + 3] : 0;
        int s = v0 + v1 + v2 + v3;
        sh[t] = s;
        __syncthreads();
        for (int off = 1; off < 256; off <<= 1) {
            int x = (t >= off) ? sh[t - off] : 0;
            __syncthreads();
            sh[t] += x;
            __syncthreads();
        }
        int excl = sh[t] - s;
        int pf[4] = {excl, excl + v0, excl + v0 + v1, excl + v0 + v1 + v2};
        int vv[4] = {v0, v1, v2, v3};
#pragma unroll
        for (int q = 0; q < 4; q++) {
            int i = b4 + q;
            if (i < nc) {
                row_ptr[node0 + i] = lo + pf[q];
                dinv[node0 + i] = rsqrtf(1.0f + (float)vv[q]);
            }
            if (i < width) cur[i] = pf[q];
        }
    }
    if (b == gridDim.x - 1 && t == 0) row_ptr[n] = e;
    __syncthreads();

    // place edges; stage through LDS when the bucket fits (it always does for
    // random graphs: avg 8.2k vs LCAP 13.5k), else scatter direct.
    if (ecnt <= LCAP) {
        for (int j = lo + t; j < hi; j += 256) {
            unsigned int v = gpk[j];
            int p = atomicAdd(&cur[v & mask], 1);
            lcol[p] = (int)(v >> shift);
        }
        __syncthreads();
        for (int j = t; j < ecnt; j += 256)
            col[lo + j] = lcol[j];
    } else {
        for (int j = lo + t; j < hi; j += 256) {
            unsigned int v = gpk[j];
            int p = atomicAdd(&cur[v & mask], 1);
            col[lo + p] = (int)(v >> shift);
        }
    }
}

// ---------------- Fused dual-output GEMM ----------------
// out1[n,CO1] = (A@W1)*dinv -> packed fp16; out2[n,CO2] = A@W2 -> fp32 (or 0).
// 512 threads: 48KB LDS hosts 8 waves/block -> 24 waves/CU (R9 @256 was 12).
// Depth-2 register pipeline; TR=4 (R5/R6: bigger tiles / min-waves bounds spill).

template <int THREADS, int CI, int CO1, int CO2>
__global__ __launch_bounds__(THREADS) void gemm_fused(const float* __restrict__ A,
                                                      const float* __restrict__ W1g,
                                                      const float* __restrict__ W2g,
                                                      const float* __restrict__ dinv,
                                                      unsigned int* __restrict__ out1,
                                                      float* __restrict__ out2, int n) {
    constexpr int CT = CO1 / 4;
    constexpr int RG = THREADS / CT;
    constexpr int TR = 4;
    constexpr int BR = RG * TR;
    __shared__ __align__(16) float Wl1[CI * CO1];
    __shared__ __align__(16) float Wl2[CO2 > 0 ? CI * CO2 : 4];
    for (int i = threadIdx.x; i < CI * CO1; i += THREADS) Wl1[i] = W1g[i];
    if (CO2 > 0)
        for (int i = threadIdx.x; i < CI * CO2; i += THREADS) Wl2[i] = W2g[i];
    __syncthreads();

    const int ct = threadIdx.x % CT;
    const int rg = threadIdx.x / CT;
    const int row0 = blockIdx.x * BR + rg * TR;

    float acc1[TR][4] = {{0.f}};
    float acc2[TR][2] = {{0.f}};

    auto loadA = [&](float4* buf, int k) {
#pragma unroll
        for (int r = 0; r < TR; r++) {
            int row = row0 + r;
            buf[r] = (row < n) ? *reinterpret_cast<const float4*>(&A[(size_t)row * CI + k])
                               : float4{0.f, 0.f, 0.f, 0.f};
        }
    };
    auto fmaStep = [&](const float4* buf, int k) {
#pragma unroll
        for (int kk = 0; kk < 4; kk++) {
            float4 w1 = *reinterpret_cast<const float4*>(&Wl1[(k + kk) * CO1 + ct * 4]);
            float2 w2{0.f, 0.f};
            if (CO2 > 0) w2 = *reinterpret_cast<const float2*>(&Wl2[(k + kk) * CO2 + ct * 2]);
#pragma unroll
            for (int r = 0; r < TR; r++) {
                float av = (kk == 0) ? buf[r].x : (kk == 1) ? buf[r].y
                         : (kk == 2) ? buf[r].z : buf[r].w;
                acc1[r][0] += av * w1.x;
                acc1[r][1] += av * w1.y;
                acc1[r][2] += av * w1.z;
                acc1[r][3] += av * w1.w;
                if (CO2 > 0) {
                    acc2[r][0] += av * w2.x;
                    acc2[r][1] += av * w2.y;
                }
            }
        }
    };

    float4 cur[TR], nxt[TR] = {};
    loadA(cur, 0);
#pragma unroll 2
    for (int k = 0; k < CI; k += 4) {
        if (k + 4 < CI) loadA(nxt, k + 4);
        fmaStep(cur, k);
#pragma unroll
        for (int r = 0; r < TR; r++) cur[r] = nxt[r];
    }

#pragma unroll
    for (int r = 0; r < TR; r++) {
        int row = row0 + r;
        if (row >= n) continue;
        float s = dinv[row];
        uint2 pk{pack_f16(acc1[r][0] * s, acc1[r][1] * s),
                 pack_f16(acc1[r][2] * s, acc1[r][3] * s)};
        *reinterpret_cast<uint2*>(&out1[(size_t)row * (CO1 / 2) + ct * 2]) = pk;
        if (CO2 > 0) {
            float2 v{acc2[r][0], acc2[r][1]};
            *reinterpret_cast<float2*>(&out2[(size_t)row * CO2 + ct * 2]) = v;
        }
    }
}

// ---------------- Fused gather + self-loop + bias + skip + relu (+head) ----------------
// ONE WAVE PER NODE; grid = cdiv(n,4) with 256-thread blocks. uint4 loads.
// R11: main loop does a pairwise fp16 tree-add (v_pk_add_f16, 12 packed adds
// per 4 loads) then ONE fp32 unpack-accumulate — ~28 VALU ops per 4 loads vs
// ~64 with per-load unpack (R10 gather was 58% VALUBusy). <=4 fp16 summands
// per group keeps the extra error ~5e-4. Tail stays full-fp32.

template <int F, bool FINAL>
__global__ __launch_bounds__(256) void gather_combine(
    const uint4* __restrict__ hp4, const int* __restrict__ row_ptr,
    const int* __restrict__ col, const float* __restrict__ dinv,
    const float* __restrict__ bias, const float* __restrict__ sk,
    const float* __restrict__ bsk, float* __restrict__ out,
    const float* __restrict__ Wlin, const float* __restrict__ blin, int n) {
    constexpr int L = F / 8;      // lanes per edge
    constexpr int EPW = 64 / L;   // edges concurrently per wave-pass
    int wid = (blockIdx.x * blockDim.x + threadIdx.x) >> 6;
    int lane = threadIdx.x & 63;
    if (wid >= n) return;
    int s = lane / L;
    int el = lane % L;
    int start = row_ptr[wid];
    int end = row_ptr[wid + 1];

    float a[8] = {0.f, 0.f, 0.f, 0.f, 0.f, 0.f, 0.f, 0.f};
    int j = start + s;
    while (j + 3 * EPW < end) {   // 4 independent load chains
        int c0 = col[j];
        int c1 = col[j + EPW];
        int c2 = col[j + 2 * EPW];
        int c3 = col[j + 3 * EPW];
        uint4 u0 = hp4[(size_t)c0 * L + el];
        uint4 u1 = hp4[(size_t)c1 * L + el];
        uint4 u2 = hp4[(size_t)c2 * L + el];
        uint4 u3 = hp4[(size_t)c3 * L + el];
        uint4 t01 = h2add4(u0, u1);
        uint4 t23 = h2add4(u2, u3);
        acc8(a, h2add4(t01, t23));
        j += 4 * EPW;
    }
    while (j < end) {
        uint4 u = hp4[(size_t)col[j] * L + el];
        acc8(a, u);
        j += EPW;
    }

    // reduce across edge slots (lanes with same el)
#pragma unroll
    for (int m = L; m < 64; m <<= 1) {
#pragma unroll
        for (int q = 0; q < 8; q++) a[q] += __shfl_xor(a[q], m);
    }

    if (lane < L) {
        float dn = dinv[wid];
        uint4 us = hp4[(size_t)wid * L + el];
        float v[8];
        unpack8(us, v);
        float4 b0 = *reinterpret_cast<const float4*>(&bias[8 * el]);
        float4 b1 = *reinterpret_cast<const float4*>(&bias[8 * el + 4]);
        float o[8];
        o[0] = dn * a[0] + v[0] * dn + b0.x;
        o[1] = dn * a[1] + v[1] * dn + b0.y;
        o[2] = dn * a[2] + v[2] * dn + b0.z;
        o[3] = dn * a[3] + v[3] * dn + b0.w;
        o[4] = dn * a[4] + v[4] * dn + b1.x;
        o[5] = dn * a[5] + v[5] * dn + b1.y;
        o[6] = dn * a[6] + v[6] * dn + b1.z;
        o[7] = dn * a[7] + v[7] * dn + b1.w;
        if (sk) {
            float4 s0 = *reinterpret_cast<const float4*>(&sk[(size_t)wid * F + 8 * el]);
            float4 s1 = *reinterpret_cast<const float4*>(&sk[(size_t)wid * F + 8 * el + 4]);
            float4 k0 = *reinterpret_cast<const float4*>(&bsk[8 * el]);
            float4 k1 = *reinterpret_cast<const float4*>(&bsk[8 * el + 4]);
            o[0] += s0.x + k0.x; o[1] += s0.y + k0.y;
            o[2] += s0.z + k0.z; o[3] += s0.w + k0.w;
            o[4] += s1.x + k1.x; o[5] += s1.y + k1.y;
            o[6] += s1.z + k1.z; o[7] += s1.w + k1.w;
        }
#pragma unroll
        for (int q = 0; q < 8; q++) o[q] = fmaxf(o[q], 0.f);
        if (FINAL) {
            float4 wl0 = *reinterpret_cast<const float4*>(&Wlin[8 * el]);
            float4 wl1 = *reinterpret_cast<const float4*>(&Wlin[8 * el + 4]);
            float d = o[0] * wl0.x + o[1] * wl0.y + o[2] * wl0.z + o[3] * wl0.w +
                      o[4] * wl1.x + o[5] * wl1.y + o[6] * wl1.z + o[7] * wl1.w;
            d += __shfl_xor(d, 1);
            if (el == 0) out[wid] = 1.0f / (1.0f + expf(-(d + blin[0])));
        } else {
            float4 w0{o[0], o[1], o[2], o[3]};
            float4 w1{o[4], o[5], o[6], o[7]};
            *reinterpret_cast<float4*>(&out[(size_t)wid * F + 8 * el]) = w0;
            *reinterpret_cast<float4*>(&out[(size_t)wid * F + 8 * el + 4]) = w1;
        }
    }
}

// ---------------- launch ----------------

extern "C" void kernel_launch(void* const* d_in, const int* in_sizes, int n_in,
                              void* d_out, int out_size, void* d_ws, size_t ws_size,
                              hipStream_t stream) {
    const float* x     = (const float*)d_in[0];
    const int*   ei    = (const int*)d_in[1];
    const float* W1    = (const float*)d_in[2];
    const float* b1    = (const float*)d_in[3];
    const float* W2    = (const float*)d_in[4];
    const float* b2    = (const float*)d_in[5];
    const float* W3    = (const float*)d_in[6];
    const float* b3    = (const float*)d_in[7];
    const float* Wsk02 = (const float*)d_in[8];
    const float* bsk02 = (const float*)d_in[9];
    const float* Wsk13 = (const float*)d_in[10];
    const float* bsk13 = (const float*)d_in[11];
    const float* Wlin  = (const float*)d_in[12];
    const float* blin  = (const float*)d_in[13];

    const int n = in_sizes[0] / 128;
    const int e = in_sizes[1] / 2;

    int shift = 8;
    while (((n + (1 << shift) - 1) >> shift) > MAXB) shift++;
    const int nbkt = (n + (1 << shift) - 1) >> shift;

    // workspace carve (256B aligned)
    char* p = (char*)d_ws;
    auto alloc = [&](size_t bytes) {
        void* r = (void*)p;
        p += (bytes + 255) / 256 * 256;
        return r;
    };
    int*   flag    = (int*)alloc(256);
    int*   gcnt    = (int*)alloc(MAXB * 4);
    int*   base    = (int*)alloc((MAXB + 1) * 4);
    int*   gcursor = (int*)alloc(MAXB * 4);
    int*   row_ptr = (int*)alloc((size_t)(n + 1) * 4);
    float* dinv    = (float*)alloc((size_t)n * 4);
    int*   col     = (int*)alloc((size_t)e * 4);
    float* h1      = (float*)alloc((size_t)n * 64 * 4);
    float* h2      = (float*)alloc((size_t)n * 32 * 4);
    float* sk02    = (float*)alloc((size_t)n * 32 * 4);              // x@Wsk02 (fp32)
    float* sk13    = (float*)alloc((size_t)n * 16 * 4);              // h1@Wsk13 (fp32)
    size_t prebytes = (size_t)(e > n * 32 ? e : n * 32) * 4;
    unsigned int* preb = (unsigned int*)alloc(prebytes);             // fp16-packed gather table
    unsigned int* gpk  = preb;  // bucketed packed edges; dead before fusedA writes preb

    auto cdiv = [](int a, int b) { return (a + b - 1) / b; };

    // CSR build: count -> scan -> bucket-sort -> fused (dinv|row_ptr|col)
    hipMemsetAsync(flag, 0, 4, stream);
    hipMemsetAsync(gcnt, 0, MAXB * 4, stream);
    detect_kernel<<<1, 1024, 0, stream>>>(ei, flag);
    bin_count<<<1024, 256, 0, stream>>>(ei, e, flag, shift, gcnt);
    bin_scan_init<<<1, 1024, 0, stream>>>(gcnt, nbkt, base, gcursor);
    bin_scatter<<<cdiv(e, TILE), SCAT_T, 0, stream>>>(ei, e, flag, shift, gcursor, gpk);
    bucket_build<<<nbkt, 256, 0, stream>>>(gpk, base, shift, n, e, dinv, row_ptr, col);

    // fused GEMM A: preb = (x@W1)*dinv (fp16), sk02 = x@Wsk02 (fp32); BR = 128
    gemm_fused<512, 128, 64, 32><<<cdiv(n, 128), 512, 0, stream>>>(x, W1, Wsk02, dinv,
                                                                   preb, sk02, n);
    // layer 1 aggregate: h1 = relu(conv(x, W1, b1))
    gather_combine<64, false><<<cdiv(n, 4), 256, 0, stream>>>(
        (const uint4*)preb, row_ptr, col, dinv, b1, nullptr, nullptr, h1, nullptr, nullptr, n);

    // fused GEMM B: preb = (h1@W2)*dinv (fp16), sk13 = h1@Wsk13 (fp32); BR = 256
    gemm_fused<512, 64, 32, 16><<<cdiv(n, 256), 512, 0, stream>>>(h1, W2, Wsk13, dinv,
                                                                  preb, sk13, n);
    // layer 2 aggregate: h2 = relu(conv(h1, W2, b2) + x@Wsk02 + bsk02)
    gather_combine<32, false><<<cdiv(n, 4), 256, 0, stream>>>(
        (const uint4*)preb, row_ptr, col, dinv, b2, sk02, bsk02, h2, nullptr, nullptr, n);

    // GEMM C: preb = (h2@W3)*dinv (fp16); BR = 512
    gemm_fused<512, 32, 16, 0><<<cdiv(n, 512), 512, 0, stream>>>(h2, W3, nullptr, dinv,
                                                                 preb, nullptr, n);
    // layer 3 aggregate + head: out = sigmoid(relu(conv(h2,W3,b3)+h1@Wsk13+bsk13) @ Wlin + blin)
    gather_combine<16, true><<<cdiv(n, 4), 256, 0, stream>>>(
        (const uint4*)preb, row_ptr, col, dinv, b3, sk13, bsk13, (float*)d_out, Wlin, blin, n);
}

// Round 12
// 630.365 us; speedup vs baseline: 3.4277x; 1.0080x over previous
//
#include <hip/hip_runtime.h>
#include <hip/hip_fp16.h>
#include <math.h>

// Bucketed CSR build tunables.
// fine bucket = 256 nodes (shift=8, nbkt=782); coarse bucket = 8 fine = 2048
// nodes (98 coarse). Two-level scatter keeps every global write in long runs.
#define MAXB 1024        // max fine buckets in LDS arrays
#define MAXCB 128        // max coarse buckets
#define TILE1 8192       // edges per scatter_coarse tile
#define SCAT_T 512
#define EPT1 (TILE1 / SCAT_T)
#define LCAP 13568       // bucket_build LDS col capacity (53KB; avg bucket ~8.2k)

// ---------------- fp16 pack helpers ----------------

__device__ __forceinline__ unsigned int pack_f16(float a, float b) {
    __half2 h = __floats2half2_rn(a, b);
    return *reinterpret_cast<unsigned int*>(&h);
}
__device__ __forceinline__ float f16_lo(unsigned int u) {
    __half2 h = *reinterpret_cast<__half2*>(&u);
    return __low2float(h);
}
__device__ __forceinline__ float f16_hi(unsigned int u) {
    __half2 h = *reinterpret_cast<__half2*>(&u);
    return __high2float(h);
}
__device__ __forceinline__ void acc8(float* a, uint4 u) {
    a[0] += f16_lo(u.x); a[1] += f16_hi(u.x);
    a[2] += f16_lo(u.y); a[3] += f16_hi(u.y);
    a[4] += f16_lo(u.z); a[5] += f16_hi(u.z);
    a[6] += f16_lo(u.w); a[7] += f16_hi(u.w);
}
__device__ __forceinline__ void unpack8(uint4 u, float* v) {
    v[0] = f16_lo(u.x); v[1] = f16_hi(u.x);
    v[2] = f16_lo(u.y); v[3] = f16_hi(u.y);
    v[4] = f16_lo(u.z); v[5] = f16_hi(u.z);
    v[6] = f16_lo(u.w); v[7] = f16_hi(u.w);
}
// packed fp16 pairwise add: 4 instrs for 8 feats
__device__ __forceinline__ uint4 h2add4(uint4 a, uint4 b) {
    const __half2* pa = reinterpret_cast<const __half2*>(&a);
    const __half2* pb = reinterpret_cast<const __half2*>(&b);
    uint4 r;
    __half2* pr = reinterpret_cast<__half2*>(&r);
#pragma unroll
    for (int i = 0; i < 4; i++) pr[i] = __hadd2(pa[i], pb[i]);
    return r;
}

// ---------------- edge dtype detection (int32 vs int64) ----------------

__global__ void detect_kernel(const int* __restrict__ ei, int* __restrict__ flag) {
    int i = threadIdx.x;  // one block of 1024
    if (ei[2 * i + 1] != 0) atomicAdd(flag, 1);
}

__device__ __forceinline__ int load_src(const int* ei, int e, bool is64, int i) {
    return is64 ? ei[2 * i] : ei[i];
}
__device__ __forceinline__ int load_dst(const int* ei, int e, bool is64, int i) {
    return is64 ? ei[2 * e + 2 * i] : ei[e + i];
}

// ---------------- pass 1: per-FINE-bucket edge counts ----------------

__global__ __launch_bounds__(256) void bin_count(const int* __restrict__ ei, int e,
                                                 const int* __restrict__ flag, int shift,
                                                 int* __restrict__ gcnt) {
    __shared__ int h[MAXB];
    for (int i = threadIdx.x; i < MAXB; i += 256) h[i] = 0;
    __syncthreads();
    bool is64 = (*flag == 0);
    int stride = gridDim.x * 256;
    for (int i = blockIdx.x * 256 + threadIdx.x; i < e; i += stride) {
        int d = load_dst(ei, e, is64, i);
        atomicAdd(&h[d >> shift], 1);
    }
    __syncthreads();
    for (int i = threadIdx.x; i < MAXB; i += 256)
        if (h[i]) atomicAdd(&gcnt[i], h[i]);
}

// ---------------- pass 2: scan fine counts -> base; init fine + coarse cursors ----

__global__ void bin_scan_init(const int* __restrict__ gcnt, int nb, int ncb,
                              int* __restrict__ base, int* __restrict__ gcursor,
                              int* __restrict__ gcur1) {
    __shared__ int sh[1024];
    __shared__ int ex[1024];
    int t = threadIdx.x;
    int v = (t < nb) ? gcnt[t] : 0;
    sh[t] = v;
    __syncthreads();
    for (int off = 1; off < 1024; off <<= 1) {
        int x = (t >= off) ? sh[t - off] : 0;
        __syncthreads();
        sh[t] += x;
        __syncthreads();
    }
    int excl = sh[t] - v;
    ex[t] = excl;
    if (t < nb) {
        base[t] = excl;
        gcursor[t] = excl;
        if (t == nb - 1) base[nb] = sh[t];
    }
    __syncthreads();
    if (t < ncb) gcur1[t] = ex[8 * t];  // coarse bucket c starts at fine 8c
}

// ---------------- pass 3a: tile-sort into COARSE buckets (runs ~84 edges) ----------
// pk = (src << PKSHIFT) | (dst & (2^PKSHIFT - 1)), PKSHIFT = shift + 3.

__global__ __launch_bounds__(SCAT_T) void scatter_coarse(const int* __restrict__ ei, int e,
                                                         const int* __restrict__ flag,
                                                         int shift,
                                                         int* __restrict__ gcur1,
                                                         unsigned int* __restrict__ gpk1) {
    __shared__ int hist[MAXCB];
    __shared__ int lbase[MAXCB];
    __shared__ int delta[MAXCB];   // gbase - lbase
    __shared__ int cur[MAXCB];
    __shared__ unsigned int sbuf[TILE1];
    __shared__ unsigned char sbkt[TILE1];
    __shared__ int sh[SCAT_T];

    const int t = threadIdx.x;
    const int pkshift = shift + 3;
    const int pkmask = (1 << pkshift) - 1;
    const bool is64 = (*flag == 0);
    const int tile0 = blockIdx.x * TILE1;
    const int cnt = min(TILE1, e - tile0);

    for (int i = t; i < MAXCB; i += SCAT_T) hist[i] = 0;
    __syncthreads();

    unsigned int pk[EPT1];
    int bk[EPT1];
#pragma unroll
    for (int k = 0; k < EPT1; k++) {
        int g = tile0 + k * SCAT_T + t;
        bk[k] = -1;
        if (g < e) {
            int s = load_src(ei, e, is64, g);
            int d = load_dst(ei, e, is64, g);
            pk[k] = ((unsigned int)s << pkshift) | (unsigned int)(d & pkmask);
            bk[k] = d >> pkshift;
            atomicAdd(&hist[bk[k]], 1);
        }
    }
    __syncthreads();

    // exclusive scan of hist[0..MAXCB) (ladder over all threads; entries >=MAXCB are 0)
    {
        int v = (t < MAXCB) ? hist[t] : 0;
        sh[t] = v;
        __syncthreads();
        for (int off = 1; off < SCAT_T; off <<= 1) {
            int x = (t >= off) ? sh[t - off] : 0;
            __syncthreads();
            sh[t] += x;
            __syncthreads();
        }
        if (t < MAXCB) lbase[t] = sh[t] - v;
    }
    __syncthreads();

    if (t < MAXCB) {
        int c = hist[t];
        if (c > 0) delta[t] = atomicAdd(&gcur1[t], c) - lbase[t];
        cur[t] = lbase[t];
    }
    __syncthreads();

#pragma unroll
    for (int k = 0; k < EPT1; k++) {
        if (bk[k] >= 0) {
            int p = atomicAdd(&cur[bk[k]], 1);
            sbuf[p] = pk[k];
            sbkt[p] = (unsigned char)bk[k];
        }
    }
    __syncthreads();

    for (int i = t; i < cnt; i += SCAT_T)
        gpk1[delta[sbkt[i]] + i] = sbuf[i];
}

// ---------------- pass 3b: per-coarse-bucket sort into FINE buckets (runs ~1000) ----

__global__ __launch_bounds__(SCAT_T) void scatter_fine(const unsigned int* __restrict__ gpk1,
                                                       const int* __restrict__ base,
                                                       int nbkt, int shift,
                                                       int* __restrict__ gcursor,
                                                       unsigned int* __restrict__ gpk2) {
    __shared__ int hist[8];
    __shared__ int lbase[8];
    __shared__ int delta[8];
    __shared__ int cur[8];
    __shared__ unsigned int sbuf[TILE1];
    __shared__ unsigned char sbkt[TILE1];

    const int t = threadIdx.x;
    const int cb = blockIdx.x >> 3;        // coarse bucket
    const int s = blockIdx.x & 7;          // sub-slice
    const int f0 = 8 * cb;
    const int fhiIdx = min(f0 + 8, nbkt);
    const int lo = base[f0];
    const int hi = base[fhiIdx];
    const int len = hi - lo;
    const int slo = lo + (int)((long long)len * s / 8);
    const int shi = lo + (int)((long long)len * (s + 1) / 8);

    for (int tile0 = slo; tile0 < shi; tile0 += TILE1) {
        const int cnt = min(TILE1, shi - tile0);
        if (t < 8) hist[t] = 0;
        __syncthreads();

        unsigned int pk[EPT1];
        int bk[EPT1];
#pragma unroll
        for (int k = 0; k < EPT1; k++) {
            int li = k * SCAT_T + t;
            bk[k] = -1;
            if (li < cnt) {
                pk[k] = gpk1[tile0 + li];
                bk[k] = (pk[k] >> shift) & 7;
                atomicAdd(&hist[bk[k]], 1);
            }
        }
        __syncthreads();

        if (t == 0) {
            int run = 0;
            for (int f = 0; f < 8; f++) { lbase[f] = run; run += hist[f]; }
        }
        __syncthreads();
        if (t < 8) {
            int c = hist[t];
            if (c > 0) delta[t] = atomicAdd(&gcursor[f0 + t], c) - lbase[t];
            cur[t] = lbase[t];
        }
        __syncthreads();

#pragma unroll
        for (int k = 0; k < EPT1; k++) {
            if (bk[k] >= 0) {
                int p = atomicAdd(&cur[bk[k]], 1);
                sbuf[p] = pk[k];
                sbkt[p] = (unsigned char)bk[k];
            }
        }
        __syncthreads();

        for (int i = t; i < cnt; i += SCAT_T)
            gpk2[delta[sbkt[i]] + i] = sbuf[i];
        __syncthreads();
    }
}

// ---------------- pass 4: fused dinv + row_ptr + CSR col per fine bucket ----------

__global__ __launch_bounds__(256) void bucket_build(const unsigned int* __restrict__ gpk,
                                                    const int* __restrict__ base, int shift,
                                                    int n, int e, float* __restrict__ dinv,
                                                    int* __restrict__ row_ptr,
                                                    int* __restrict__ col) {
    __shared__ int lcol[LCAP];
    __shared__ int dc[MAXB];
    __shared__ int cur[MAXB];
    __shared__ int sh[256];
    const int t = threadIdx.x;
    const int b = blockIdx.x;
    const int pkshift = shift + 3;
    const int mask = (1 << shift) - 1;
    const int width = 1 << shift;
    const int node0 = b << shift;
    const int nc = min(width, n - node0);
    const int lo = base[b], hi = base[b + 1];
    const int ecnt = hi - lo;

    for (int i = t; i < width; i += 256) dc[i] = 0;
    __syncthreads();
    for (int j = lo + t; j < hi; j += 256)
        atomicAdd(&dc[gpk[j] & mask], 1);
    __syncthreads();
    {
        int b4 = t * 4;
        int v0 = (b4 + 0 < width) ? dc[b4 + 0] : 0;
        int v1 = (b4 + 1 < width) ? dc[b4 + 1] : 0;
        int v2 = (b4 + 2 < width) ? dc[b4 + 2] : 0;
        int v3 = (b4 + 3 < width) ? dc[b4 + 3] : 0;
        int s = v0 + v1 + v2 + v3;
        sh[t] = s;
        __syncthreads();
        for (int off = 1; off < 256; off <<= 1) {
            int x = (t >= off) ? sh[t - off] : 0;
            __syncthreads();
            sh[t] += x;
            __syncthreads();
        }
        int excl = sh[t] - s;
        int pf[4] = {excl, excl + v0, excl + v0 + v1, excl + v0 + v1 + v2};
        int vv[4] = {v0, v1, v2, v3};
#pragma unroll
        for (int q = 0; q < 4; q++) {
            int i = b4 + q;
            if (i < nc) {
                row_ptr[node0 + i] = lo + pf[q];
                dinv[node0 + i] = rsqrtf(1.0f + (float)vv[q]);
            }
            if (i < width) cur[i] = pf[q];
        }
    }
    if (b == gridDim.x - 1 && t == 0) row_ptr[n] = e;
    __syncthreads();

    if (ecnt <= LCAP) {
        for (int j = lo + t; j < hi; j += 256) {
            unsigned int v = gpk[j];
            int p = atomicAdd(&cur[v & mask], 1);
            lcol[p] = (int)(v >> pkshift);
        }
        __syncthreads();
        for (int j = t; j < ecnt; j += 256)
            col[lo + j] = lcol[j];
    } else {
        for (int j = lo + t; j < hi; j += 256) {
            unsigned int v = gpk[j];
            int p = atomicAdd(&cur[v & mask], 1);
            col[lo + p] = (int)(v >> pkshift);
        }
    }
}

// ---------------- Fused dual-output GEMM ----------------
// out1[n,CO1] = (A@W1)*dinv -> packed fp16; out2[n,CO2] = A@W2 -> fp32 (or 0).
// AHALF: A is packed fp16 (h1/h2 are stored fp16 from the gathers).
// 512 threads; depth-2 register pipeline; TR=4 (R5/R6: bigger tiles or
// min-waves bounds spill).

template <int THREADS, int CI, int CO1, int CO2, bool AHALF>
__global__ __launch_bounds__(THREADS) void gemm_fused(const void* __restrict__ Av,
                                                      const float* __restrict__ W1g,
                                                      const float* __restrict__ W2g,
                                                      const float* __restrict__ dinv,
                                                      unsigned int* __restrict__ out1,
                                                      float* __restrict__ out2, int n) {
    constexpr int CT = CO1 / 4;
    constexpr int RG = THREADS / CT;
    constexpr int TR = 4;
    constexpr int BR = RG * TR;
    __shared__ __align__(16) float Wl1[CI * CO1];
    __shared__ __align__(16) float Wl2[CO2 > 0 ? CI * CO2 : 4];
    for (int i = threadIdx.x; i < CI * CO1; i += THREADS) Wl1[i] = W1g[i];
    if (CO2 > 0)
        for (int i = threadIdx.x; i < CI * CO2; i += THREADS) Wl2[i] = W2g[i];
    __syncthreads();

    const int ct = threadIdx.x % CT;
    const int rg = threadIdx.x / CT;
    const int row0 = blockIdx.x * BR + rg * TR;

    float acc1[TR][4] = {{0.f}};
    float acc2[TR][2] = {{0.f}};

    auto loadA = [&](float4* buf, int k) {
#pragma unroll
        for (int r = 0; r < TR; r++) {
            int row = row0 + r;
            if (row >= n) { buf[r] = float4{0.f, 0.f, 0.f, 0.f}; continue; }
            if (AHALF) {
                const unsigned int* Ah = (const unsigned int*)Av;
                uint2 u = *reinterpret_cast<const uint2*>(&Ah[(size_t)row * (CI / 2) + k / 2]);
                buf[r] = float4{f16_lo(u.x), f16_hi(u.x), f16_lo(u.y), f16_hi(u.y)};
            } else {
                const float* Af = (const float*)Av;
                buf[r] = *reinterpret_cast<const float4*>(&Af[(size_t)row * CI + k]);
            }
        }
    };
    auto fmaStep = [&](const float4* buf, int k) {
#pragma unroll
        for (int kk = 0; kk < 4; kk++) {
            float4 w1 = *reinterpret_cast<const float4*>(&Wl1[(k + kk) * CO1 + ct * 4]);
            float2 w2{0.f, 0.f};
            if (CO2 > 0) w2 = *reinterpret_cast<const float2*>(&Wl2[(k + kk) * CO2 + ct * 2]);
#pragma unroll
            for (int r = 0; r < TR; r++) {
                float av = (kk == 0) ? buf[r].x : (kk == 1) ? buf[r].y
                         : (kk == 2) ? buf[r].z : buf[r].w;
                acc1[r][0] += av * w1.x;
                acc1[r][1] += av * w1.y;
                acc1[r][2] += av * w1.z;
                acc1[r][3] += av * w1.w;
                if (CO2 > 0) {
                    acc2[r][0] += av * w2.x;
                    acc2[r][1] += av * w2.y;
                }
            }
        }
    };

    float4 cur[TR], nxt[TR] = {};
    loadA(cur, 0);
#pragma unroll 2
    for (int k = 0; k < CI; k += 4) {
        if (k + 4 < CI) loadA(nxt, k + 4);
        fmaStep(cur, k);
#pragma unroll
        for (int r = 0; r < TR; r++) cur[r] = nxt[r];
    }

#pragma unroll
    for (int r = 0; r < TR; r++) {
        int row = row0 + r;
        if (row >= n) continue;
        float s = dinv[row];
        uint2 pk{pack_f16(acc1[r][0] * s, acc1[r][1] * s),
                 pack_f16(acc1[r][2] * s, acc1[r][3] * s)};
        *reinterpret_cast<uint2*>(&out1[(size_t)row * (CO1 / 2) + ct * 2]) = pk;
        if (CO2 > 0) {
            float2 v{acc2[r][0], acc2[r][1]};
            *reinterpret_cast<float2*>(&out2[(size_t)row * CO2 + ct * 2]) = v;
        }
    }
}

// ---------------- Fused gather + self-loop + bias + skip + relu (+head) ----------------
// ONE WAVE PER NODE; grid = cdiv(n,4), 256-thread blocks; uint4 loads; fp16
// tree-add in the main loop. PACKOUT: write result as packed fp16 (feeds the
// next layer's fp16-A GEMM). FINAL: fuse the sigmoid head, write d_out[wid].

template <int F, bool FINAL, bool PACKOUT>
__global__ __launch_bounds__(256) void gather_combine(
    const uint4* __restrict__ hp4, const int* __restrict__ row_ptr,
    const int* __restrict__ col, const float* __restrict__ dinv,
    const float* __restrict__ bias, const float* __restrict__ sk,
    const float* __restrict__ bsk, void* __restrict__ outv,
    const float* __restrict__ Wlin, const float* __restrict__ blin, int n) {
    constexpr int L = F / 8;
    constexpr int EPW = 64 / L;
    int wid = (blockIdx.x * blockDim.x + threadIdx.x) >> 6;
    int lane = threadIdx.x & 63;
    if (wid >= n) return;
    int s = lane / L;
    int el = lane % L;
    int start = row_ptr[wid];
    int end = row_ptr[wid + 1];

    float a[8] = {0.f, 0.f, 0.f, 0.f, 0.f, 0.f, 0.f, 0.f};
    int j = start + s;
    while (j + 3 * EPW < end) {
        int c0 = col[j];
        int c1 = col[j + EPW];
        int c2 = col[j + 2 * EPW];
        int c3 = col[j + 3 * EPW];
        uint4 u0 = hp4[(size_t)c0 * L + el];
        uint4 u1 = hp4[(size_t)c1 * L + el];
        uint4 u2 = hp4[(size_t)c2 * L + el];
        uint4 u3 = hp4[(size_t)c3 * L + el];
        uint4 t01 = h2add4(u0, u1);
        uint4 t23 = h2add4(u2, u3);
        acc8(a, h2add4(t01, t23));
        j += 4 * EPW;
    }
    while (j < end) {
        uint4 u = hp4[(size_t)col[j] * L + el];
        acc8(a, u);
        j += EPW;
    }

#pragma unroll
    for (int m = L; m < 64; m <<= 1) {
#pragma unroll
        for (int q = 0; q < 8; q++) a[q] += __shfl_xor(a[q], m);
    }

    if (lane < L) {
        float dn = dinv[wid];
        uint4 us = hp4[(size_t)wid * L + el];
        float v[8];
        unpack8(us, v);
        float4 b0 = *reinterpret_cast<const float4*>(&bias[8 * el]);
        float4 b1 = *reinterpret_cast<const float4*>(&bias[8 * el + 4]);
        float o[8];
        o[0] = dn * a[0] + v[0] * dn + b0.x;
        o[1] = dn * a[1] + v[1] * dn + b0.y;
        o[2] = dn * a[2] + v[2] * dn + b0.z;
        o[3] = dn * a[3] + v[3] * dn + b0.w;
        o[4] = dn * a[4] + v[4] * dn + b1.x;
        o[5] = dn * a[5] + v[5] * dn + b1.y;
        o[6] = dn * a[6] + v[6] * dn + b1.z;
        o[7] = dn * a[7] + v[7] * dn + b1.w;
        if (sk) {
            float4 s0 = *reinterpret_cast<const float4*>(&sk[(size_t)wid * F + 8 * el]);
            float4 s1 = *reinterpret_cast<const float4*>(&sk[(size_t)wid * F + 8 * el + 4]);
            float4 k0 = *reinterpret_cast<const float4*>(&bsk[8 * el]);
            float4 k1 = *reinterpret_cast<const float4*>(&bsk[8 * el + 4]);
            o[0] += s0.x + k0.x; o[1] += s0.y + k0.y;
            o[2] += s0.z + k0.z; o[3] += s0.w + k0.w;
            o[4] += s1.x + k1.x; o[5] += s1.y + k1.y;
            o[6] += s1.z + k1.z; o[7] += s1.w + k1.w;
        }
#pragma unroll
        for (int q = 0; q < 8; q++) o[q] = fmaxf(o[q], 0.f);
        if (FINAL) {
            float4 wl0 = *reinterpret_cast<const float4*>(&Wlin[8 * el]);
            float4 wl1 = *reinterpret_cast<const float4*>(&Wlin[8 * el + 4]);
            float d = o[0] * wl0.x + o[1] * wl0.y + o[2] * wl0.z + o[3] * wl0.w +
                      o[4] * wl1.x + o[5] * wl1.y + o[6] * wl1.z + o[7] * wl1.w;
            d += __shfl_xor(d, 1);
            if (el == 0) ((float*)outv)[wid] = 1.0f / (1.0f + expf(-(d + blin[0])));
        } else if (PACKOUT) {
            uint4 pk{pack_f16(o[0], o[1]), pack_f16(o[2], o[3]),
                     pack_f16(o[4], o[5]), pack_f16(o[6], o[7])};
            ((uint4*)outv)[(size_t)wid * L + el] = pk;
        } else {
            float* out = (float*)outv;
            float4 w0{o[0], o[1], o[2], o[3]};
            float4 w1{o[4], o[5], o[6], o[7]};
            *reinterpret_cast<float4*>(&out[(size_t)wid * F + 8 * el]) = w0;
            *reinterpret_cast<float4*>(&out[(size_t)wid * F + 8 * el + 4]) = w1;
        }
    }
}

// ---------------- launch ----------------

extern "C" void kernel_launch(void* const* d_in, const int* in_sizes, int n_in,
                              void* d_out, int out_size, void* d_ws, size_t ws_size,
                              hipStream_t stream) {
    const float* x     = (const float*)d_in[0];
    const int*   ei    = (const int*)d_in[1];
    const float* W1    = (const float*)d_in[2];
    const float* b1    = (const float*)d_in[3];
    const float* W2    = (const float*)d_in[4];
    const float* b2    = (const float*)d_in[5];
    const float* W3    = (const float*)d_in[6];
    const float* b3    = (const float*)d_in[7];
    const float* Wsk02 = (const float*)d_in[8];
    const float* bsk02 = (const float*)d_in[9];
    const float* Wsk13 = (const float*)d_in[10];
    const float* bsk13 = (const float*)d_in[11];
    const float* Wlin  = (const float*)d_in[12];
    const float* blin  = (const float*)d_in[13];

    const int n = in_sizes[0] / 128;
    const int e = in_sizes[1] / 2;

    int shift = 8;
    while (((n + (1 << shift) - 1) >> shift) > MAXB) shift++;
    const int nbkt = (n + (1 << shift) - 1) >> shift;
    const int ncb = (nbkt + 7) / 8;   // coarse buckets (<= MAXCB)

    // workspace carve (256B aligned)
    char* p = (char*)d_ws;
    auto alloc = [&](size_t bytes) {
        void* r = (void*)p;
        p += (bytes + 255) / 256 * 256;
        return r;
    };
    int*   flag    = (int*)alloc(256);
    int*   gcnt    = (int*)alloc(MAXB * 4);
    int*   base    = (int*)alloc((MAXB + 1) * 4);
    int*   gcursor = (int*)alloc(MAXB * 4);
    int*   gcur1   = (int*)alloc(MAXCB * 4);
    int*   row_ptr = (int*)alloc((size_t)(n + 1) * 4);
    float* dinv    = (float*)alloc((size_t)n * 4);
    int*   col     = (int*)alloc((size_t)e * 4);
    size_t h1b     = (size_t)e * 4 > (size_t)n * 128 ? (size_t)e * 4 : (size_t)n * 128;
    unsigned int* h1 = (unsigned int*)alloc(h1b);                 // fp16 h1 | gpk1 scratch
    unsigned int* h2 = (unsigned int*)alloc((size_t)n * 64);      // fp16 h2
    float* sk02    = (float*)alloc((size_t)n * 32 * 4);
    float* sk13    = (float*)alloc((size_t)n * 16 * 4);
    size_t prebytes = (size_t)e * 4 > (size_t)n * 128 ? (size_t)e * 4 : (size_t)n * 128;
    unsigned int* preb = (unsigned int*)alloc(prebytes);          // fp16 table | gpk2 scratch
    unsigned int* gpk1 = h1;    // dead before gather1 writes h1
    unsigned int* gpk2 = preb;  // dead before gemmA writes preb

    auto cdiv = [](int a, int b) { return (a + b - 1) / b; };

    // CSR build: count -> scan -> coarse sort -> fine sort -> fused build
    hipMemsetAsync(flag, 0, 4, stream);
    hipMemsetAsync(gcnt, 0, MAXB * 4, stream);
    detect_kernel<<<1, 1024, 0, stream>>>(ei, flag);
    bin_count<<<1024, 256, 0, stream>>>(ei, e, flag, shift, gcnt);
    bin_scan_init<<<1, 1024, 0, stream>>>(gcnt, nbkt, ncb, base, gcursor, gcur1);
    scatter_coarse<<<cdiv(e, TILE1), SCAT_T, 0, stream>>>(ei, e, flag, shift, gcur1, gpk1);
    scatter_fine<<<ncb * 8, SCAT_T, 0, stream>>>(gpk1, base, nbkt, shift, gcursor, gpk2);
    bucket_build<<<nbkt, 256, 0, stream>>>(gpk2, base, shift, n, e, dinv, row_ptr, col);

    // fused GEMM A: preb = (x@W1)*dinv (fp16), sk02 = x@Wsk02 (fp32)
    gemm_fused<512, 128, 64, 32, false><<<cdiv(n, 128), 512, 0, stream>>>(
        x, W1, Wsk02, dinv, preb, sk02, n);
    // layer 1: h1 = relu(conv(x,W1,b1))  (stored fp16)
    gather_combine<64, false, true><<<cdiv(n, 4), 256, 0, stream>>>(
        (const uint4*)preb, row_ptr, col, dinv, b1, nullptr, nullptr, h1, nullptr, nullptr, n);

    // fused GEMM B (fp16 A): preb = (h1@W2)*dinv, sk13 = h1@Wsk13
    gemm_fused<512, 64, 32, 16, true><<<cdiv(n, 256), 512, 0, stream>>>(
        h1, W2, Wsk13, dinv, preb, sk13, n);
    // layer 2: h2 = relu(conv(h1,W2,b2) + x@Wsk02 + bsk02)  (stored fp16)
    gather_combine<32, false, true><<<cdiv(n, 4), 256, 0, stream>>>(
        (const uint4*)preb, row_ptr, col, dinv, b2, sk02, bsk02, h2, nullptr, nullptr, n);

    // GEMM C (fp16 A): preb = (h2@W3)*dinv
    gemm_fused<512, 32, 16, 0, true><<<cdiv(n, 512), 512, 0, stream>>>(
        h2, W3, nullptr, dinv, preb, nullptr, n);
    // layer 3 + head: d_out = sigmoid(relu(conv(h2,W3,b3)+h1@Wsk13+bsk13) @ Wlin + blin)
    gather_combine<16, true, false><<<cdiv(n, 4), 256, 0, stream>>>(
        (const uint4*)preb, row_ptr, col, dinv, b3, sk13, bsk13, d_out, Wlin, blin, n);
}

// Round 13
// 538.564 us; speedup vs baseline: 4.0120x; 1.1705x over previous
//
#include <hip/hip_runtime.h>
#include <hip/hip_fp16.h>
#include <math.h>

// Bucketed CSR build tunables.
#define MAXB 1024        // max fine buckets in LDS arrays
#define MAXCB 128        // max coarse buckets
#define TILE1 8192       // edges per scatter tile
#define SCAT_T 512
#define EPT1 (TILE1 / SCAT_T)
#define LCAP 13568       // bucket_build LDS col capacity

typedef _Float16 f16x8 __attribute__((ext_vector_type(8)));
typedef float f32x4 __attribute__((ext_vector_type(4)));

// ---------------- fp16 pack helpers ----------------

__device__ __forceinline__ unsigned int pack_f16(float a, float b) {
    __half2 h = __floats2half2_rn(a, b);
    return *reinterpret_cast<unsigned int*>(&h);
}
__device__ __forceinline__ float f16_lo(unsigned int u) {
    __half2 h = *reinterpret_cast<__half2*>(&u);
    return __low2float(h);
}
__device__ __forceinline__ float f16_hi(unsigned int u) {
    __half2 h = *reinterpret_cast<__half2*>(&u);
    return __high2float(h);
}
__device__ __forceinline__ void acc8(float* a, uint4 u) {
    a[0] += f16_lo(u.x); a[1] += f16_hi(u.x);
    a[2] += f16_lo(u.y); a[3] += f16_hi(u.y);
    a[4] += f16_lo(u.z); a[5] += f16_hi(u.z);
    a[6] += f16_lo(u.w); a[7] += f16_hi(u.w);
}
__device__ __forceinline__ void unpack8(uint4 u, float* v) {
    v[0] = f16_lo(u.x); v[1] = f16_hi(u.x);
    v[2] = f16_lo(u.y); v[3] = f16_hi(u.y);
    v[4] = f16_lo(u.z); v[5] = f16_hi(u.z);
    v[6] = f16_lo(u.w); v[7] = f16_hi(u.w);
}
__device__ __forceinline__ uint4 h2add4(uint4 a, uint4 b) {
    const __half2* pa = reinterpret_cast<const __half2*>(&a);
    const __half2* pb = reinterpret_cast<const __half2*>(&b);
    uint4 r;
    __half2* pr = reinterpret_cast<__half2*>(&r);
#pragma unroll
    for (int i = 0; i < 4; i++) pr[i] = __hadd2(pa[i], pb[i]);
    return r;
}

// ---------------- edge dtype detection (int32 vs int64) ----------------

__global__ void detect_kernel(const int* __restrict__ ei, int* __restrict__ flag) {
    int i = threadIdx.x;
    if (ei[2 * i + 1] != 0) atomicAdd(flag, 1);
}

__device__ __forceinline__ int load_src(const int* ei, int e, bool is64, int i) {
    return is64 ? ei[2 * i] : ei[i];
}
__device__ __forceinline__ int load_dst(const int* ei, int e, bool is64, int i) {
    return is64 ? ei[2 * e + 2 * i] : ei[e + i];
}

// ---------------- pass 1: per-fine-bucket edge counts ----------------

__global__ __launch_bounds__(256) void bin_count(const int* __restrict__ ei, int e,
                                                 const int* __restrict__ flag, int shift,
                                                 int* __restrict__ gcnt) {
    __shared__ int h[MAXB];
    for (int i = threadIdx.x; i < MAXB; i += 256) h[i] = 0;
    __syncthreads();
    bool is64 = (*flag == 0);
    int stride = gridDim.x * 256;
    for (int i = blockIdx.x * 256 + threadIdx.x; i < e; i += stride) {
        int d = load_dst(ei, e, is64, i);
        atomicAdd(&h[d >> shift], 1);
    }
    __syncthreads();
    for (int i = threadIdx.x; i < MAXB; i += 256)
        if (h[i]) atomicAdd(&gcnt[i], h[i]);
}

// ---------------- pass 2: scan fine counts; init fine + coarse cursors ----------

__global__ void bin_scan_init(const int* __restrict__ gcnt, int nb, int ncb,
                              int* __restrict__ base, int* __restrict__ gcursor,
                              int* __restrict__ gcur1) {
    __shared__ int sh[1024];
    __shared__ int ex[1024];
    int t = threadIdx.x;
    int v = (t < nb) ? gcnt[t] : 0;
    sh[t] = v;
    __syncthreads();
    for (int off = 1; off < 1024; off <<= 1) {
        int x = (t >= off) ? sh[t - off] : 0;
        __syncthreads();
        sh[t] += x;
        __syncthreads();
    }
    int excl = sh[t] - v;
    ex[t] = excl;
    if (t < nb) {
        base[t] = excl;
        gcursor[t] = excl;
        if (t == nb - 1) base[nb] = sh[t];
    }
    __syncthreads();
    if (t < ncb) gcur1[t] = ex[8 * t];
}

// ---------------- pass 3a: coarse scatter ----------------

__global__ __launch_bounds__(SCAT_T) void scatter_coarse(const int* __restrict__ ei, int e,
                                                         const int* __restrict__ flag,
                                                         int shift,
                                                         int* __restrict__ gcur1,
                                                         unsigned int* __restrict__ gpk1) {
    __shared__ int hist[MAXCB];
    __shared__ int lbase[MAXCB];
    __shared__ int delta[MAXCB];
    __shared__ int cur[MAXCB];
    __shared__ unsigned int sbuf[TILE1];
    __shared__ unsigned char sbkt[TILE1];
    __shared__ int sh[SCAT_T];

    const int t = threadIdx.x;
    const int pkshift = shift + 3;
    const int pkmask = (1 << pkshift) - 1;
    const bool is64 = (*flag == 0);
    const int tile0 = blockIdx.x * TILE1;
    const int cnt = min(TILE1, e - tile0);

    for (int i = t; i < MAXCB; i += SCAT_T) hist[i] = 0;
    __syncthreads();

    unsigned int pk[EPT1];
    int bk[EPT1];
#pragma unroll
    for (int k = 0; k < EPT1; k++) {
        int g = tile0 + k * SCAT_T + t;
        bk[k] = -1;
        if (g < e) {
            int s = load_src(ei, e, is64, g);
            int d = load_dst(ei, e, is64, g);
            pk[k] = ((unsigned int)s << pkshift) | (unsigned int)(d & pkmask);
            bk[k] = d >> pkshift;
            atomicAdd(&hist[bk[k]], 1);
        }
    }
    __syncthreads();

    {
        int v = (t < MAXCB) ? hist[t] : 0;
        sh[t] = v;
        __syncthreads();
        for (int off = 1; off < SCAT_T; off <<= 1) {
            int x = (t >= off) ? sh[t - off] : 0;
            __syncthreads();
            sh[t] += x;
            __syncthreads();
        }
        if (t < MAXCB) lbase[t] = sh[t] - v;
    }
    __syncthreads();

    if (t < MAXCB) {
        int c = hist[t];
        if (c > 0) delta[t] = atomicAdd(&gcur1[t], c) - lbase[t];
        cur[t] = lbase[t];
    }
    __syncthreads();

#pragma unroll
    for (int k = 0; k < EPT1; k++) {
        if (bk[k] >= 0) {
            int p = atomicAdd(&cur[bk[k]], 1);
            sbuf[p] = pk[k];
            sbkt[p] = (unsigned char)bk[k];
        }
    }
    __syncthreads();

    for (int i = t; i < cnt; i += SCAT_T)
        gpk1[delta[sbkt[i]] + i] = sbuf[i];
}

// ---------------- pass 3b: fine scatter within coarse buckets ----------------

__global__ __launch_bounds__(SCAT_T) void scatter_fine(const unsigned int* __restrict__ gpk1,
                                                       const int* __restrict__ base,
                                                       int nbkt, int shift,
                                                       int* __restrict__ gcursor,
                                                       unsigned int* __restrict__ gpk2) {
    __shared__ int hist[8];
    __shared__ int lbase[8];
    __shared__ int delta[8];
    __shared__ int cur[8];
    __shared__ unsigned int sbuf[TILE1];
    __shared__ unsigned char sbkt[TILE1];

    const int t = threadIdx.x;
    const int cb = blockIdx.x >> 3;
    const int s = blockIdx.x & 7;
    const int f0 = 8 * cb;
    const int fhiIdx = min(f0 + 8, nbkt);
    const int lo = base[f0];
    const int hi = base[fhiIdx];
    const int len = hi - lo;
    const int slo = lo + (int)((long long)len * s / 8);
    const int shi = lo + (int)((long long)len * (s + 1) / 8);

    for (int tile0 = slo; tile0 < shi; tile0 += TILE1) {
        const int cnt = min(TILE1, shi - tile0);
        if (t < 8) hist[t] = 0;
        __syncthreads();

        unsigned int pk[EPT1];
        int bk[EPT1];
#pragma unroll
        for (int k = 0; k < EPT1; k++) {
            int li = k * SCAT_T + t;
            bk[k] = -1;
            if (li < cnt) {
                pk[k] = gpk1[tile0 + li];
                bk[k] = (pk[k] >> shift) & 7;
                atomicAdd(&hist[bk[k]], 1);
            }
        }
        __syncthreads();

        if (t == 0) {
            int run = 0;
            for (int f = 0; f < 8; f++) { lbase[f] = run; run += hist[f]; }
        }
        __syncthreads();
        if (t < 8) {
            int c = hist[t];
            if (c > 0) delta[t] = atomicAdd(&gcursor[f0 + t], c) - lbase[t];
            cur[t] = lbase[t];
        }
        __syncthreads();

#pragma unroll
        for (int k = 0; k < EPT1; k++) {
            if (bk[k] >= 0) {
                int p = atomicAdd(&cur[bk[k]], 1);
                sbuf[p] = pk[k];
                sbkt[p] = (unsigned char)bk[k];
            }
        }
        __syncthreads();

        for (int i = t; i < cnt; i += SCAT_T)
            gpk2[delta[sbkt[i]] + i] = sbuf[i];
        __syncthreads();
    }
}

// ---------------- pass 4: fused dinv + row_ptr + CSR col ----------------

__global__ __launch_bounds__(256) void bucket_build(const unsigned int* __restrict__ gpk,
                                                    const int* __restrict__ base, int shift,
                                                    int n, int e, float* __restrict__ dinv,
                                                    int* __restrict__ row_ptr,
                                                    int* __restrict__ col) {
    __shared__ int lcol[LCAP];
    __shared__ int dc[MAXB];
    __shared__ int cur[MAXB];
    __shared__ int sh[256];
    const int t = threadIdx.x;
    const int b = blockIdx.x;
    const int pkshift = shift + 3;
    const int mask = (1 << shift) - 1;
    const int width = 1 << shift;
    const int node0 = b << shift;
    const int nc = min(width, n - node0);
    const int lo = base[b], hi = base[b + 1];
    const int ecnt = hi - lo;

    for (int i = t; i < width; i += 256) dc[i] = 0;
    __syncthreads();
    for (int j = lo + t; j < hi; j += 256)
        atomicAdd(&dc[gpk[j] & mask], 1);
    __syncthreads();
    {
        int b4 = t * 4;
        int v0 = (b4 + 0 < width) ? dc[b4 + 0] : 0;
        int v1 = (b4 + 1 < width) ? dc[b4 + 1] : 0;
        int v2 = (b4 + 2 < width) ? dc[b4 + 2] : 0;
        int v3 = (b4 + 3 < width) ? dc[b4 + 3] : 0;
        int s = v0 + v1 + v2 + v3;
        sh[t] = s;
        __syncthreads();
        for (int off = 1; off < 256; off <<= 1) {
            int x = (t >= off) ? sh[t - off] : 0;
            __syncthreads();
            sh[t] += x;
            __syncthreads();
        }
        int excl = sh[t] - s;
        int pf[4] = {excl, excl + v0, excl + v0 + v1, excl + v0 + v1 + v2};
        int vv[4] = {v0, v1, v2, v3};
#pragma unroll
        for (int q = 0; q < 4; q++) {
            int i = b4 + q;
            if (i < nc) {
                row_ptr[node0 + i] = lo + pf[q];
                dinv[node0 + i] = rsqrtf(1.0f + (float)vv[q]);
            }
            if (i < width) cur[i] = pf[q];
        }
    }
    if (b == gridDim.x - 1 && t == 0) row_ptr[n] = e;
    __syncthreads();

    if (ecnt <= LCAP) {
        for (int j = lo + t; j < hi; j += 256) {
            unsigned int v = gpk[j];
            int p = atomicAdd(&cur[v & mask], 1);
            lcol[p] = (int)(v >> pkshift);
        }
        __syncthreads();
        for (int j = t; j < ecnt; j += 256)
            col[lo + j] = lcol[j];
    } else {
        for (int j = lo + t; j < hi; j += 256) {
            unsigned int v = gpk[j];
            int p = atomicAdd(&cur[v & mask], 1);
            col[lo + p] = (int)(v >> pkshift);
        }
    }
}

// ---------------- one-shot weight transpose+convert: W^T fp16 ----------------
// wt layout: [96][128] (W1|Wsk02) at 0; [48][64] (W2|Wsk13) at 12288;
// [16][32] (W3) at 15360. Row-major [col][k].

__global__ void prep_w(const float* __restrict__ W1, const float* __restrict__ Wsk02,
                       const float* __restrict__ W2, const float* __restrict__ Wsk13,
                       const float* __restrict__ W3, unsigned short* __restrict__ wt) {
    int i = blockIdx.x * 256 + threadIdx.x;
    float v;
    if (i < 12288) {
        int c = i >> 7, k = i & 127;
        v = (c < 64) ? W1[k * 64 + c] : Wsk02[k * 32 + (c - 64)];
    } else if (i < 15360) {
        int j = i - 12288;
        int c = j >> 6, k = j & 63;
        v = (c < 32) ? W2[k * 32 + c] : Wsk13[k * 16 + (c - 32)];
    } else if (i < 15872) {
        int j = i - 15360;
        int c = j >> 5, k = j & 31;
        v = W3[k * 16 + c];
    } else return;
    wt[i] = (unsigned short)pack_f16(v, 0.f);
}

// ---------------- MFMA GEMM: out1[n,CO1]=(A@W1)*dinv fp16; out2[n,CO2]=A@W2 fp32 ----
// BM=64 rows/block, 4 waves x 16 rows, full K in LDS (no K-loop).
// v_mfma_f32_16x16x32_f16; A frag: row=lane&15, k=(lane>>4)*8+[0..8);
// C/D: col=lane&15, row=(lane>>4)*4+reg [guide m89]. XOR-swizzled LDS (G4).
// R13: replaces the VALU gemm_fused (gemmA stuck ~110-125us: 31us of FMA on
// the vector pipe + latency; MFMA makes it pure staging-bandwidth).

template <int K, int CO1, int CO2, bool AHALF>
__global__ __launch_bounds__(256) void gemm_mfma(const void* __restrict__ Av,
                                                 const unsigned short* __restrict__ wt,
                                                 const float* __restrict__ dinv,
                                                 unsigned int* __restrict__ out1,
                                                 float* __restrict__ out2, int n) {
    constexpr int N = CO1 + CO2;
    constexpr int NCT = N / 16;            // 16-col MFMA tiles
    constexpr int NK = K / 32;             // 32-k MFMA steps
    constexpr int CHK = K / 8;             // 16B chunks per row
    constexpr int SWZ = (CHK - 1) < 15 ? (CHK - 1) : 15;
    __shared__ __align__(16) unsigned char Ash[64 * K * 2];
    __shared__ __align__(16) unsigned char Bsh[N * K * 2];

    const int t = threadIdx.x;
    const int row0 = blockIdx.x * 64;

    // stage A (64 x K fp16, swizzled)
    for (int i = t; i < 64 * CHK; i += 256) {
        int r = i / CHK, c = i % CHK;
        int row = row0 + r;
        uint4 w{0u, 0u, 0u, 0u};
        if (row < n) {
            if (AHALF) {
                w = *reinterpret_cast<const uint4*>(
                    (const unsigned short*)Av + (size_t)row * K + c * 8);
            } else {
                const float* xr = (const float*)Av + (size_t)row * K + c * 8;
                float4 p = *reinterpret_cast<const float4*>(xr);
                float4 q = *reinterpret_cast<const float4*>(xr + 4);
                w.x = pack_f16(p.x, p.y); w.y = pack_f16(p.z, p.w);
                w.z = pack_f16(q.x, q.y); w.w = pack_f16(q.z, q.w);
            }
        }
        int addr = i * 16;
        addr ^= ((r & SWZ) << 4);
        *reinterpret_cast<uint4*>(&Ash[addr]) = w;
    }
    // stage B (N x K fp16 from wt, swizzled)
    for (int i = t; i < N * CHK; i += 256) {
        int cc = i / CHK;
        uint4 w = *reinterpret_cast<const uint4*>(&wt[(i / CHK) * K + (i % CHK) * 8]);
        int addr = i * 16;
        addr ^= ((cc & SWZ) << 4);
        *reinterpret_cast<uint4*>(&Bsh[addr]) = w;
    }
    __syncthreads();

    const int wv = t >> 6;
    const int lane = t & 63;
    const int lrow = wv * 16 + (lane & 15);
    const int kb = (lane >> 4) * 16;       // byte offset of lane's 8-f16 slice in 32-k step

    f16x8 afr[NK];
#pragma unroll
    for (int s = 0; s < NK; s++) {
        int addr = lrow * (2 * K) + s * 64 + kb;
        addr ^= ((lrow & SWZ) << 4);
        afr[s] = *reinterpret_cast<const f16x8*>(&Ash[addr]);
    }

    f32x4 acc[NCT];
#pragma unroll
    for (int ct = 0; ct < NCT; ct++) acc[ct] = f32x4{0.f, 0.f, 0.f, 0.f};

#pragma unroll
    for (int ct = 0; ct < NCT; ct++) {
        int cc = ct * 16 + (lane & 15);
#pragma unroll
        for (int s = 0; s < NK; s++) {
            int addr = cc * (2 * K) + s * 64 + kb;
            addr ^= ((cc & SWZ) << 4);
            f16x8 bfr = *reinterpret_cast<const f16x8*>(&Bsh[addr]);
            acc[ct] = __builtin_amdgcn_mfma_f32_16x16x32_f16(afr[s], bfr, acc[ct], 0, 0, 0);
        }
    }

    // epilogue: C/D col=lane&15, row=(lane>>4)*4+reg
    const int rbase = row0 + wv * 16 + (lane >> 4) * 4;
    const int cidx = lane & 15;
    float dn[4];
#pragma unroll
    for (int r = 0; r < 4; r++) dn[r] = (rbase + r < n) ? dinv[rbase + r] : 0.f;

#pragma unroll
    for (int ct = 0; ct < NCT; ct++) {
        int col = ct * 16 + cidx;
        if (col < CO1) {
#pragma unroll
            for (int r = 0; r < 4; r++) {
                float v = acc[ct][r] * dn[r];
                float o = __shfl_xor(v, 1);
                int row = rbase + r;
                if (!(lane & 1) && row < n)
                    out1[(size_t)row * (CO1 / 2) + ct * 8 + cidx / 2] = pack_f16(v, o);
            }
        } else if (CO2 > 0) {
#pragma unroll
            for (int r = 0; r < 4; r++) {
                int row = rbase + r;
                if (row < n) out2[(size_t)row * CO2 + (col - CO1)] = acc[ct][r];
            }
        }
    }
}

// ---------------- Fused gather + self-loop + bias + skip + relu (+head) ----------------

template <int F, bool FINAL, bool PACKOUT>
__global__ __launch_bounds__(256) void gather_combine(
    const uint4* __restrict__ hp4, const int* __restrict__ row_ptr,
    const int* __restrict__ col, const float* __restrict__ dinv,
    const float* __restrict__ bias, const float* __restrict__ sk,
    const float* __restrict__ bsk, void* __restrict__ outv,
    const float* __restrict__ Wlin, const float* __restrict__ blin, int n) {
    constexpr int L = F / 8;
    constexpr int EPW = 64 / L;
    int wid = (blockIdx.x * blockDim.x + threadIdx.x) >> 6;
    int lane = threadIdx.x & 63;
    if (wid >= n) return;
    int s = lane / L;
    int el = lane % L;
    int start = row_ptr[wid];
    int end = row_ptr[wid + 1];

    float a[8] = {0.f, 0.f, 0.f, 0.f, 0.f, 0.f, 0.f, 0.f};
    int j = start + s;
    while (j + 3 * EPW < end) {
        int c0 = col[j];
        int c1 = col[j + EPW];
        int c2 = col[j + 2 * EPW];
        int c3 = col[j + 3 * EPW];
        uint4 u0 = hp4[(size_t)c0 * L + el];
        uint4 u1 = hp4[(size_t)c1 * L + el];
        uint4 u2 = hp4[(size_t)c2 * L + el];
        uint4 u3 = hp4[(size_t)c3 * L + el];
        uint4 t01 = h2add4(u0, u1);
        uint4 t23 = h2add4(u2, u3);
        acc8(a, h2add4(t01, t23));
        j += 4 * EPW;
    }
    while (j < end) {
        uint4 u = hp4[(size_t)col[j] * L + el];
        acc8(a, u);
        j += EPW;
    }

#pragma unroll
    for (int m = L; m < 64; m <<= 1) {
#pragma unroll
        for (int q = 0; q < 8; q++) a[q] += __shfl_xor(a[q], m);
    }

    if (lane < L) {
        float dn = dinv[wid];
        uint4 us = hp4[(size_t)wid * L + el];
        float v[8];
        unpack8(us, v);
        float4 b0 = *reinterpret_cast<const float4*>(&bias[8 * el]);
        float4 b1 = *reinterpret_cast<const float4*>(&bias[8 * el + 4]);
        float o[8];
        o[0] = dn * a[0] + v[0] * dn + b0.x;
        o[1] = dn * a[1] + v[1] * dn + b0.y;
        o[2] = dn * a[2] + v[2] * dn + b0.z;
        o[3] = dn * a[3] + v[3] * dn + b0.w;
        o[4] = dn * a[4] + v[4] * dn + b1.x;
        o[5] = dn * a[5] + v[5] * dn + b1.y;
        o[6] = dn * a[6] + v[6] * dn + b1.z;
        o[7] = dn * a[7] + v[7] * dn + b1.w;
        if (sk) {
            float4 s0 = *reinterpret_cast<const float4*>(&sk[(size_t)wid * F + 8 * el]);
            float4 s1 = *reinterpret_cast<const float4*>(&sk[(size_t)wid * F + 8 * el + 4]);
            float4 k0 = *reinterpret_cast<const float4*>(&bsk[8 * el]);
            float4 k1 = *reinterpret_cast<const float4*>(&bsk[8 * el + 4]);
            o[0] += s0.x + k0.x; o[1] += s0.y + k0.y;
            o[2] += s0.z + k0.z; o[3] += s0.w + k0.w;
            o[4] += s1.x + k1.x; o[5] += s1.y + k1.y;
            o[6] += s1.z + k1.z; o[7] += s1.w + k1.w;
        }
#pragma unroll
        for (int q = 0; q < 8; q++) o[q] = fmaxf(o[q], 0.f);
        if (FINAL) {
            float4 wl0 = *reinterpret_cast<const float4*>(&Wlin[8 * el]);
            float4 wl1 = *reinterpret_cast<const float4*>(&Wlin[8 * el + 4]);
            float d = o[0] * wl0.x + o[1] * wl0.y + o[2] * wl0.z + o[3] * wl0.w +
                      o[4] * wl1.x + o[5] * wl1.y + o[6] * wl1.z + o[7] * wl1.w;
            d += __shfl_xor(d, 1);
            if (el == 0) ((float*)outv)[wid] = 1.0f / (1.0f + expf(-(d + blin[0])));
        } else if (PACKOUT) {
            uint4 pk{pack_f16(o[0], o[1]), pack_f16(o[2], o[3]),
                     pack_f16(o[4], o[5]), pack_f16(o[6], o[7])};
            ((uint4*)outv)[(size_t)wid * L + el] = pk;
        } else {
            float* out = (float*)outv;
            float4 w0{o[0], o[1], o[2], o[3]};
            float4 w1{o[4], o[5], o[6], o[7]};
            *reinterpret_cast<float4*>(&out[(size_t)wid * F + 8 * el]) = w0;
            *reinterpret_cast<float4*>(&out[(size_t)wid * F + 8 * el + 4]) = w1;
        }
    }
}

// ---------------- launch ----------------

extern "C" void kernel_launch(void* const* d_in, const int* in_sizes, int n_in,
                              void* d_out, int out_size, void* d_ws, size_t ws_size,
                              hipStream_t stream) {
    const float* x     = (const float*)d_in[0];
    const int*   ei    = (const int*)d_in[1];
    const float* W1    = (const float*)d_in[2];
    const float* b1    = (const float*)d_in[3];
    const float* W2    = (const float*)d_in[4];
    const float* b2    = (const float*)d_in[5];
    const float* W3    = (const float*)d_in[6];
    const float* b3    = (const float*)d_in[7];
    const float* Wsk02 = (const float*)d_in[8];
    const float* bsk02 = (const float*)d_in[9];
    const float* Wsk13 = (const float*)d_in[10];
    const float* bsk13 = (const float*)d_in[11];
    const float* Wlin  = (const float*)d_in[12];
    const float* blin  = (const float*)d_in[13];

    const int n = in_sizes[0] / 128;
    const int e = in_sizes[1] / 2;

    int shift = 8;
    while (((n + (1 << shift) - 1) >> shift) > MAXB) shift++;
    const int nbkt = (n + (1 << shift) - 1) >> shift;
    const int ncb = (nbkt + 7) / 8;

    // workspace carve (256B aligned)
    char* p = (char*)d_ws;
    auto alloc = [&](size_t bytes) {
        void* r = (void*)p;
        p += (bytes + 255) / 256 * 256;
        return r;
    };
    int*   flag    = (int*)alloc(256);
    int*   gcnt    = (int*)alloc(MAXB * 4);
    int*   base    = (int*)alloc((MAXB + 1) * 4);
    int*   gcursor = (int*)alloc(MAXB * 4);
    int*   gcur1   = (int*)alloc(MAXCB * 4);
    unsigned short* wt = (unsigned short*)alloc(15872 * 2);       // fp16 W^T (all layers)
    int*   row_ptr = (int*)alloc((size_t)(n + 1) * 4);
    float* dinv    = (float*)alloc((size_t)n * 4);
    int*   col     = (int*)alloc((size_t)e * 4);
    size_t h1b     = (size_t)e * 4 > (size_t)n * 128 ? (size_t)e * 4 : (size_t)n * 128;
    unsigned int* h1 = (unsigned int*)alloc(h1b);                 // fp16 h1 | gpk1 scratch
    unsigned int* h2 = (unsigned int*)alloc((size_t)n * 64);      // fp16 h2
    float* sk02    = (float*)alloc((size_t)n * 32 * 4);
    float* sk13    = (float*)alloc((size_t)n * 16 * 4);
    size_t prebytes = (size_t)e * 4 > (size_t)n * 128 ? (size_t)e * 4 : (size_t)n * 128;
    unsigned int* preb = (unsigned int*)alloc(prebytes);          // fp16 table | gpk2 scratch
    unsigned int* gpk1 = h1;
    unsigned int* gpk2 = preb;

    auto cdiv = [](int a, int b) { return (a + b - 1) / b; };

    // weight prep (independent)
    prep_w<<<62, 256, 0, stream>>>(W1, Wsk02, W2, Wsk13, W3, wt);

    // CSR build
    hipMemsetAsync(flag, 0, 4, stream);
    hipMemsetAsync(gcnt, 0, MAXB * 4, stream);
    detect_kernel<<<1, 1024, 0, stream>>>(ei, flag);
    bin_count<<<1024, 256, 0, stream>>>(ei, e, flag, shift, gcnt);
    bin_scan_init<<<1, 1024, 0, stream>>>(gcnt, nbkt, ncb, base, gcursor, gcur1);
    scatter_coarse<<<cdiv(e, TILE1), SCAT_T, 0, stream>>>(ei, e, flag, shift, gcur1, gpk1);
    scatter_fine<<<ncb * 8, SCAT_T, 0, stream>>>(gpk1, base, nbkt, shift, gcursor, gpk2);
    bucket_build<<<nbkt, 256, 0, stream>>>(gpk2, base, shift, n, e, dinv, row_ptr, col);

    // GEMM A (MFMA): preb = (x@W1)*dinv fp16, sk02 = x@Wsk02 fp32
    gemm_mfma<128, 64, 32, false><<<cdiv(n, 64), 256, 0, stream>>>(
        x, wt, dinv, preb, sk02, n);
    // layer 1: h1 = relu(conv(x,W1,b1))  (fp16)
    gather_combine<64, false, true><<<cdiv(n, 4), 256, 0, stream>>>(
        (const uint4*)preb, row_ptr, col, dinv, b1, nullptr, nullptr, h1, nullptr, nullptr, n);

    // GEMM B (MFMA, fp16 A): preb = (h1@W2)*dinv, sk13 = h1@Wsk13
    gemm_mfma<64, 32, 16, true><<<cdiv(n, 64), 256, 0, stream>>>(
        h1, wt + 12288, dinv, preb, sk13, n);
    // layer 2: h2 = relu(conv(h1,W2,b2) + x@Wsk02 + bsk02)  (fp16)
    gather_combine<32, false, true><<<cdiv(n, 4), 256, 0, stream>>>(
        (const uint4*)preb, row_ptr, col, dinv, b2, sk02, bsk02, h2, nullptr, nullptr, n);

    // GEMM C (MFMA, fp16 A): preb = (h2@W3)*dinv
    gemm_mfma<32, 16, 0, true><<<cdiv(n, 64), 256, 0, stream>>>(
        h2, wt + 15360, dinv, preb, sk13, n);
    // layer 3 + head
    gather_combine<16, true, false><<<cdiv(n, 4), 256, 0, stream>>>(
        (const uint4*)preb, row_ptr, col, dinv, b3, sk13, bsk13, d_out, Wlin, blin, n);
}

// Round 14
// 516.818 us; speedup vs baseline: 4.1808x; 1.0421x over previous
//
#include <hip/hip_runtime.h>
#include <hip/hip_fp16.h>
#include <math.h>

// Bucketed CSR build tunables.
#define MAXB 1024        // max fine buckets in LDS arrays
#define MAXCB 128        // max coarse buckets
#define TILE1 8192       // edges per scatter tile
#define SCAT_T 512
#define EPT1 (TILE1 / SCAT_T)
#define LCAP 13568       // bucket_build LDS col capacity

typedef _Float16 f16x8 __attribute__((ext_vector_type(8)));
typedef float f32x4 __attribute__((ext_vector_type(4)));

// ---------------- fp16 pack helpers ----------------

__device__ __forceinline__ unsigned int pack_f16(float a, float b) {
    __half2 h = __floats2half2_rn(a, b);
    return *reinterpret_cast<unsigned int*>(&h);
}
__device__ __forceinline__ float f16_lo(unsigned int u) {
    __half2 h = *reinterpret_cast<__half2*>(&u);
    return __low2float(h);
}
__device__ __forceinline__ float f16_hi(unsigned int u) {
    __half2 h = *reinterpret_cast<__half2*>(&u);
    return __high2float(h);
}
__device__ __forceinline__ void acc8(float* a, uint4 u) {
    a[0] += f16_lo(u.x); a[1] += f16_hi(u.x);
    a[2] += f16_lo(u.y); a[3] += f16_hi(u.y);
    a[4] += f16_lo(u.z); a[5] += f16_hi(u.z);
    a[6] += f16_lo(u.w); a[7] += f16_hi(u.w);
}
__device__ __forceinline__ void unpack8(uint4 u, float* v) {
    v[0] = f16_lo(u.x); v[1] = f16_hi(u.x);
    v[2] = f16_lo(u.y); v[3] = f16_hi(u.y);
    v[4] = f16_lo(u.z); v[5] = f16_hi(u.z);
    v[6] = f16_lo(u.w); v[7] = f16_hi(u.w);
}
__device__ __forceinline__ uint4 h2add4(uint4 a, uint4 b) {
    const __half2* pa = reinterpret_cast<const __half2*>(&a);
    const __half2* pb = reinterpret_cast<const __half2*>(&b);
    uint4 r;
    __half2* pr = reinterpret_cast<__half2*>(&r);
#pragma unroll
    for (int i = 0; i < 4; i++) pr[i] = __hadd2(pa[i], pb[i]);
    return r;
}

// ---------------- inline edge dtype detection (int32 vs int64) ----------------
// int64 little-endian values < 2^31 have every odd 32-bit word zero; int32
// random node ids make odd words nonzero. 64 samples via wave ballot —
// deterministic, same result in every wave of every block.

__device__ __forceinline__ bool detect64(const int* __restrict__ ei) {
    int lane = threadIdx.x & 63;
    unsigned long long m = __ballot(ei[2 * lane + 1] != 0);
    return m == 0ull;
}

__device__ __forceinline__ int load_src(const int* ei, int e, bool is64, int i) {
    return is64 ? ei[2 * i] : ei[i];
}
__device__ __forceinline__ int load_dst(const int* ei, int e, bool is64, int i) {
    return is64 ? ei[2 * e + 2 * i] : ei[e + i];
}

// ---------------- pass 1: per-fine-bucket edge counts ----------------

__global__ __launch_bounds__(256) void bin_count(const int* __restrict__ ei, int e,
                                                 int shift, int* __restrict__ gcnt) {
    __shared__ int h[MAXB];
    for (int i = threadIdx.x; i < MAXB; i += 256) h[i] = 0;
    bool is64 = detect64(ei);
    __syncthreads();
    int stride = gridDim.x * 256;
    for (int i = blockIdx.x * 256 + threadIdx.x; i < e; i += stride) {
        int d = load_dst(ei, e, is64, i);
        atomicAdd(&h[d >> shift], 1);
    }
    __syncthreads();
    for (int i = threadIdx.x; i < MAXB; i += 256)
        if (h[i]) atomicAdd(&gcnt[i], h[i]);
}

// ---------------- pass 2: scan fine counts; init fine + coarse cursors ----------

__global__ void bin_scan_init(const int* __restrict__ gcnt, int nb, int ncb,
                              int* __restrict__ base, int* __restrict__ gcursor,
                              int* __restrict__ gcur1) {
    __shared__ int sh[1024];
    __shared__ int ex[1024];
    int t = threadIdx.x;
    int v = (t < nb) ? gcnt[t] : 0;
    sh[t] = v;
    __syncthreads();
    for (int off = 1; off < 1024; off <<= 1) {
        int x = (t >= off) ? sh[t - off] : 0;
        __syncthreads();
        sh[t] += x;
        __syncthreads();
    }
    int excl = sh[t] - v;
    ex[t] = excl;
    if (t < nb) {
        base[t] = excl;
        gcursor[t] = excl;
        if (t == nb - 1) base[nb] = sh[t];
    }
    __syncthreads();
    if (t < ncb) gcur1[t] = ex[8 * t];
}

// ---------------- pass 3a: coarse scatter ----------------

__global__ __launch_bounds__(SCAT_T) void scatter_coarse(const int* __restrict__ ei, int e,
                                                         int shift,
                                                         int* __restrict__ gcur1,
                                                         unsigned int* __restrict__ gpk1) {
    __shared__ int hist[MAXCB];
    __shared__ int lbase[MAXCB];
    __shared__ int delta[MAXCB];
    __shared__ int cur[MAXCB];
    __shared__ unsigned int sbuf[TILE1];
    __shared__ unsigned char sbkt[TILE1];
    __shared__ int sh[SCAT_T];

    const int t = threadIdx.x;
    const int pkshift = shift + 3;
    const int pkmask = (1 << pkshift) - 1;
    const bool is64 = detect64(ei);
    const int tile0 = blockIdx.x * TILE1;
    const int cnt = min(TILE1, e - tile0);

    for (int i = t; i < MAXCB; i += SCAT_T) hist[i] = 0;
    __syncthreads();

    unsigned int pk[EPT1];
    int bk[EPT1];
#pragma unroll
    for (int k = 0; k < EPT1; k++) {
        int g = tile0 + k * SCAT_T + t;
        bk[k] = -1;
        if (g < e) {
            int s = load_src(ei, e, is64, g);
            int d = load_dst(ei, e, is64, g);
            pk[k] = ((unsigned int)s << pkshift) | (unsigned int)(d & pkmask);
            bk[k] = d >> pkshift;
            atomicAdd(&hist[bk[k]], 1);
        }
    }
    __syncthreads();

    {
        int v = (t < MAXCB) ? hist[t] : 0;
        sh[t] = v;
        __syncthreads();
        for (int off = 1; off < SCAT_T; off <<= 1) {
            int x = (t >= off) ? sh[t - off] : 0;
            __syncthreads();
            sh[t] += x;
            __syncthreads();
        }
        if (t < MAXCB) lbase[t] = sh[t] - v;
    }
    __syncthreads();

    if (t < MAXCB) {
        int c = hist[t];
        if (c > 0) delta[t] = atomicAdd(&gcur1[t], c) - lbase[t];
        cur[t] = lbase[t];
    }
    __syncthreads();

#pragma unroll
    for (int k = 0; k < EPT1; k++) {
        if (bk[k] >= 0) {
            int p = atomicAdd(&cur[bk[k]], 1);
            sbuf[p] = pk[k];
            sbkt[p] = (unsigned char)bk[k];
        }
    }
    __syncthreads();

    for (int i = t; i < cnt; i += SCAT_T)
        gpk1[delta[sbkt[i]] + i] = sbuf[i];
}

// ---------------- pass 3b: fine scatter within coarse buckets ----------------

__global__ __launch_bounds__(SCAT_T) void scatter_fine(const unsigned int* __restrict__ gpk1,
                                                       const int* __restrict__ base,
                                                       int nbkt, int shift,
                                                       int* __restrict__ gcursor,
                                                       unsigned int* __restrict__ gpk2) {
    __shared__ int hist[8];
    __shared__ int lbase[8];
    __shared__ int delta[8];
    __shared__ int cur[8];
    __shared__ unsigned int sbuf[TILE1];
    __shared__ unsigned char sbkt[TILE1];

    const int t = threadIdx.x;
    const int cb = blockIdx.x >> 3;
    const int s = blockIdx.x & 7;
    const int f0 = 8 * cb;
    const int fhiIdx = min(f0 + 8, nbkt);
    const int lo = base[f0];
    const int hi = base[fhiIdx];
    const int len = hi - lo;
    const int slo = lo + (int)((long long)len * s / 8);
    const int shi = lo + (int)((long long)len * (s + 1) / 8);

    for (int tile0 = slo; tile0 < shi; tile0 += TILE1) {
        const int cnt = min(TILE1, shi - tile0);
        if (t < 8) hist[t] = 0;
        __syncthreads();

        unsigned int pk[EPT1];
        int bk[EPT1];
#pragma unroll
        for (int k = 0; k < EPT1; k++) {
            int li = k * SCAT_T + t;
            bk[k] = -1;
            if (li < cnt) {
                pk[k] = gpk1[tile0 + li];
                bk[k] = (pk[k] >> shift) & 7;
                atomicAdd(&hist[bk[k]], 1);
            }
        }
        __syncthreads();

        if (t == 0) {
            int run = 0;
            for (int f = 0; f < 8; f++) { lbase[f] = run; run += hist[f]; }
        }
        __syncthreads();
        if (t < 8) {
            int c = hist[t];
            if (c > 0) delta[t] = atomicAdd(&gcursor[f0 + t], c) - lbase[t];
            cur[t] = lbase[t];
        }
        __syncthreads();

#pragma unroll
        for (int k = 0; k < EPT1; k++) {
            if (bk[k] >= 0) {
                int p = atomicAdd(&cur[bk[k]], 1);
                sbuf[p] = pk[k];
                sbkt[p] = (unsigned char)bk[k];
            }
        }
        __syncthreads();

        for (int i = t; i < cnt; i += SCAT_T)
            gpk2[delta[sbkt[i]] + i] = sbuf[i];
        __syncthreads();
    }
}

// ---------------- pass 4: fused dinv + row_ptr + CSR col ----------------

__global__ __launch_bounds__(256) void bucket_build(const unsigned int* __restrict__ gpk,
                                                    const int* __restrict__ base, int shift,
                                                    int n, int e, float* __restrict__ dinv,
                                                    int* __restrict__ row_ptr,
                                                    int* __restrict__ col) {
    __shared__ int lcol[LCAP];
    __shared__ int dc[MAXB];
    __shared__ int cur[MAXB];
    __shared__ int sh[256];
    const int t = threadIdx.x;
    const int b = blockIdx.x;
    const int pkshift = shift + 3;
    const int mask = (1 << shift) - 1;
    const int width = 1 << shift;
    const int node0 = b << shift;
    const int nc = min(width, n - node0);
    const int lo = base[b], hi = base[b + 1];
    const int ecnt = hi - lo;

    for (int i = t; i < width; i += 256) dc[i] = 0;
    __syncthreads();
    for (int j = lo + t; j < hi; j += 256)
        atomicAdd(&dc[gpk[j] & mask], 1);
    __syncthreads();
    {
        int b4 = t * 4;
        int v0 = (b4 + 0 < width) ? dc[b4 + 0] : 0;
        int v1 = (b4 + 1 < width) ? dc[b4 + 1] : 0;
        int v2 = (b4 + 2 < width) ? dc[b4 + 2] : 0;
        int v3 = (b4 + 3 < width) ? dc[b4 + 3] : 0;
        int s = v0 + v1 + v2 + v3;
        sh[t] = s;
        __syncthreads();
        for (int off = 1; off < 256; off <<= 1) {
            int x = (t >= off) ? sh[t - off] : 0;
            __syncthreads();
            sh[t] += x;
            __syncthreads();
        }
        int excl = sh[t] - s;
        int pf[4] = {excl, excl + v0, excl + v0 + v1, excl + v0 + v1 + v2};
        int vv[4] = {v0, v1, v2, v3};
#pragma unroll
        for (int q = 0; q < 4; q++) {
            int i = b4 + q;
            if (i < nc) {
                row_ptr[node0 + i] = lo + pf[q];
                dinv[node0 + i] = rsqrtf(1.0f + (float)vv[q]);
            }
            if (i < width) cur[i] = pf[q];
        }
    }
    if (b == gridDim.x - 1 && t == 0) row_ptr[n] = e;
    __syncthreads();

    if (ecnt <= LCAP) {
        for (int j = lo + t; j < hi; j += 256) {
            unsigned int v = gpk[j];
            int p = atomicAdd(&cur[v & mask], 1);
            lcol[p] = (int)(v >> pkshift);
        }
        __syncthreads();
        for (int j = t; j < ecnt; j += 256)
            col[lo + j] = lcol[j];
    } else {
        for (int j = lo + t; j < hi; j += 256) {
            unsigned int v = gpk[j];
            int p = atomicAdd(&cur[v & mask], 1);
            col[lo + p] = (int)(v >> pkshift);
        }
    }
}

// ---------------- one-shot weight transpose+convert: W^T fp16 ----------------

__global__ void prep_w(const float* __restrict__ W1, const float* __restrict__ Wsk02,
                       const float* __restrict__ W2, const float* __restrict__ Wsk13,
                       const float* __restrict__ W3, unsigned short* __restrict__ wt) {
    int i = blockIdx.x * 256 + threadIdx.x;
    float v;
    if (i < 12288) {
        int c = i >> 7, k = i & 127;
        v = (c < 64) ? W1[k * 64 + c] : Wsk02[k * 32 + (c - 64)];
    } else if (i < 15360) {
        int j = i - 12288;
        int c = j >> 6, k = j & 63;
        v = (c < 32) ? W2[k * 32 + c] : Wsk13[k * 16 + (c - 32)];
    } else if (i < 15872) {
        int j = i - 15360;
        int c = j >> 5, k = j & 31;
        v = W3[k * 16 + c];
    } else return;
    wt[i] = (unsigned short)pack_f16(v, 0.f);
}

// ---------------- MFMA GEMM (R13, verified) ----------------

template <int K, int CO1, int CO2, bool AHALF>
__global__ __launch_bounds__(256) void gemm_mfma(const void* __restrict__ Av,
                                                 const unsigned short* __restrict__ wt,
                                                 const float* __restrict__ dinv,
                                                 unsigned int* __restrict__ out1,
                                                 float* __restrict__ out2, int n) {
    constexpr int N = CO1 + CO2;
    constexpr int NCT = N / 16;
    constexpr int NK = K / 32;
    constexpr int CHK = K / 8;
    constexpr int SWZ = (CHK - 1) < 15 ? (CHK - 1) : 15;
    __shared__ __align__(16) unsigned char Ash[64 * K * 2];
    __shared__ __align__(16) unsigned char Bsh[N * K * 2];

    const int t = threadIdx.x;
    const int row0 = blockIdx.x * 64;

    for (int i = t; i < 64 * CHK; i += 256) {
        int r = i / CHK, c = i % CHK;
        int row = row0 + r;
        uint4 w{0u, 0u, 0u, 0u};
        if (row < n) {
            if (AHALF) {
                w = *reinterpret_cast<const uint4*>(
                    (const unsigned short*)Av + (size_t)row * K + c * 8);
            } else {
                const float* xr = (const float*)Av + (size_t)row * K + c * 8;
                float4 p = *reinterpret_cast<const float4*>(xr);
                float4 q = *reinterpret_cast<const float4*>(xr + 4);
                w.x = pack_f16(p.x, p.y); w.y = pack_f16(p.z, p.w);
                w.z = pack_f16(q.x, q.y); w.w = pack_f16(q.z, q.w);
            }
        }
        int addr = i * 16;
        addr ^= ((r & SWZ) << 4);
        *reinterpret_cast<uint4*>(&Ash[addr]) = w;
    }
    for (int i = t; i < N * CHK; i += 256) {
        int cc = i / CHK;
        uint4 w = *reinterpret_cast<const uint4*>(&wt[(i / CHK) * K + (i % CHK) * 8]);
        int addr = i * 16;
        addr ^= ((cc & SWZ) << 4);
        *reinterpret_cast<uint4*>(&Bsh[addr]) = w;
    }
    __syncthreads();

    const int wv = t >> 6;
    const int lane = t & 63;
    const int lrow = wv * 16 + (lane & 15);
    const int kb = (lane >> 4) * 16;

    f16x8 afr[NK];
#pragma unroll
    for (int s = 0; s < NK; s++) {
        int addr = lrow * (2 * K) + s * 64 + kb;
        addr ^= ((lrow & SWZ) << 4);
        afr[s] = *reinterpret_cast<const f16x8*>(&Ash[addr]);
    }

    f32x4 acc[NCT];
#pragma unroll
    for (int ct = 0; ct < NCT; ct++) acc[ct] = f32x4{0.f, 0.f, 0.f, 0.f};

#pragma unroll
    for (int ct = 0; ct < NCT; ct++) {
        int cc = ct * 16 + (lane & 15);
#pragma unroll
        for (int s = 0; s < NK; s++) {
            int addr = cc * (2 * K) + s * 64 + kb;
            addr ^= ((cc & SWZ) << 4);
            f16x8 bfr = *reinterpret_cast<const f16x8*>(&Bsh[addr]);
            acc[ct] = __builtin_amdgcn_mfma_f32_16x16x32_f16(afr[s], bfr, acc[ct], 0, 0, 0);
        }
    }

    const int rbase = row0 + wv * 16 + (lane >> 4) * 4;
    const int cidx = lane & 15;
    float dn[4];
#pragma unroll
    for (int r = 0; r < 4; r++) dn[r] = (rbase + r < n) ? dinv[rbase + r] : 0.f;

#pragma unroll
    for (int ct = 0; ct < NCT; ct++) {
        int col = ct * 16 + cidx;
        if (col < CO1) {
#pragma unroll
            for (int r = 0; r < 4; r++) {
                float v = acc[ct][r] * dn[r];
                float o = __shfl_xor(v, 1);
                int row = rbase + r;
                if (!(lane & 1) && row < n)
                    out1[(size_t)row * (CO1 / 2) + ct * 8 + cidx / 2] = pack_f16(v, o);
            }
        } else if (CO2 > 0) {
#pragma unroll
            for (int r = 0; r < 4; r++) {
                int row = rbase + r;
                if (row < n) out2[(size_t)row * CO2 + (col - CO1)] = acc[ct][r];
            }
        }
    }
}

// ---------------- Fused gather + self-loop + bias + skip + relu (+head) ----------------
// ONE WAVE PER NODE; grid = cdiv(n,4), 256-thread blocks; uint4 loads; fp16
// tree-add. R14: PREDICATED 4-deep load loop — always 4 independent loads per
// round (OOB slots clamp to j, contribution zeroed). R13's guarded main loop
// (needs deg > 3*EPW = 48/96 for F=32/16) never ran at deg~32, pushing all
// edges through a serial 1-load tail.

template <int F, bool FINAL, bool PACKOUT>
__global__ __launch_bounds__(256) void gather_combine(
    const uint4* __restrict__ hp4, const int* __restrict__ row_ptr,
    const int* __restrict__ col, const float* __restrict__ dinv,
    const float* __restrict__ bias, const float* __restrict__ sk,
    const float* __restrict__ bsk, void* __restrict__ outv,
    const float* __restrict__ Wlin, const float* __restrict__ blin, int n) {
    constexpr int L = F / 8;
    constexpr int EPW = 64 / L;
    int wid = (blockIdx.x * blockDim.x + threadIdx.x) >> 6;
    int lane = threadIdx.x & 63;
    if (wid >= n) return;
    int s = lane / L;
    int el = lane % L;
    int start = row_ptr[wid];
    int end = row_ptr[wid + 1];

    float a[8] = {0.f, 0.f, 0.f, 0.f, 0.f, 0.f, 0.f, 0.f};
    const uint4 z4{0u, 0u, 0u, 0u};
    for (int j = start + s; j < end; j += 4 * EPW) {
        int j1 = j + EPW, j2 = j + 2 * EPW, j3 = j + 3 * EPW;
        bool v1 = j1 < end, v2 = j2 < end, v3 = j3 < end;
        int c0 = col[j];
        int c1 = col[v1 ? j1 : j];
        int c2 = col[v2 ? j2 : j];
        int c3 = col[v3 ? j3 : j];
        uint4 u0 = hp4[(size_t)c0 * L + el];
        uint4 u1 = hp4[(size_t)c1 * L + el];
        uint4 u2 = hp4[(size_t)c2 * L + el];
        uint4 u3 = hp4[(size_t)c3 * L + el];
        if (!v1) u1 = z4;
        if (!v2) u2 = z4;
        if (!v3) u3 = z4;
        uint4 t01 = h2add4(u0, u1);
        uint4 t23 = h2add4(u2, u3);
        acc8(a, h2add4(t01, t23));
    }

#pragma unroll
    for (int m = L; m < 64; m <<= 1) {
#pragma unroll
        for (int q = 0; q < 8; q++) a[q] += __shfl_xor(a[q], m);
    }

    if (lane < L) {
        float dn = dinv[wid];
        uint4 us = hp4[(size_t)wid * L + el];
        float v[8];
        unpack8(us, v);
        float4 b0 = *reinterpret_cast<const float4*>(&bias[8 * el]);
        float4 b1 = *reinterpret_cast<const float4*>(&bias[8 * el + 4]);
        float o[8];
        o[0] = dn * a[0] + v[0] * dn + b0.x;
        o[1] = dn * a[1] + v[1] * dn + b0.y;
        o[2] = dn * a[2] + v[2] * dn + b0.z;
        o[3] = dn * a[3] + v[3] * dn + b0.w;
        o[4] = dn * a[4] + v[4] * dn + b1.x;
        o[5] = dn * a[5] + v[5] * dn + b1.y;
        o[6] = dn * a[6] + v[6] * dn + b1.z;
        o[7] = dn * a[7] + v[7] * dn + b1.w;
        if (sk) {
            float4 s0 = *reinterpret_cast<const float4*>(&sk[(size_t)wid * F + 8 * el]);
            float4 s1 = *reinterpret_cast<const float4*>(&sk[(size_t)wid * F + 8 * el + 4]);
            float4 k0 = *reinterpret_cast<const float4*>(&bsk[8 * el]);
            float4 k1 = *reinterpret_cast<const float4*>(&bsk[8 * el + 4]);
            o[0] += s0.x + k0.x; o[1] += s0.y + k0.y;
            o[2] += s0.z + k0.z; o[3] += s0.w + k0.w;
            o[4] += s1.x + k1.x; o[5] += s1.y + k1.y;
            o[6] += s1.z + k1.z; o[7] += s1.w + k1.w;
        }
#pragma unroll
        for (int q = 0; q < 8; q++) o[q] = fmaxf(o[q], 0.f);
        if (FINAL) {
            float4 wl0 = *reinterpret_cast<const float4*>(&Wlin[8 * el]);
            float4 wl1 = *reinterpret_cast<const float4*>(&Wlin[8 * el + 4]);
            float d = o[0] * wl0.x + o[1] * wl0.y + o[2] * wl0.z + o[3] * wl0.w +
                      o[4] * wl1.x + o[5] * wl1.y + o[6] * wl1.z + o[7] * wl1.w;
            d += __shfl_xor(d, 1);
            if (el == 0) ((float*)outv)[wid] = 1.0f / (1.0f + expf(-(d + blin[0])));
        } else if (PACKOUT) {
            uint4 pk{pack_f16(o[0], o[1]), pack_f16(o[2], o[3]),
                     pack_f16(o[4], o[5]), pack_f16(o[6], o[7])};
            ((uint4*)outv)[(size_t)wid * L + el] = pk;
        } else {
            float* out = (float*)outv;
            float4 w0{o[0], o[1], o[2], o[3]};
            float4 w1{o[4], o[5], o[6], o[7]};
            *reinterpret_cast<float4*>(&out[(size_t)wid * F + 8 * el]) = w0;
            *reinterpret_cast<float4*>(&out[(size_t)wid * F + 8 * el + 4]) = w1;
        }
    }
}

// ---------------- launch ----------------

extern "C" void kernel_launch(void* const* d_in, const int* in_sizes, int n_in,
                              void* d_out, int out_size, void* d_ws, size_t ws_size,
                              hipStream_t stream) {
    const float* x     = (const float*)d_in[0];
    const int*   ei    = (const int*)d_in[1];
    const float* W1    = (const float*)d_in[2];
    const float* b1    = (const float*)d_in[3];
    const float* W2    = (const float*)d_in[4];
    const float* b2    = (const float*)d_in[5];
    const float* W3    = (const float*)d_in[6];
    const float* b3    = (const float*)d_in[7];
    const float* Wsk02 = (const float*)d_in[8];
    const float* bsk02 = (const float*)d_in[9];
    const float* Wsk13 = (const float*)d_in[10];
    const float* bsk13 = (const float*)d_in[11];
    const float* Wlin  = (const float*)d_in[12];
    const float* blin  = (const float*)d_in[13];

    const int n = in_sizes[0] / 128;
    const int e = in_sizes[1] / 2;

    int shift = 8;
    while (((n + (1 << shift) - 1) >> shift) > MAXB) shift++;
    const int nbkt = (n + (1 << shift) - 1) >> shift;
    const int ncb = (nbkt + 7) / 8;

    // workspace carve (256B aligned)
    char* p = (char*)d_ws;
    auto alloc = [&](size_t bytes) {
        void* r = (void*)p;
        p += (bytes + 255) / 256 * 256;
        return r;
    };
    int*   gcnt    = (int*)alloc(MAXB * 4);
    int*   base    = (int*)alloc((MAXB + 1) * 4);
    int*   gcursor = (int*)alloc(MAXB * 4);
    int*   gcur1   = (int*)alloc(MAXCB * 4);
    unsigned short* wt = (unsigned short*)alloc(15872 * 2);
    int*   row_ptr = (int*)alloc((size_t)(n + 1) * 4);
    float* dinv    = (float*)alloc((size_t)n * 4);
    int*   col     = (int*)alloc((size_t)e * 4);
    size_t h1b     = (size_t)e * 4 > (size_t)n * 128 ? (size_t)e * 4 : (size_t)n * 128;
    unsigned int* h1 = (unsigned int*)alloc(h1b);
    unsigned int* h2 = (unsigned int*)alloc((size_t)n * 64);
    float* sk02    = (float*)alloc((size_t)n * 32 * 4);
    float* sk13    = (float*)alloc((size_t)n * 16 * 4);
    size_t prebytes = (size_t)e * 4 > (size_t)n * 128 ? (size_t)e * 4 : (size_t)n * 128;
    unsigned int* preb = (unsigned int*)alloc(prebytes);
    unsigned int* gpk1 = h1;
    unsigned int* gpk2 = preb;

    auto cdiv = [](int a, int b) { return (a + b - 1) / b; };

    // weight prep (independent)
    prep_w<<<62, 256, 0, stream>>>(W1, Wsk02, W2, Wsk13, W3, wt);

    // CSR build
    hipMemsetAsync(gcnt, 0, MAXB * 4, stream);
    bin_count<<<1024, 256, 0, stream>>>(ei, e, shift, gcnt);
    bin_scan_init<<<1, 1024, 0, stream>>>(gcnt, nbkt, ncb, base, gcursor, gcur1);
    scatter_coarse<<<cdiv(e, TILE1), SCAT_T, 0, stream>>>(ei, e, shift, gcur1, gpk1);
    scatter_fine<<<ncb * 8, SCAT_T, 0, stream>>>(gpk1, base, nbkt, shift, gcursor, gpk2);
    bucket_build<<<nbkt, 256, 0, stream>>>(gpk2, base, shift, n, e, dinv, row_ptr, col);

    // GEMM A (MFMA): preb = (x@W1)*dinv fp16, sk02 = x@Wsk02 fp32
    gemm_mfma<128, 64, 32, false><<<cdiv(n, 64), 256, 0, stream>>>(
        x, wt, dinv, preb, sk02, n);
    // layer 1: h1 = relu(conv(x,W1,b1))  (fp16)
    gather_combine<64, false, true><<<cdiv(n, 4), 256, 0, stream>>>(
        (const uint4*)preb, row_ptr, col, dinv, b1, nullptr, nullptr, h1, nullptr, nullptr, n);

    // GEMM B (MFMA, fp16 A): preb = (h1@W2)*dinv, sk13 = h1@Wsk13
    gemm_mfma<64, 32, 16, true><<<cdiv(n, 64), 256, 0, stream>>>(
        h1, wt + 12288, dinv, preb, sk13, n);
    // layer 2: h2 = relu(conv(h1,W2,b2) + x@Wsk02 + bsk02)  (fp16)
    gather_combine<32, false, true><<<cdiv(n, 4), 256, 0, stream>>>(
        (const uint4*)preb, row_ptr, col, dinv, b2, sk02, bsk02, h2, nullptr, nullptr, n);

    // GEMM C (MFMA, fp16 A): preb = (h2@W3)*dinv
    gemm_mfma<32, 16, 0, true><<<cdiv(n, 64), 256, 0, stream>>>(
        h2, wt + 15360, dinv, preb, sk13, n);
    // layer 3 + head
    gather_combine<16, true, false><<<cdiv(n, 4), 256, 0, stream>>>(
        (const uint4*)preb, row_ptr, col, dinv, b3, sk13, bsk13, d_out, Wlin, blin, n);
}